// Round 3
// baseline (3592.612 us; speedup 1.0000x reference)
//
#include <hip/hip_runtime.h>

constexpr int B_ = 64, N_ = 500, E_ = 16000, L_ = 64, G_ = 64, F_ = 8, H_ = 128;
constexpr int GL_ = G_ * L_;                 // 4096
constexpr int ACC_ELEMS = B_ * N_ * G_;      // 2,048,000 fp32
constexpr size_t ACC_BYTES = (size_t)ACC_ELEMS * 4;   // 8.192 MB

static __device__ __forceinline__ unsigned short f2bf(float f) {
    union { float f; unsigned u; } v; v.f = f;
    unsigned r = v.u + 0x7fffu + ((v.u >> 16) & 1u);
    return (unsigned short)(r >> 16);
}
static __device__ __forceinline__ float bf2f(unsigned short s) {
    union { float f; unsigned u; } v; v.u = ((unsigned)s) << 16;
    return v.f;
}

// ---- zero the fp32 accumulator (ws) ----------------------------------------
__global__ __launch_bounds__(256)
void k_zero(float* __restrict__ acc)
{
    const int i = blockIdx.x * 256 + threadIdx.x;
    if (i < ACC_ELEMS) acc[i] = 0.f;
}

// ---- Kernel A: K[e_local, g*L+l] = relu(ef[e]@W1+b1) @ W2 + b2  (bf16) -----
__global__ __launch_bounds__(256)
void k_gen(const float* __restrict__ ef, const float* __restrict__ W1,
           const float* __restrict__ b1, const float* __restrict__ W2,
           const float* __restrict__ b2, unsigned short* __restrict__ Kb)
{
    const int gl0 = blockIdx.x * 1024;
    const int e0  = blockIdx.y * 16;
    const int tid = threadIdx.x;
    __shared__ float hs[16][H_];
    for (int idx = tid; idx < 16 * H_; idx += 256) {
        const int ei = idx >> 7, hh = idx & 127;
        float v = b1[hh];
        const float* efp = ef + (size_t)(e0 + ei) * F_;
        #pragma unroll
        for (int f = 0; f < F_; ++f) v += efp[f] * W1[f * H_ + hh];
        hs[ei][hh] = v > 0.f ? v : 0.f;
    }
    __syncthreads();
    const int gl = gl0 + tid * 4;
    const float4 bb = *(const float4*)&b2[gl];
    float acc[16][4];
    #pragma unroll
    for (int ei = 0; ei < 16; ++ei) {
        acc[ei][0] = bb.x; acc[ei][1] = bb.y; acc[ei][2] = bb.z; acc[ei][3] = bb.w;
    }
    for (int hh = 0; hh < H_; ++hh) {
        const float4 w = *(const float4*)&W2[(size_t)hh * GL_ + gl];
        #pragma unroll
        for (int ei = 0; ei < 16; ++ei) {
            const float hv = hs[ei][hh];
            acc[ei][0] += hv * w.x; acc[ei][1] += hv * w.y;
            acc[ei][2] += hv * w.z; acc[ei][3] += hv * w.w;
        }
    }
    #pragma unroll
    for (int ei = 0; ei < 16; ++ei) {
        ushort4 u;
        u.x = f2bf(acc[ei][0]); u.y = f2bf(acc[ei][1]);
        u.z = f2bf(acc[ei][2]); u.w = f2bf(acc[ei][3]);
        *(ushort4*)&Kb[(size_t)(e0 + ei) * GL_ + gl] = u;
    }
}

// ---- Kernel B: t[b, e_local, l] = sum_n x[b,n,l] * inc[n, e_off+e] (bf16) --
__global__ __launch_bounds__(256)
void k_t(const float* __restrict__ x, const float* __restrict__ inc,
         unsigned short* __restrict__ t, int e_off, int Ec)
{
    const int e0 = blockIdx.x * 64;
    const int b  = blockIdx.y;
    const int tid = threadIdx.x;
    __shared__ float incs[32][64];
    __shared__ float xs[32][64];
    const int col = tid & 63;
    const int r0  = tid >> 6;
    const int te  = tid >> 4;
    const int tl  = tid & 15;
    float acc[4][4] = {};
    for (int n0 = 0; n0 < N_; n0 += 32) {
        #pragma unroll
        for (int nn = r0; nn < 32; nn += 4) {
            const int n = n0 + nn;
            incs[nn][col] = (n < N_) ? inc[(size_t)n * E_ + e_off + e0 + col] : 0.f;
            xs[nn][col]   = (n < N_) ? x[((size_t)b * N_ + n) * L_ + col] : 0.f;
        }
        __syncthreads();
        #pragma unroll 8
        for (int nn = 0; nn < 32; ++nn) {
            const float4 a = *(const float4*)&incs[nn][te * 4];
            const float4 c = *(const float4*)&xs[nn][tl * 4];
            const float av[4] = {a.x, a.y, a.z, a.w};
            const float cv[4] = {c.x, c.y, c.z, c.w};
            #pragma unroll
            for (int i = 0; i < 4; ++i)
                #pragma unroll
                for (int j = 0; j < 4; ++j)
                    acc[i][j] += av[i] * cv[j];
        }
        __syncthreads();
    }
    #pragma unroll
    for (int i = 0; i < 4; ++i) {
        ushort4 u;
        u.x = f2bf(acc[i][0]); u.y = f2bf(acc[i][1]);
        u.z = f2bf(acc[i][2]); u.w = f2bf(acc[i][3]);
        *(ushort4*)&t[((size_t)b * Ec + e0 + te * 4 + i) * L_ + tl * 4] = u;
    }
}

// ---- Kernel C: y[b, e_local, g] = sum_l K[e,g,l] * t[b,e,l]  (bf16) --------
__global__ __launch_bounds__(256)
void k_y(const unsigned short* __restrict__ Kb, const unsigned short* __restrict__ t,
         unsigned short* __restrict__ y, int Ec)
{
    const int e = blockIdx.x;
    const int tid = threadIdx.x;
    __shared__ float Ks[64][64];
    __shared__ float ts[64][68];
    const int l  = tid & 63;
    const int r0 = tid >> 6;
    #pragma unroll
    for (int r = r0; r < 64; r += 4) {
        const int c  = l >> 2;
        const int cs = c ^ (r >> 2);
        Ks[r][(cs << 2) | (l & 3)] = bf2f(Kb[(size_t)e * GL_ + r * 64 + l]);
        ts[r][l] = bf2f(t[((size_t)r * Ec + e) * L_ + l]);
    }
    __syncthreads();
    const int tg = tid & 15, tb = tid >> 4;
    float acc[4][4] = {};
    #pragma unroll
    for (int c = 0; c < 16; ++c) {
        float4 tv[4], kv[4];
        #pragma unroll
        for (int i = 0; i < 4; ++i) tv[i] = *(const float4*)&ts[tb * 4 + i][c * 4];
        #pragma unroll
        for (int j = 0; j < 4; ++j)
            kv[j] = *(const float4*)&Ks[tg * 4 + j][(c ^ tg) << 2];
        #pragma unroll
        for (int i = 0; i < 4; ++i)
            #pragma unroll
            for (int j = 0; j < 4; ++j)
                acc[i][j] += tv[i].x * kv[j].x + tv[i].y * kv[j].y
                           + tv[i].z * kv[j].z + tv[i].w * kv[j].w;
    }
    #pragma unroll
    for (int i = 0; i < 4; ++i) {
        ushort4 u;
        u.x = f2bf(acc[i][0]); u.y = f2bf(acc[i][1]);
        u.z = f2bf(acc[i][2]); u.w = f2bf(acc[i][3]);
        *(ushort4*)&y[((size_t)(tb * 4 + i) * Ec + e) * G_ + tg * 4] = u;
    }
}

// ---- Kernel D: acc[b,n,g] += sum_e inc[n, e_off+e] * y[b,e,g]  (atomicAdd) -
__global__ __launch_bounds__(256)
void k_acc(const float* __restrict__ inc, const unsigned short* __restrict__ y,
           float* __restrict__ acc, int e_off, int Ec)
{
    const int n0 = blockIdx.x * 64;
    const int b  = blockIdx.y;
    const int tid = threadIdx.x;
    __shared__ float incs[64][65];
    __shared__ float ys[64][64];
    const int col = tid & 63;
    const int r0  = tid >> 6;
    const int tg = tid & 15, tn = tid >> 4;
    float a[4][4] = {};
    for (int ec = 0; ec < Ec; ec += 64) {
        #pragma unroll
        for (int rr = r0; rr < 64; rr += 4) {
            const int n = n0 + rr;
            incs[col][rr] = (n < N_) ? inc[(size_t)n * E_ + e_off + ec + col] : 0.f;
            ys[rr][col]   = bf2f(y[((size_t)b * Ec + ec + rr) * G_ + col]);
        }
        __syncthreads();
        #pragma unroll 8
        for (int ee = 0; ee < 64; ++ee) {
            const float4 yv = *(const float4*)&ys[ee][tg * 4];
            float iv[4];
            #pragma unroll
            for (int i = 0; i < 4; ++i) iv[i] = incs[ee][tn * 4 + i];
            #pragma unroll
            for (int i = 0; i < 4; ++i) {
                a[i][0] += iv[i] * yv.x; a[i][1] += iv[i] * yv.y;
                a[i][2] += iv[i] * yv.z; a[i][3] += iv[i] * yv.w;
            }
        }
        __syncthreads();
    }
    #pragma unroll
    for (int i = 0; i < 4; ++i) {
        const int n = n0 + tn * 4 + i;
        if (n < N_) {
            float* ap = &acc[((size_t)b * N_ + n) * G_ + tg * 4];
            #pragma unroll
            for (int j = 0; j < 4; ++j) atomicAdd(&ap[j], a[i][j]);
        }
    }
}

// ---- final: out = relu(acc + bgc)  (single write of d_out) -----------------
__global__ __launch_bounds__(256)
void k_final(const float* __restrict__ acc, const float* __restrict__ bgc,
             float* __restrict__ out)
{
    const int i = blockIdx.x * 256 + threadIdx.x;
    if (i < ACC_ELEMS) {
        const int g = i & 63;
        out[i] = fmaxf(acc[i] + bgc[g], 0.f);
    }
}

extern "C" void kernel_launch(void* const* d_in, const int* in_sizes, int n_in,
                              void* d_out, int out_size, void* d_ws, size_t ws_size,
                              hipStream_t stream) {
    const float* x   = (const float*)d_in[0];
    const float* inc = (const float*)d_in[1];
    const float* ef  = (const float*)d_in[2];
    const float* W1  = (const float*)d_in[3];
    const float* b1  = (const float*)d_in[4];
    const float* W2  = (const float*)d_in[5];
    const float* b2  = (const float*)d_in[6];
    const float* bgc = (const float*)d_in[7];
    float* out = (float*)d_out;

    float* accw = (float*)d_ws;
    unsigned short* chunkw = (unsigned short*)((char*)d_ws + ACC_BYTES);

    // Per-edge chunk scratch: K (GL) + t (B*L) + y (B*G) bf16 = 24576 B/edge.
    const size_t perEdge = ((size_t)GL_ + (size_t)B_ * L_ + (size_t)B_ * G_) * 2;
    const size_t avail = ws_size > ACC_BYTES ? ws_size - ACC_BYTES : 0;
    int Ec = (int)((avail / perEdge / 64) * 64);
    if (Ec > E_) Ec = E_;
    if (Ec < 64) Ec = 64;   // requires ws_size >= ~9.8 MB

    k_zero<<<dim3((ACC_ELEMS + 255) / 256), dim3(256), 0, stream>>>(accw);

    for (int e_off = 0; e_off < E_; e_off += Ec) {
        const int ec = (E_ - e_off) < Ec ? (E_ - e_off) : Ec;   // multiple of 64
        unsigned short* Kw = chunkw;
        unsigned short* tw = Kw + (size_t)ec * GL_;
        unsigned short* yw = tw + (size_t)B_ * ec * L_;

        k_gen<<<dim3(GL_ / 1024, ec / 16), dim3(256), 0, stream>>>(
            ef + (size_t)e_off * F_, W1, b1, W2, b2, Kw);
        k_t  <<<dim3(ec / 64, B_), dim3(256), 0, stream>>>(x, inc, tw, e_off, ec);
        k_y  <<<dim3(ec),          dim3(256), 0, stream>>>(Kw, tw, yw, ec);
        k_acc<<<dim3((N_ + 63) / 64, B_), dim3(256), 0, stream>>>(
            inc, yw, accw, e_off, ec);
    }

    k_final<<<dim3((ACC_ELEMS + 255) / 256), dim3(256), 0, stream>>>(accw, bgc, out);
}

// Round 5
// 1234.069 us; speedup vs baseline: 2.9112x; 2.9112x over previous
//
#include <hip/hip_runtime.h>

constexpr int B_ = 64, N_ = 500, E_ = 16000, L_ = 64, G_ = 64, F_ = 8, H_ = 128;
constexpr int GL_ = 4096;     // G*L
constexpr int NP_ = 512;      // n padded to multiple of 64 (zero pad)
constexpr int ACC_ELEMS = B_ * N_ * G_;               // 2,048,000 fp32
constexpr size_t ACC_BYTES = (size_t)ACC_ELEMS * 4;   // 8.192 MB

using bf16x8  = __attribute__((ext_vector_type(8))) short;
using f32x4   = __attribute__((ext_vector_type(4))) float;
using ushort8 = __attribute__((ext_vector_type(8))) unsigned short;

#define MFMA16(a, b, c) __builtin_amdgcn_mfma_f32_16x16x32_bf16((a), (b), (c), 0, 0, 0)

static __device__ __forceinline__ unsigned short f2bf(float f) {
    union { float f; unsigned u; } v; v.f = f;
    unsigned r = v.u + 0x7fffu + ((v.u >> 16) & 1u);
    return (unsigned short)(r >> 16);
}

// ---- zero the fp32 accumulator ---------------------------------------------
__global__ __launch_bounds__(256)
void k_zero(float* __restrict__ acc)
{
    const int i = blockIdx.x * 256 + threadIdx.x;
    if (i < ACC_ELEMS) acc[i] = 0.f;
}

// ---- incB[n][e] bf16, rows n>=500 zeroed -----------------------------------
__global__ __launch_bounds__(256)
void k_cvt_incB(const float* __restrict__ inc, unsigned short* __restrict__ incB)
{
    const int n = blockIdx.y;
    const int c = blockIdx.x * 1024 + threadIdx.x * 4;
    if (c >= E_) return;
    ushort4 u;
    if (n < N_) {
        const float4 v = *(const float4*)&inc[(size_t)n * E_ + c];
        u.x = f2bf(v.x); u.y = f2bf(v.y); u.z = f2bf(v.z); u.w = f2bf(v.w);
    } else { u.x = 0; u.y = 0; u.z = 0; u.w = 0; }
    *(ushort4*)&incB[(size_t)n * E_ + c] = u;
}

// ---- generic f32 [R][C] -> bf16 [C][Rp] transpose, zero pad rows >= R ------
__global__ __launch_bounds__(256)
void k_tr32(const float* __restrict__ in, unsigned short* __restrict__ out,
            int R, int C, int Rp, size_t inZ, size_t outZ)
{
    in  += (size_t)blockIdx.z * inZ;
    out += (size_t)blockIdx.z * outZ;
    const int c0 = blockIdx.x * 64, r0 = blockIdx.y * 64;
    __shared__ float sm[64][65];
    const int cl = threadIdx.x & 63;
    for (int rr = threadIdx.x >> 6; rr < 64; rr += 4) {
        const int r = r0 + rr;
        sm[cl][rr] = (r < R) ? in[(size_t)r * C + c0 + cl] : 0.f;
    }
    __syncthreads();
    const int cw = threadIdx.x >> 2, j0 = (threadIdx.x & 3) * 16;
    unsigned short tmp[16];
    #pragma unroll
    for (int j = 0; j < 16; ++j) tmp[j] = f2bf(sm[cw][j0 + j]);
    *(ushort8*)&out[(size_t)(c0 + cw) * Rp + r0 + j0]     = *(ushort8*)&tmp[0];
    *(ushort8*)&out[(size_t)(c0 + cw) * Rp + r0 + j0 + 8] = *(ushort8*)&tmp[8];
}

// ---- h[e][hh] = relu(ef@W1 + b1) bf16 --------------------------------------
__global__ __launch_bounds__(256)
void k_h(const float* __restrict__ ef, const float* __restrict__ W1,
         const float* __restrict__ b1, unsigned short* __restrict__ h)
{
    const int idx = blockIdx.x * 256 + threadIdx.x;
    const int e = idx >> 7, hh = idx & 127;
    float v = b1[hh];
    const float* efp = &ef[(size_t)e * F_];
    #pragma unroll
    for (int f = 0; f < F_; ++f) v += efp[f] * W1[f * H_ + hh];
    h[idx] = f2bf(fmaxf(v, 0.f));
}

// ---- K[e_loc][gl] = h @ W2T^T + b2  (MFMA, chunk) --------------------------
__global__ __launch_bounds__(256)
void k_gen(const unsigned short* __restrict__ h, const unsigned short* __restrict__ W2T,
           const float* __restrict__ b2, unsigned short* __restrict__ Kc)
{
    const int gl0 = blockIdx.x * 64, e0 = blockIdx.y * 64;
    const int tid = threadIdx.x, lane = tid & 63, wid = tid >> 6;
    const int wm = wid >> 1, wn = wid & 1;
    const int row = lane & 15, koff = (lane >> 4) * 8;
    const unsigned short* A  = &h[(size_t)(e0 + wm * 32 + row) * H_ + koff];
    const unsigned short* Bp = &W2T[(size_t)(gl0 + wn * 32 + row) * H_ + koff];
    const f32x4 fz = {0.f, 0.f, 0.f, 0.f};
    f32x4 acc[2][2] = {{fz, fz}, {fz, fz}};
    #pragma unroll
    for (int k0 = 0; k0 < H_; k0 += 32) {
        const bf16x8 a0 = *(const bf16x8*)(A + k0);
        const bf16x8 a1 = *(const bf16x8*)(A + 16 * H_ + k0);
        const bf16x8 b0 = *(const bf16x8*)(Bp + k0);
        const bf16x8 bv = *(const bf16x8*)(Bp + 16 * H_ + k0);
        acc[0][0] = MFMA16(a0, b0, acc[0][0]);
        acc[0][1] = MFMA16(a0, bv, acc[0][1]);
        acc[1][0] = MFMA16(a1, b0, acc[1][0]);
        acc[1][1] = MFMA16(a1, bv, acc[1][1]);
    }
    __shared__ unsigned short sm[64][72];
    #pragma unroll
    for (int mi = 0; mi < 2; ++mi)
        #pragma unroll
        for (int ni = 0; ni < 2; ++ni) {
            const float bias = b2[gl0 + wn * 32 + ni * 16 + row];
            #pragma unroll
            for (int r = 0; r < 4; ++r)
                sm[wm * 32 + mi * 16 + (lane >> 4) * 4 + r][wn * 32 + ni * 16 + row] =
                    f2bf(acc[mi][ni][r] + bias);
        }
    __syncthreads();
    const int er = tid >> 2, c = (tid & 3) * 16;
    *(ushort8*)&Kc[(size_t)(e0 + er) * GL_ + gl0 + c]     = *(ushort8*)&sm[er][c];
    *(ushort8*)&Kc[(size_t)(e0 + er) * GL_ + gl0 + c + 8] = *(ushort8*)&sm[er][c + 8];
}

// ---- t[e_loc][b][l] = incT_chunk @ xT_b^T  (MFMA, K=512) -------------------
__global__ __launch_bounds__(256)
void k_t(const unsigned short* __restrict__ incT, const unsigned short* __restrict__ xT,
         unsigned short* __restrict__ t)
{
    const int e0 = blockIdx.x * 64, b = blockIdx.y;
    const int tid = threadIdx.x, lane = tid & 63, wid = tid >> 6;
    const int wm = wid >> 1, wn = wid & 1;
    const int row = lane & 15, koff = (lane >> 4) * 8;
    const unsigned short* A  = &incT[(size_t)(e0 + wm * 32 + row) * NP_ + koff];
    const unsigned short* Bp = &xT[((size_t)b * 64 + wn * 32 + row) * NP_ + koff];
    const f32x4 fz = {0.f, 0.f, 0.f, 0.f};
    f32x4 acc[2][2] = {{fz, fz}, {fz, fz}};
    #pragma unroll 4
    for (int k0 = 0; k0 < NP_; k0 += 32) {
        const bf16x8 a0 = *(const bf16x8*)(A + k0);
        const bf16x8 a1 = *(const bf16x8*)(A + 16 * NP_ + k0);
        const bf16x8 b0 = *(const bf16x8*)(Bp + k0);
        const bf16x8 bv = *(const bf16x8*)(Bp + 16 * NP_ + k0);
        acc[0][0] = MFMA16(a0, b0, acc[0][0]);
        acc[0][1] = MFMA16(a0, bv, acc[0][1]);
        acc[1][0] = MFMA16(a1, b0, acc[1][0]);
        acc[1][1] = MFMA16(a1, bv, acc[1][1]);
    }
    __shared__ unsigned short sm[64][72];   // [e][l]
    #pragma unroll
    for (int mi = 0; mi < 2; ++mi)
        #pragma unroll
        for (int ni = 0; ni < 2; ++ni)
            #pragma unroll
            for (int r = 0; r < 4; ++r)
                sm[wm * 32 + mi * 16 + (lane >> 4) * 4 + r][wn * 32 + ni * 16 + row] =
                    f2bf(acc[mi][ni][r]);
    __syncthreads();
    const int er = tid >> 2, c = (tid & 3) * 16;
    *(ushort8*)&t[(size_t)(e0 + er) * GL_ + b * 64 + c]     = *(ushort8*)&sm[er][c];
    *(ushort8*)&t[(size_t)(e0 + er) * GL_ + b * 64 + c + 8] = *(ushort8*)&sm[er][c + 8];
}

// ---- y[e_loc][b*64+g] = t[e] @ K[e]^T  (MFMA per edge) ---------------------
__global__ __launch_bounds__(256)
void k_y(const unsigned short* __restrict__ t, const unsigned short* __restrict__ Kc,
         unsigned short* __restrict__ y)
{
    const int e = blockIdx.x;
    const int tid = threadIdx.x, lane = tid & 63, wid = tid >> 6;
    const int wm = wid >> 1, wn = wid & 1;
    const int row = lane & 15, koff = (lane >> 4) * 8;
    const unsigned short* A  = &t[(size_t)e * GL_ + (wm * 32 + row) * 64 + koff];
    const unsigned short* Bp = &Kc[(size_t)e * GL_ + (wn * 32 + row) * 64 + koff];
    const f32x4 fz = {0.f, 0.f, 0.f, 0.f};
    f32x4 acc[2][2] = {{fz, fz}, {fz, fz}};
    #pragma unroll
    for (int l0 = 0; l0 < 64; l0 += 32) {
        const bf16x8 a0 = *(const bf16x8*)(A + l0);
        const bf16x8 a1 = *(const bf16x8*)(A + 1024 + l0);
        const bf16x8 b0 = *(const bf16x8*)(Bp + l0);
        const bf16x8 bv = *(const bf16x8*)(Bp + 1024 + l0);
        acc[0][0] = MFMA16(a0, b0, acc[0][0]);
        acc[0][1] = MFMA16(a0, bv, acc[0][1]);
        acc[1][0] = MFMA16(a1, b0, acc[1][0]);
        acc[1][1] = MFMA16(a1, bv, acc[1][1]);
    }
    __shared__ unsigned short sm[64][72];   // [b][g]
    #pragma unroll
    for (int mi = 0; mi < 2; ++mi)
        #pragma unroll
        for (int ni = 0; ni < 2; ++ni)
            #pragma unroll
            for (int r = 0; r < 4; ++r)
                sm[wm * 32 + mi * 16 + (lane >> 4) * 4 + r][wn * 32 + ni * 16 + row] =
                    f2bf(acc[mi][ni][r]);
    __syncthreads();
    const int er = tid >> 2, c = (tid & 3) * 16;
    *(ushort8*)&y[(size_t)e * GL_ + er * 64 + c]     = *(ushort8*)&sm[er][c];
    *(ushort8*)&y[(size_t)e * GL_ + er * 64 + c + 8] = *(ushort8*)&sm[er][c + 8];
}

// ---- yT[bg][e_loc] <- y[e_loc][bg]  (bf16 transpose, chunk) ----------------
__global__ __launch_bounds__(256)
void k_tr(const unsigned short* __restrict__ y, unsigned short* __restrict__ yT, int ec)
{
    const int c0 = blockIdx.x * 64;   // over 4096 (bg)
    const int r0 = blockIdx.y * 64;   // over ec (e)
    __shared__ unsigned int sm[64][65];
    const int cl = threadIdx.x & 63;
    for (int rr = threadIdx.x >> 6; rr < 64; rr += 4)
        sm[cl][rr] = y[(size_t)(r0 + rr) * GL_ + c0 + cl];
    __syncthreads();
    const int cw = threadIdx.x >> 2, j0 = (threadIdx.x & 3) * 16;
    unsigned short tmp[16];
    #pragma unroll
    for (int j = 0; j < 16; ++j) tmp[j] = (unsigned short)sm[cw][j0 + j];
    *(ushort8*)&yT[(size_t)(c0 + cw) * ec + r0 + j0]     = *(ushort8*)&tmp[0];
    *(ushort8*)&yT[(size_t)(c0 + cw) * ec + r0 + j0 + 8] = *(ushort8*)&tmp[8];
}

// ---- acc[b][n][g] += incB[n][e_off..] @ yT_b^T  (MFMA, atomic epilogue) ----
__global__ __launch_bounds__(256)
void k_acc(const unsigned short* __restrict__ incB, const unsigned short* __restrict__ yT,
           float* __restrict__ acc, int e_off, int ec)
{
    const int n0 = blockIdx.x * 64, b = blockIdx.y;
    const int tid = threadIdx.x, lane = tid & 63, wid = tid >> 6;
    const int wm = wid >> 1, wn = wid & 1;
    const int row = lane & 15, koff = (lane >> 4) * 8;
    const unsigned short* A  = &incB[(size_t)(n0 + wm * 32 + row) * E_ + e_off + koff];
    const unsigned short* Bp = &yT[((size_t)b * 64 + wn * 32 + row) * ec + koff];
    const f32x4 fz = {0.f, 0.f, 0.f, 0.f};
    f32x4 a4[2][2] = {{fz, fz}, {fz, fz}};
    #pragma unroll 2
    for (int k0 = 0; k0 < ec; k0 += 32) {
        const bf16x8 a0 = *(const bf16x8*)(A + k0);
        const bf16x8 a1 = *(const bf16x8*)(A + (size_t)16 * E_ + k0);
        const bf16x8 b0 = *(const bf16x8*)(Bp + k0);
        const bf16x8 bv = *(const bf16x8*)(Bp + (size_t)16 * ec + k0);
        a4[0][0] = MFMA16(a0, b0, a4[0][0]);
        a4[0][1] = MFMA16(a0, bv, a4[0][1]);
        a4[1][0] = MFMA16(a1, b0, a4[1][0]);
        a4[1][1] = MFMA16(a1, bv, a4[1][1]);
    }
    #pragma unroll
    for (int mi = 0; mi < 2; ++mi)
        #pragma unroll
        for (int ni = 0; ni < 2; ++ni) {
            const int g = wn * 32 + ni * 16 + row;
            #pragma unroll
            for (int r = 0; r < 4; ++r) {
                const int n = n0 + wm * 32 + mi * 16 + (lane >> 4) * 4 + r;
                if (n < N_)
                    atomicAdd(&acc[((size_t)b * N_ + n) * G_ + g], a4[mi][ni][r]);
            }
        }
}

// ---- final: out = relu(acc + bgc), single write of d_out -------------------
__global__ __launch_bounds__(256)
void k_final(const float* __restrict__ acc, const float* __restrict__ bgc,
             float* __restrict__ out)
{
    const int i = blockIdx.x * 256 + threadIdx.x;
    if (i < ACC_ELEMS) out[i] = fmaxf(acc[i] + bgc[i & 63], 0.f);
}

extern "C" void kernel_launch(void* const* d_in, const int* in_sizes, int n_in,
                              void* d_out, int out_size, void* d_ws, size_t ws_size,
                              hipStream_t stream) {
    const float* x   = (const float*)d_in[0];
    const float* inc = (const float*)d_in[1];
    const float* ef  = (const float*)d_in[2];
    const float* W1  = (const float*)d_in[3];
    const float* b1  = (const float*)d_in[4];
    const float* W2  = (const float*)d_in[5];
    const float* b2  = (const float*)d_in[6];
    const float* bgc = (const float*)d_in[7];
    float* out = (float*)d_out;

    // ws: acc fp32 | incB | incT | xT | h | W2T | chunk{K/yT, t, y}
    float* accw = (float*)d_ws;
    unsigned short* incB = (unsigned short*)((char*)d_ws + ACC_BYTES);
    unsigned short* incT = incB + (size_t)NP_ * E_;
    unsigned short* xT   = incT + (size_t)E_ * NP_;
    unsigned short* h    = xT   + (size_t)B_ * L_ * NP_;
    unsigned short* W2T  = h    + (size_t)E_ * H_;
    unsigned short* chunk = W2T + (size_t)GL_ * H_;
    const size_t persistBytes = (char*)chunk - (char*)d_ws;   // ~50.3 MB

    const size_t perEdge = 3 * (size_t)GL_ * 2;               // 24576 B
    const size_t avail = ws_size > persistBytes ? ws_size - persistBytes : 0;
    int Ec = (int)((avail / perEdge / 64) * 64);
    if (Ec > E_) Ec = E_;
    if (Ec < 64) Ec = 64;

    unsigned short* Kc = chunk;                       // [Ec][4096]; later yT
    unsigned short* tc = Kc + (size_t)Ec * GL_;       // [Ec][64][64]
    unsigned short* yc = tc + (size_t)Ec * GL_;       // [Ec][4096]

    k_zero<<<dim3((ACC_ELEMS + 255) / 256), 256, 0, stream>>>(accw);
    k_cvt_incB<<<dim3(16, NP_), 256, 0, stream>>>(inc, incB);
    k_tr32<<<dim3(E_ / 64, NP_ / 64, 1), 256, 0, stream>>>(inc, incT, N_, E_, NP_, 0, 0);
    k_tr32<<<dim3(1, NP_ / 64, B_),      256, 0, stream>>>(x, xT, N_, L_, NP_,
                                                           (size_t)N_ * L_, (size_t)L_ * NP_);
    k_tr32<<<dim3(GL_ / 64, H_ / 64, 1), 256, 0, stream>>>(W2, W2T, H_, GL_, H_, 0, 0);
    k_h<<<dim3(E_ * H_ / 256), 256, 0, stream>>>(ef, W1, b1, h);

    for (int e_off = 0; e_off < E_; e_off += Ec) {
        const int ec = (E_ - e_off) < Ec ? (E_ - e_off) : Ec;   // multiple of 64
        k_gen<<<dim3(GL_ / 64, ec / 64), 256, 0, stream>>>(h + (size_t)e_off * H_, W2T, b2, Kc);
        k_t  <<<dim3(ec / 64, B_), 256, 0, stream>>>(incT + (size_t)e_off * NP_, xT, tc);
        k_y  <<<dim3(ec),          256, 0, stream>>>(tc, Kc, yc);
        k_tr <<<dim3(GL_ / 64, ec / 64), 256, 0, stream>>>(yc, Kc, ec);   // yT over K
        k_acc<<<dim3(NP_ / 64, B_), 256, 0, stream>>>(incB, Kc, accw, e_off, ec);
    }

    k_final<<<dim3((ACC_ELEMS + 255) / 256), 256, 0, stream>>>(accw, bgc, out);
}

// Round 6
// 1089.402 us; speedup vs baseline: 3.2978x; 1.1328x over previous
//
#include <hip/hip_runtime.h>

constexpr int B_ = 64, N_ = 500, E_ = 16000, L_ = 64, G_ = 64, F_ = 8, H_ = 128;
constexpr int GL_ = 4096;     // G*L
constexpr int NP_ = 512;      // n padded
constexpr int ACC_ELEMS = B_ * N_ * G_;               // 2,048,000 fp32
constexpr size_t ACC_BYTES = (size_t)ACC_ELEMS * 4;   // 8.192 MB

using bf16x8  = __attribute__((ext_vector_type(8))) short;
using f32x4   = __attribute__((ext_vector_type(4))) float;
using ushort8 = __attribute__((ext_vector_type(8))) unsigned short;

#define MFMA16(a, b, c) __builtin_amdgcn_mfma_f32_16x16x32_bf16((a), (b), (c), 0, 0, 0)

static __device__ __forceinline__ unsigned short f2bf(float f) {
    union { float f; unsigned u; } v; v.f = f;
    unsigned r = v.u + 0x7fffu + ((v.u >> 16) & 1u);
    return (unsigned short)(r >> 16);
}

// ======================= unified 128x128 MFMA GEMM ==========================
// C[M][N] = A[M][K] (row-major, lda) @ Bm[N][K]^T (row-major, ldb)
// MODE 0: store bf16 C (ldc). MODE 1: +bias[col], store bf16. MODE 2: atomicAdd
// fp32 into acc[b][n][g] with col=(b*64+g), row=n (guard n<N_), K-split grid.y.
template<int MODE>
__global__ __launch_bounds__(256)
void gemm128(const unsigned short* __restrict__ A, int lda,
             const unsigned short* __restrict__ Bm, int ldb,
             int K, int nN,
             unsigned short* __restrict__ C, int ldc,
             const float* __restrict__ bias, float* __restrict__ accp)
{
    const int nwg = gridDim.x;
    const int bid = blockIdx.x;
    const int swz = (nwg & 7) ? bid : ((bid & 7) * (nwg >> 3) + (bid >> 3));
    const int m0 = (swz / nN) * 128, n0 = (swz % nN) * 128;

    int kbeg = 0, kend = K;
    if (MODE == 2) {                       // K-split across blockIdx.y
        const int kl = K / gridDim.y;      // caller guarantees kl % 64 == 0
        kbeg = blockIdx.y * kl;
        kend = kbeg + kl;
    }

    const int tid  = threadIdx.x;
    const int srow = tid >> 3;             // 0..31
    const int soff = (tid & 7) * 8;        // element offset (8 ushorts = 16B)
    const int lane = tid & 63, wid = tid >> 6;
    const int wm = wid >> 1, wn = wid & 1;
    const int fr = lane & 15, fq = lane >> 4;

    __shared__ __align__(16) unsigned short sm[2][128][72];  // +8 pad: bank rotate
    auto As = sm[0];
    auto Bs = sm[1];

    uint4 ra[4], rb[4];
    const int nk = (kend - kbeg) / 64;
    #pragma unroll
    for (int i = 0; i < 4; ++i) {
        ra[i] = *(const uint4*)&A[(size_t)(m0 + i * 32 + srow) * lda + kbeg + soff];
        rb[i] = *(const uint4*)&Bm[(size_t)(n0 + i * 32 + srow) * ldb + kbeg + soff];
    }
    const f32x4 fz = {0.f, 0.f, 0.f, 0.f};
    f32x4 acc[4][4] = {{fz, fz, fz, fz}, {fz, fz, fz, fz},
                       {fz, fz, fz, fz}, {fz, fz, fz, fz}};

    for (int kt = 0; kt < nk; ++kt) {
        #pragma unroll
        for (int i = 0; i < 4; ++i) {
            *(uint4*)&As[i * 32 + srow][soff] = ra[i];
            *(uint4*)&Bs[i * 32 + srow][soff] = rb[i];
        }
        __syncthreads();
        if (kt + 1 < nk) {
            const int kk = kbeg + (kt + 1) * 64;
            #pragma unroll
            for (int i = 0; i < 4; ++i) {
                ra[i] = *(const uint4*)&A[(size_t)(m0 + i * 32 + srow) * lda + kk + soff];
                rb[i] = *(const uint4*)&Bm[(size_t)(n0 + i * 32 + srow) * ldb + kk + soff];
            }
        }
        #pragma unroll
        for (int ks = 0; ks < 2; ++ks) {
            bf16x8 af[4], bf[4];
            #pragma unroll
            for (int i = 0; i < 4; ++i)
                af[i] = *(const bf16x8*)&As[wm * 64 + i * 16 + fr][ks * 32 + fq * 8];
            #pragma unroll
            for (int j = 0; j < 4; ++j)
                bf[j] = *(const bf16x8*)&Bs[wn * 64 + j * 16 + fr][ks * 32 + fq * 8];
            #pragma unroll
            for (int i = 0; i < 4; ++i)
                #pragma unroll
                for (int j = 0; j < 4; ++j)
                    acc[i][j] = MFMA16(af[i], bf[j], acc[i][j]);
        }
        __syncthreads();
    }

    if constexpr (MODE == 2) {
        #pragma unroll
        for (int i = 0; i < 4; ++i)
            #pragma unroll
            for (int j = 0; j < 4; ++j) {
                const int col = n0 + wn * 64 + j * 16 + fr;
                const int b = col >> 6, g = col & 63;
                #pragma unroll
                for (int r = 0; r < 4; ++r) {
                    const int n = m0 + wm * 64 + i * 16 + fq * 4 + r;
                    if (n < N_)
                        atomicAdd(&accp[((size_t)b * N_ + n) * G_ + g], acc[i][j][r]);
                }
            }
    } else {
        auto Cs = (unsigned short(*)[128])&sm[0][0][0];
        #pragma unroll
        for (int i = 0; i < 4; ++i)
            #pragma unroll
            for (int j = 0; j < 4; ++j) {
                float bv = 0.f;
                if constexpr (MODE == 1) bv = bias[n0 + wn * 64 + j * 16 + fr];
                #pragma unroll
                for (int r = 0; r < 4; ++r)
                    Cs[wm * 64 + i * 16 + fq * 4 + r][wn * 64 + j * 16 + fr] =
                        f2bf(acc[i][j][r] + bv);
            }
        __syncthreads();
        const int r2 = tid >> 4, o2 = (tid & 15) * 8;
        #pragma unroll
        for (int i = 0; i < 8; ++i) {
            const int row = i * 16 + r2;
            *(uint4*)&C[(size_t)(m0 + row) * ldc + n0 + o2] = *(const uint4*)&Cs[row][o2];
        }
    }
}

// ======================= prologue / small kernels ===========================
__global__ __launch_bounds__(256)
void k_zero(float* __restrict__ acc)
{
    const int i = blockIdx.x * 256 + threadIdx.x;
    if (i < ACC_ELEMS) acc[i] = 0.f;
}

__global__ __launch_bounds__(256)
void k_cvt_incB(const float* __restrict__ inc, unsigned short* __restrict__ incB)
{
    const int n = blockIdx.y;
    const int c = blockIdx.x * 1024 + threadIdx.x * 4;
    if (c >= E_) return;
    ushort4 u;
    if (n < N_) {
        const float4 v = *(const float4*)&inc[(size_t)n * E_ + c];
        u.x = f2bf(v.x); u.y = f2bf(v.y); u.z = f2bf(v.z); u.w = f2bf(v.w);
    } else { u.x = 0; u.y = 0; u.z = 0; u.w = 0; }
    *(ushort4*)&incB[(size_t)n * E_ + c] = u;
}

__global__ __launch_bounds__(256)
void k_tr32(const float* __restrict__ in, unsigned short* __restrict__ out,
            int R, int C, int Rp, size_t inZ, size_t outZ)
{
    in  += (size_t)blockIdx.z * inZ;
    out += (size_t)blockIdx.z * outZ;
    const int c0 = blockIdx.x * 64, r0 = blockIdx.y * 64;
    __shared__ float sm[64][65];
    const int cl = threadIdx.x & 63;
    for (int rr = threadIdx.x >> 6; rr < 64; rr += 4) {
        const int r = r0 + rr;
        sm[cl][rr] = (r < R) ? in[(size_t)r * C + c0 + cl] : 0.f;
    }
    __syncthreads();
    const int cw = threadIdx.x >> 2, j0 = (threadIdx.x & 3) * 16;
    unsigned short tmp[16];
    #pragma unroll
    for (int j = 0; j < 16; ++j) tmp[j] = f2bf(sm[cw][j0 + j]);
    *(ushort8*)&out[(size_t)(c0 + cw) * Rp + r0 + j0]     = *(ushort8*)&tmp[0];
    *(ushort8*)&out[(size_t)(c0 + cw) * Rp + r0 + j0 + 8] = *(ushort8*)&tmp[8];
}

__global__ __launch_bounds__(256)
void k_h(const float* __restrict__ ef, const float* __restrict__ W1,
         const float* __restrict__ b1, unsigned short* __restrict__ h)
{
    const int idx = blockIdx.x * 256 + threadIdx.x;
    const int e = idx >> 7, hh = idx & 127;
    float v = b1[hh];
    const float* efp = &ef[(size_t)e * F_];
    #pragma unroll
    for (int f = 0; f < F_; ++f) v += efp[f] * W1[f * H_ + hh];
    h[idx] = f2bf(fmaxf(v, 0.f));
}

// ---- y[e_loc][b*64+g] = t[e] @ K[e]^T  (MFMA per edge) ---------------------
__global__ __launch_bounds__(256)
void k_y(const unsigned short* __restrict__ t, const unsigned short* __restrict__ Kc,
         unsigned short* __restrict__ y)
{
    const int e = blockIdx.x;
    const int tid = threadIdx.x, lane = tid & 63, wid = tid >> 6;
    const int wm = wid >> 1, wn = wid & 1;
    const int row = lane & 15, koff = (lane >> 4) * 8;
    const unsigned short* A  = &t[(size_t)e * GL_ + (wm * 32 + row) * 64 + koff];
    const unsigned short* Bp = &Kc[(size_t)e * GL_ + (wn * 32 + row) * 64 + koff];
    const f32x4 fz = {0.f, 0.f, 0.f, 0.f};
    f32x4 acc[2][2] = {{fz, fz}, {fz, fz}};
    #pragma unroll
    for (int l0 = 0; l0 < 64; l0 += 32) {
        const bf16x8 a0 = *(const bf16x8*)(A + l0);
        const bf16x8 a1 = *(const bf16x8*)(A + 1024 + l0);
        const bf16x8 b0 = *(const bf16x8*)(Bp + l0);
        const bf16x8 bv = *(const bf16x8*)(Bp + 1024 + l0);
        acc[0][0] = MFMA16(a0, b0, acc[0][0]);
        acc[0][1] = MFMA16(a0, bv, acc[0][1]);
        acc[1][0] = MFMA16(a1, b0, acc[1][0]);
        acc[1][1] = MFMA16(a1, bv, acc[1][1]);
    }
    __shared__ unsigned short sm[64][72];
    #pragma unroll
    for (int mi = 0; mi < 2; ++mi)
        #pragma unroll
        for (int ni = 0; ni < 2; ++ni)
            #pragma unroll
            for (int r = 0; r < 4; ++r)
                sm[wm * 32 + mi * 16 + (lane >> 4) * 4 + r][wn * 32 + ni * 16 + row] =
                    f2bf(acc[mi][ni][r]);
    __syncthreads();
    const int er = tid >> 2, c = (tid & 3) * 16;
    *(ushort8*)&y[(size_t)e * GL_ + er * 64 + c]     = *(ushort8*)&sm[er][c];
    *(ushort8*)&y[(size_t)e * GL_ + er * 64 + c + 8] = *(ushort8*)&sm[er][c + 8];
}

// ---- yT[bg][e_loc] <- y[e_loc][bg]  (bf16 transpose, chunk) ----------------
__global__ __launch_bounds__(256)
void k_tr(const unsigned short* __restrict__ y, unsigned short* __restrict__ yT, int ec)
{
    const int c0 = blockIdx.x * 64;
    const int r0 = blockIdx.y * 64;
    __shared__ unsigned int sm[64][65];
    const int cl = threadIdx.x & 63;
    for (int rr = threadIdx.x >> 6; rr < 64; rr += 4)
        sm[cl][rr] = y[(size_t)(r0 + rr) * GL_ + c0 + cl];
    __syncthreads();
    const int cw = threadIdx.x >> 2, j0 = (threadIdx.x & 3) * 16;
    unsigned short tmp[16];
    #pragma unroll
    for (int j = 0; j < 16; ++j) tmp[j] = (unsigned short)sm[cw][j0 + j];
    *(ushort8*)&yT[(size_t)(c0 + cw) * ec + r0 + j0]     = *(ushort8*)&tmp[0];
    *(ushort8*)&yT[(size_t)(c0 + cw) * ec + r0 + j0 + 8] = *(ushort8*)&tmp[8];
}

__global__ __launch_bounds__(256)
void k_final(const float* __restrict__ acc, const float* __restrict__ bgc,
             float* __restrict__ out)
{
    const int i = blockIdx.x * 256 + threadIdx.x;
    if (i < ACC_ELEMS) out[i] = fmaxf(acc[i] + bgc[i & 63], 0.f);
}

extern "C" void kernel_launch(void* const* d_in, const int* in_sizes, int n_in,
                              void* d_out, int out_size, void* d_ws, size_t ws_size,
                              hipStream_t stream) {
    const float* x   = (const float*)d_in[0];
    const float* inc = (const float*)d_in[1];
    const float* ef  = (const float*)d_in[2];
    const float* W1  = (const float*)d_in[3];
    const float* b1  = (const float*)d_in[4];
    const float* W2  = (const float*)d_in[5];
    const float* b2  = (const float*)d_in[6];
    const float* bgc = (const float*)d_in[7];
    float* out = (float*)d_out;

    float* accw = (float*)d_ws;
    unsigned short* incB = (unsigned short*)((char*)d_ws + ACC_BYTES);
    unsigned short* incT = incB + (size_t)NP_ * E_;
    unsigned short* xT   = incT + (size_t)E_ * NP_;
    unsigned short* h    = xT   + (size_t)B_ * L_ * NP_;
    unsigned short* W2T  = h    + (size_t)E_ * H_;
    unsigned short* chunk = W2T + (size_t)GL_ * H_;
    const size_t persistBytes = (char*)chunk - (char*)d_ws;   // ~50.3 MB

    const size_t perEdge = 3 * (size_t)GL_ * 2;               // 24576 B
    const size_t avail = ws_size > persistBytes ? ws_size - persistBytes : 0;
    int Ec = (int)((avail / perEdge / 128) * 128);
    if (Ec > E_) Ec = E_;
    if (Ec < 128) Ec = 128;

    unsigned short* Kc = chunk;                       // [Ec][4096]; later yT
    unsigned short* tc = Kc + (size_t)Ec * GL_;       // [Ec][4096]
    unsigned short* yc = tc + (size_t)Ec * GL_;       // [Ec][4096]

    k_zero<<<dim3((ACC_ELEMS + 255) / 256), 256, 0, stream>>>(accw);
    k_cvt_incB<<<dim3(16, NP_), 256, 0, stream>>>(inc, incB);
    k_tr32<<<dim3(E_ / 64, NP_ / 64, 1), 256, 0, stream>>>(inc, incT, N_, E_, NP_, 0, 0);
    k_tr32<<<dim3(1, NP_ / 64, B_),      256, 0, stream>>>(x, xT, N_, L_, NP_,
                                                           (size_t)N_ * L_, (size_t)L_ * NP_);
    k_tr32<<<dim3(GL_ / 64, H_ / 64, 1), 256, 0, stream>>>(W2, W2T, H_, GL_, H_, 0, 0);
    k_h<<<dim3(E_ * H_ / 256), 256, 0, stream>>>(ef, W1, b1, h);

    for (int e_off = 0; e_off < E_; e_off += Ec) {
        const int ec = (E_ - e_off) < Ec ? (E_ - e_off) : Ec;   // multiple of 128
        // K-kernel: [ec][4096] = h_chunk @ W2T^T + b2
        gemm128<1><<<dim3((ec / 128) * 32), 256, 0, stream>>>(
            h + (size_t)e_off * H_, H_, W2T, H_, H_, 32, Kc, GL_, b2, nullptr);
        // t: [ec][4096] = incT_chunk @ xT^T
        gemm128<0><<<dim3((ec / 128) * 32), 256, 0, stream>>>(
            incT + (size_t)e_off * NP_, NP_, xT, NP_, NP_, 32, tc, GL_, nullptr, nullptr);
        // y per edge
        k_y<<<dim3(ec), 256, 0, stream>>>(tc, Kc, yc);
        // yT over K buffer
        k_tr<<<dim3(GL_ / 64, ec / 64), 256, 0, stream>>>(yc, Kc, ec);
        // acc += incB_chunk @ yT^T  (K-split for occupancy)
        const int ks = (ec % 256 == 0) ? 4 : 2;
        gemm128<2><<<dim3((NP_ / 128) * 32, ks), 256, 0, stream>>>(
            incB + e_off, E_, Kc, ec, ec, 32, nullptr, 0, nullptr, accw);
    }

    k_final<<<dim3((ACC_ELEMS + 255) / 256), 256, 0, stream>>>(accw, bgc, out);
}

// Round 7
// 1051.829 us; speedup vs baseline: 3.4156x; 1.0357x over previous
//
#include <hip/hip_runtime.h>

constexpr int B_ = 64, N_ = 500, E_ = 16000, L_ = 64, G_ = 64, F_ = 8, H_ = 128;
constexpr int GL_ = 4096;     // G*L
constexpr int NP_ = 512;      // n padded
constexpr int KS_ = 2;        // K-split planes per chunk
constexpr int ACC_ELEMS = B_ * N_ * G_;               // 2,048,000 fp32

using bf16x8  = __attribute__((ext_vector_type(8))) short;
using f32x4   = __attribute__((ext_vector_type(4))) float;
using ushort8 = __attribute__((ext_vector_type(8))) unsigned short;

#define MFMA16(a, b, c) __builtin_amdgcn_mfma_f32_16x16x32_bf16((a), (b), (c), 0, 0, 0)

static __device__ __forceinline__ unsigned short f2bf(float f) {
    union { float f; unsigned u; } v; v.f = f;
    unsigned r = v.u + 0x7fffu + ((v.u >> 16) & 1u);
    return (unsigned short)(r >> 16);
}

// ======================= unified 128x128 MFMA GEMM ==========================
// C[M][N] = A[M][K] (row-major, lda) @ Bm[N][K]^T (row-major, ldb)
// MODE 0: store bf16 C (ldc). MODE 1: +bias[col], store bf16.
// MODE 2: plain fp32 stores of partials into plane[pbase+blockIdx.y]
//         (col=(b*64+g), row=n, guard n<N_; K-split across blockIdx.y).
template<int MODE>
__global__ __launch_bounds__(256)
void gemm128(const unsigned short* __restrict__ A, int lda,
             const unsigned short* __restrict__ Bm, int ldb,
             int K, int nN,
             unsigned short* __restrict__ C, int ldc,
             const float* __restrict__ bias, float* __restrict__ planes, int pbase)
{
    const int nwg = gridDim.x;
    const int bid = blockIdx.x;
    const int swz = (nwg & 7) ? bid : ((bid & 7) * (nwg >> 3) + (bid >> 3));
    const int m0 = (swz / nN) * 128, n0 = (swz % nN) * 128;

    int kbeg = 0, kend = K;
    if (MODE == 2) {
        const int kl = K / gridDim.y;      // caller guarantees kl % 64 == 0
        kbeg = blockIdx.y * kl;
        kend = kbeg + kl;
    }

    const int tid  = threadIdx.x;
    const int srow = tid >> 3;             // 0..31
    const int soff = (tid & 7) * 8;        // 8 ushorts = 16B
    const int lane = tid & 63, wid = tid >> 6;
    const int wm = wid >> 1, wn = wid & 1;
    const int fr = lane & 15, fq = lane >> 4;

    __shared__ __align__(16) unsigned short sm[2][128][72];
    auto As = sm[0];
    auto Bs = sm[1];

    uint4 ra[4], rb[4];
    const int nk = (kend - kbeg) / 64;
    #pragma unroll
    for (int i = 0; i < 4; ++i) {
        ra[i] = *(const uint4*)&A[(size_t)(m0 + i * 32 + srow) * lda + kbeg + soff];
        rb[i] = *(const uint4*)&Bm[(size_t)(n0 + i * 32 + srow) * ldb + kbeg + soff];
    }
    const f32x4 fz = {0.f, 0.f, 0.f, 0.f};
    f32x4 acc[4][4] = {{fz, fz, fz, fz}, {fz, fz, fz, fz},
                       {fz, fz, fz, fz}, {fz, fz, fz, fz}};

    for (int kt = 0; kt < nk; ++kt) {
        #pragma unroll
        for (int i = 0; i < 4; ++i) {
            *(uint4*)&As[i * 32 + srow][soff] = ra[i];
            *(uint4*)&Bs[i * 32 + srow][soff] = rb[i];
        }
        __syncthreads();
        if (kt + 1 < nk) {
            const int kk = kbeg + (kt + 1) * 64;
            #pragma unroll
            for (int i = 0; i < 4; ++i) {
                ra[i] = *(const uint4*)&A[(size_t)(m0 + i * 32 + srow) * lda + kk + soff];
                rb[i] = *(const uint4*)&Bm[(size_t)(n0 + i * 32 + srow) * ldb + kk + soff];
            }
        }
        #pragma unroll
        for (int ks = 0; ks < 2; ++ks) {
            bf16x8 af[4], bf[4];
            #pragma unroll
            for (int i = 0; i < 4; ++i)
                af[i] = *(const bf16x8*)&As[wm * 64 + i * 16 + fr][ks * 32 + fq * 8];
            #pragma unroll
            for (int j = 0; j < 4; ++j)
                bf[j] = *(const bf16x8*)&Bs[wn * 64 + j * 16 + fr][ks * 32 + fq * 8];
            #pragma unroll
            for (int i = 0; i < 4; ++i)
                #pragma unroll
                for (int j = 0; j < 4; ++j)
                    acc[i][j] = MFMA16(af[i], bf[j], acc[i][j]);
        }
        __syncthreads();
    }

    if constexpr (MODE == 2) {
        float* pl = planes + (size_t)(pbase + blockIdx.y) * ACC_ELEMS;
        #pragma unroll
        for (int i = 0; i < 4; ++i)
            #pragma unroll
            for (int j = 0; j < 4; ++j) {
                const int col = n0 + wn * 64 + j * 16 + fr;
                const int b = col >> 6, g = col & 63;
                #pragma unroll
                for (int r = 0; r < 4; ++r) {
                    const int n = m0 + wm * 64 + i * 16 + fq * 4 + r;
                    if (n < N_)
                        pl[((size_t)b * N_ + n) * G_ + g] = acc[i][j][r];
                }
            }
    } else {
        auto Cs = (unsigned short(*)[128])&sm[0][0][0];
        #pragma unroll
        for (int i = 0; i < 4; ++i)
            #pragma unroll
            for (int j = 0; j < 4; ++j) {
                float bv = 0.f;
                if constexpr (MODE == 1) bv = bias[n0 + wn * 64 + j * 16 + fr];
                #pragma unroll
                for (int r = 0; r < 4; ++r)
                    Cs[wm * 64 + i * 16 + fq * 4 + r][wn * 64 + j * 16 + fr] =
                        f2bf(acc[i][j][r] + bv);
            }
        __syncthreads();
        const int r2 = tid >> 4, o2 = (tid & 15) * 8;
        #pragma unroll
        for (int i = 0; i < 8; ++i) {
            const int row = i * 16 + r2;
            *(uint4*)&C[(size_t)(m0 + row) * ldc + n0 + o2] = *(const uint4*)&Cs[row][o2];
        }
    }
}

// ======================= prologue / small kernels ===========================
__global__ __launch_bounds__(256)
void k_cvt_incB(const float* __restrict__ inc, unsigned short* __restrict__ incB)
{
    const int n = blockIdx.y;
    const int c = blockIdx.x * 1024 + threadIdx.x * 4;
    if (c >= E_) return;
    ushort4 u;
    if (n < N_) {
        const float4 v = *(const float4*)&inc[(size_t)n * E_ + c];
        u.x = f2bf(v.x); u.y = f2bf(v.y); u.z = f2bf(v.z); u.w = f2bf(v.w);
    } else { u.x = 0; u.y = 0; u.z = 0; u.w = 0; }
    *(ushort4*)&incB[(size_t)n * E_ + c] = u;
}

__global__ __launch_bounds__(256)
void k_tr32(const float* __restrict__ in, unsigned short* __restrict__ out,
            int R, int C, int Rp, size_t inZ, size_t outZ)
{
    in  += (size_t)blockIdx.z * inZ;
    out += (size_t)blockIdx.z * outZ;
    const int c0 = blockIdx.x * 64, r0 = blockIdx.y * 64;
    __shared__ float sm[64][65];
    const int cl = threadIdx.x & 63;
    for (int rr = threadIdx.x >> 6; rr < 64; rr += 4) {
        const int r = r0 + rr;
        sm[cl][rr] = (r < R) ? in[(size_t)r * C + c0 + cl] : 0.f;
    }
    __syncthreads();
    const int cw = threadIdx.x >> 2, j0 = (threadIdx.x & 3) * 16;
    unsigned short tmp[16];
    #pragma unroll
    for (int j = 0; j < 16; ++j) tmp[j] = f2bf(sm[cw][j0 + j]);
    *(ushort8*)&out[(size_t)(c0 + cw) * Rp + r0 + j0]     = *(ushort8*)&tmp[0];
    *(ushort8*)&out[(size_t)(c0 + cw) * Rp + r0 + j0 + 8] = *(ushort8*)&tmp[8];
}

__global__ __launch_bounds__(256)
void k_h(const float* __restrict__ ef, const float* __restrict__ W1,
         const float* __restrict__ b1, unsigned short* __restrict__ h)
{
    const int idx = blockIdx.x * 256 + threadIdx.x;
    const int e = idx >> 7, hh = idx & 127;
    float v = b1[hh];
    const float* efp = &ef[(size_t)e * F_];
    #pragma unroll
    for (int f = 0; f < F_; ++f) v += efp[f] * W1[f * H_ + hh];
    h[idx] = f2bf(fmaxf(v, 0.f));
}

// ---- y[e_loc][b*64+g] = t[e] @ K[e]^T  (MFMA per edge) ---------------------
__global__ __launch_bounds__(256)
void k_y(const unsigned short* __restrict__ t, const unsigned short* __restrict__ Kc,
         unsigned short* __restrict__ y)
{
    const int e = blockIdx.x;
    const int tid = threadIdx.x, lane = tid & 63, wid = tid >> 6;
    const int wm = wid >> 1, wn = wid & 1;
    const int row = lane & 15, koff = (lane >> 4) * 8;
    const unsigned short* A  = &t[(size_t)e * GL_ + (wm * 32 + row) * 64 + koff];
    const unsigned short* Bp = &Kc[(size_t)e * GL_ + (wn * 32 + row) * 64 + koff];
    const f32x4 fz = {0.f, 0.f, 0.f, 0.f};
    f32x4 acc[2][2] = {{fz, fz}, {fz, fz}};
    #pragma unroll
    for (int l0 = 0; l0 < 64; l0 += 32) {
        const bf16x8 a0 = *(const bf16x8*)(A + l0);
        const bf16x8 a1 = *(const bf16x8*)(A + 1024 + l0);
        const bf16x8 b0 = *(const bf16x8*)(Bp + l0);
        const bf16x8 bv = *(const bf16x8*)(Bp + 1024 + l0);
        acc[0][0] = MFMA16(a0, b0, acc[0][0]);
        acc[0][1] = MFMA16(a0, bv, acc[0][1]);
        acc[1][0] = MFMA16(a1, b0, acc[1][0]);
        acc[1][1] = MFMA16(a1, bv, acc[1][1]);
    }
    __shared__ unsigned short sm[64][72];
    #pragma unroll
    for (int mi = 0; mi < 2; ++mi)
        #pragma unroll
        for (int ni = 0; ni < 2; ++ni)
            #pragma unroll
            for (int r = 0; r < 4; ++r)
                sm[wm * 32 + mi * 16 + (lane >> 4) * 4 + r][wn * 32 + ni * 16 + row] =
                    f2bf(acc[mi][ni][r]);
    __syncthreads();
    const int er = tid >> 2, c = (tid & 3) * 16;
    *(ushort8*)&y[(size_t)e * GL_ + er * 64 + c]     = *(ushort8*)&sm[er][c];
    *(ushort8*)&y[(size_t)e * GL_ + er * 64 + c + 8] = *(ushort8*)&sm[er][c + 8];
}

// ---- yT[bg][e_loc] <- y[e_loc][bg]  (bf16 transpose, chunk) ----------------
__global__ __launch_bounds__(256)
void k_tr(const unsigned short* __restrict__ y, unsigned short* __restrict__ yT, int ec)
{
    const int c0 = blockIdx.x * 64;
    const int r0 = blockIdx.y * 64;
    __shared__ unsigned int sm[64][65];
    const int cl = threadIdx.x & 63;
    for (int rr = threadIdx.x >> 6; rr < 64; rr += 4)
        sm[cl][rr] = y[(size_t)(r0 + rr) * GL_ + c0 + cl];
    __syncthreads();
    const int cw = threadIdx.x >> 2, j0 = (threadIdx.x & 3) * 16;
    unsigned short tmp[16];
    #pragma unroll
    for (int j = 0; j < 16; ++j) tmp[j] = (unsigned short)sm[cw][j0 + j];
    *(ushort8*)&yT[(size_t)(c0 + cw) * ec + r0 + j0]     = *(ushort8*)&tmp[0];
    *(ushort8*)&yT[(size_t)(c0 + cw) * ec + r0 + j0 + 8] = *(ushort8*)&tmp[8];
}

// ---- final: out = relu(sum_p planes[p] + bgc), single write of d_out -------
__global__ __launch_bounds__(256)
void k_final(const float* __restrict__ planes, int P,
             const float* __restrict__ bgc, float* __restrict__ out)
{
    const int i = blockIdx.x * 256 + threadIdx.x;
    if (i >= ACC_ELEMS) return;
    float s = bgc[i & 63];
    for (int p = 0; p < P; ++p) s += planes[(size_t)p * ACC_ELEMS + i];
    out[i] = fmaxf(s, 0.f);
}

extern "C" void kernel_launch(void* const* d_in, const int* in_sizes, int n_in,
                              void* d_out, int out_size, void* d_ws, size_t ws_size,
                              hipStream_t stream) {
    const float* x   = (const float*)d_in[0];
    const float* inc = (const float*)d_in[1];
    const float* ef  = (const float*)d_in[2];
    const float* W1  = (const float*)d_in[3];
    const float* b1  = (const float*)d_in[4];
    const float* W2  = (const float*)d_in[5];
    const float* b2  = (const float*)d_in[6];
    const float* bgc = (const float*)d_in[7];
    float* out = (float*)d_out;

    // persistent bf16 operands
    const size_t persistU16 = (size_t)NP_ * E_      // incB
                            + (size_t)E_ * NP_      // incT
                            + (size_t)B_ * L_ * NP_ // xT
                            + (size_t)E_ * H_       // h
                            + (size_t)GL_ * H_;     // W2T
    const size_t persistBytes = persistU16 * 2;     // ~41.9 MB

    // pick smallest chunk count nc such that planes + chunk buffers fit
    int nc = 1, Ec = E_;
    for (; nc <= 16; ++nc) {
        Ec = ((E_ + nc - 1) / nc + 127) / 128 * 128;
        const size_t need = persistBytes
                          + (size_t)nc * KS_ * ACC_ELEMS * 4     // planes
                          + 3 * (size_t)Ec * GL_ * 2;            // K,t,y chunk
        if (need <= ws_size) break;
    }
    if (nc > 16) { nc = 16; Ec = 1024; }   // last-resort (shouldn't happen)

    float* planes = (float*)d_ws;
    unsigned short* incB = (unsigned short*)(planes + (size_t)nc * KS_ * ACC_ELEMS);
    unsigned short* incT = incB + (size_t)NP_ * E_;
    unsigned short* xT   = incT + (size_t)E_ * NP_;
    unsigned short* h    = xT   + (size_t)B_ * L_ * NP_;
    unsigned short* W2T  = h    + (size_t)E_ * H_;
    unsigned short* Kc   = W2T  + (size_t)GL_ * H_;    // [Ec][4096]; later yT
    unsigned short* tc   = Kc   + (size_t)Ec * GL_;    // [Ec][4096]
    unsigned short* yc   = tc   + (size_t)Ec * GL_;    // [Ec][4096]

    k_cvt_incB<<<dim3(16, NP_), 256, 0, stream>>>(inc, incB);
    k_tr32<<<dim3(E_ / 64, NP_ / 64, 1), 256, 0, stream>>>(inc, incT, N_, E_, NP_, 0, 0);
    k_tr32<<<dim3(1, NP_ / 64, B_),      256, 0, stream>>>(x, xT, N_, L_, NP_,
                                                           (size_t)N_ * L_, (size_t)L_ * NP_);
    k_tr32<<<dim3(GL_ / 64, H_ / 64, 1), 256, 0, stream>>>(W2, W2T, H_, GL_, H_, 0, 0);
    k_h<<<dim3(E_ * H_ / 256), 256, 0, stream>>>(ef, W1, b1, h);

    int cidx = 0;
    for (int e_off = 0; e_off < E_; e_off += Ec, ++cidx) {
        const int ec = (E_ - e_off) < Ec ? (E_ - e_off) : Ec;   // multiple of 128
        // K-kernel: [ec][4096] = h_chunk @ W2T^T + b2
        gemm128<1><<<dim3((ec / 128) * 32), 256, 0, stream>>>(
            h + (size_t)e_off * H_, H_, W2T, H_, H_, 32, Kc, GL_, b2, nullptr, 0);
        // t: [ec][4096] = incT_chunk @ xT^T
        gemm128<0><<<dim3((ec / 128) * 32), 256, 0, stream>>>(
            incT + (size_t)e_off * NP_, NP_, xT, NP_, NP_, 32, tc, GL_, nullptr, nullptr, 0);
        // y per edge
        k_y<<<dim3(ec), 256, 0, stream>>>(tc, Kc, yc);
        // yT over K buffer
        k_tr<<<dim3(GL_ / 64, ec / 64), 256, 0, stream>>>(yc, Kc, ec);
        // planes[cidx*KS_+ky] = incB_chunk @ yT^T (K-split)
        gemm128<2><<<dim3((NP_ / 128) * 32, KS_), 256, 0, stream>>>(
            incB + e_off, E_, Kc, ec, ec, 32, nullptr, 0, nullptr, planes, cidx * KS_);
    }

    k_final<<<dim3((ACC_ELEMS + 255) / 256), 256, 0, stream>>>(planes, nc * KS_, bgc, out);
}

// Round 8
// 988.003 us; speedup vs baseline: 3.6362x; 1.0646x over previous
//
#include <hip/hip_runtime.h>

constexpr int B_ = 64, N_ = 500, E_ = 16000, L_ = 64, G_ = 64, F_ = 8, H_ = 128;
constexpr int GL_ = 4096;     // G*L
constexpr int NP_ = 512;      // n padded
constexpr int KS_ = 4;        // K-split planes per chunk
constexpr int ACC_ELEMS = B_ * N_ * G_;               // 2,048,000

using bf16x8  = __attribute__((ext_vector_type(8))) short;
using f32x4   = __attribute__((ext_vector_type(4))) float;
using ushort8 = __attribute__((ext_vector_type(8))) unsigned short;

#define MFMA16(a, b, c) __builtin_amdgcn_mfma_f32_16x16x32_bf16((a), (b), (c), 0, 0, 0)

static __device__ __forceinline__ unsigned short f2bf(float f) {
    union { float f; unsigned u; } v; v.f = f;
    unsigned r = v.u + 0x7fffu + ((v.u >> 16) & 1u);
    return (unsigned short)(r >> 16);
}
static __device__ __forceinline__ float bf2f(unsigned short s) {
    union { float f; unsigned u; } v; v.u = ((unsigned)s) << 16;
    return v.f;
}

// ======================= unified 128x128 MFMA GEMM ==========================
// C[M][N] = A[M][K] (row-major, lda) @ Bm[N][K]^T (row-major, ldb)
// MODE 0: store bf16 C (ldc). MODE 1: +bias[col], store bf16.
// MODE 2: bf16 partial-sum stores into plane[pbase+blockIdx.y]
//         (col=(b*64+g), row=n, guard n<N_; variable K-split; XCD mapping).
template<int MODE>
__global__ __launch_bounds__(256)
void gemm128(const unsigned short* __restrict__ A, int lda,
             const unsigned short* __restrict__ Bm, int ldb,
             int K, int nN,
             unsigned short* __restrict__ C, int ldc,
             const float* __restrict__ bias,
             unsigned short* __restrict__ planesB, int pbase)
{
    int m0, n0, kbeg, kend;
    if (MODE == 2) {
        // grid.x = 128 (4 m-tiles x 32 n-tiles). Same-n m-tiles adjacent per XCD.
        const int xcd = blockIdx.x & 7, grp = blockIdx.x >> 3;   // grp 0..15
        m0 = (grp & 3) * 128;
        n0 = (xcd + 8 * (grp >> 2)) * 128;
        const int KSY = gridDim.y;
        const int kl = ((K / KSY) / 64) * 64;
        kbeg = blockIdx.y * kl;
        kend = ((int)blockIdx.y == KSY - 1) ? K : kbeg + kl;
    } else {
        const int nwg = gridDim.x;
        const int bid = blockIdx.x;
        const int swz = (nwg & 7) ? bid : ((bid & 7) * (nwg >> 3) + (bid >> 3));
        m0 = (swz / nN) * 128; n0 = (swz % nN) * 128;
        kbeg = 0; kend = K;
    }

    const int tid  = threadIdx.x;
    const int srow = tid >> 3;             // 0..31
    const int soff = (tid & 7) * 8;        // 8 ushorts = 16B
    const int lane = tid & 63, wid = tid >> 6;
    const int wm = wid >> 1, wn = wid & 1;
    const int fr = lane & 15, fq = lane >> 4;

    __shared__ __align__(16) unsigned short sm[2][128][72];
    auto As = sm[0];
    auto Bs = sm[1];

    uint4 ra[4], rb[4];
    const int nk = (kend - kbeg) / 64;
    #pragma unroll
    for (int i = 0; i < 4; ++i) {
        ra[i] = *(const uint4*)&A[(size_t)(m0 + i * 32 + srow) * lda + kbeg + soff];
        rb[i] = *(const uint4*)&Bm[(size_t)(n0 + i * 32 + srow) * ldb + kbeg + soff];
    }
    const f32x4 fz = {0.f, 0.f, 0.f, 0.f};
    f32x4 acc[4][4] = {{fz, fz, fz, fz}, {fz, fz, fz, fz},
                       {fz, fz, fz, fz}, {fz, fz, fz, fz}};

    for (int kt = 0; kt < nk; ++kt) {
        #pragma unroll
        for (int i = 0; i < 4; ++i) {
            *(uint4*)&As[i * 32 + srow][soff] = ra[i];
            *(uint4*)&Bs[i * 32 + srow][soff] = rb[i];
        }
        __syncthreads();
        if (kt + 1 < nk) {
            const int kk = kbeg + (kt + 1) * 64;
            #pragma unroll
            for (int i = 0; i < 4; ++i) {
                ra[i] = *(const uint4*)&A[(size_t)(m0 + i * 32 + srow) * lda + kk + soff];
                rb[i] = *(const uint4*)&Bm[(size_t)(n0 + i * 32 + srow) * ldb + kk + soff];
            }
        }
        #pragma unroll
        for (int ks = 0; ks < 2; ++ks) {
            bf16x8 af[4], bf[4];
            #pragma unroll
            for (int i = 0; i < 4; ++i)
                af[i] = *(const bf16x8*)&As[wm * 64 + i * 16 + fr][ks * 32 + fq * 8];
            #pragma unroll
            for (int j = 0; j < 4; ++j)
                bf[j] = *(const bf16x8*)&Bs[wn * 64 + j * 16 + fr][ks * 32 + fq * 8];
            #pragma unroll
            for (int i = 0; i < 4; ++i)
                #pragma unroll
                for (int j = 0; j < 4; ++j)
                    acc[i][j] = MFMA16(af[i], bf[j], acc[i][j]);
        }
        __syncthreads();
    }

    if constexpr (MODE == 2) {
        unsigned short* pl = planesB + (size_t)(pbase + blockIdx.y) * ACC_ELEMS;
        #pragma unroll
        for (int i = 0; i < 4; ++i)
            #pragma unroll
            for (int j = 0; j < 4; ++j) {
                const int col = n0 + wn * 64 + j * 16 + fr;
                const int b = col >> 6, g = col & 63;
                #pragma unroll
                for (int r = 0; r < 4; ++r) {
                    const int n = m0 + wm * 64 + i * 16 + fq * 4 + r;
                    if (n < N_)
                        pl[((size_t)b * N_ + n) * G_ + g] = f2bf(acc[i][j][r]);
                }
            }
    } else {
        auto Cs = (unsigned short(*)[128])&sm[0][0][0];
        #pragma unroll
        for (int i = 0; i < 4; ++i)
            #pragma unroll
            for (int j = 0; j < 4; ++j) {
                float bv = 0.f;
                if constexpr (MODE == 1) bv = bias[n0 + wn * 64 + j * 16 + fr];
                #pragma unroll
                for (int r = 0; r < 4; ++r)
                    Cs[wm * 64 + i * 16 + fq * 4 + r][wn * 64 + j * 16 + fr] =
                        f2bf(acc[i][j][r] + bv);
            }
        __syncthreads();
        const int r2 = tid >> 4, o2 = (tid & 15) * 8;
        #pragma unroll
        for (int i = 0; i < 8; ++i) {
            const int row = i * 16 + r2;
            *(uint4*)&C[(size_t)(m0 + row) * ldc + n0 + o2] = *(const uint4*)&Cs[row][o2];
        }
    }
}

// ======================= prologue / small kernels ===========================
__global__ __launch_bounds__(256)
void k_cvt_incB(const float* __restrict__ inc, unsigned short* __restrict__ incB)
{
    const int n = blockIdx.y;
    const int c = blockIdx.x * 1024 + threadIdx.x * 4;
    if (c >= E_) return;
    ushort4 u;
    if (n < N_) {
        const float4 v = *(const float4*)&inc[(size_t)n * E_ + c];
        u.x = f2bf(v.x); u.y = f2bf(v.y); u.z = f2bf(v.z); u.w = f2bf(v.w);
    } else { u.x = 0; u.y = 0; u.z = 0; u.w = 0; }
    *(ushort4*)&incB[(size_t)n * E_ + c] = u;
}

__global__ __launch_bounds__(256)
void k_tr32(const float* __restrict__ in, unsigned short* __restrict__ out,
            int R, int C, int Rp, size_t inZ, size_t outZ)
{
    in  += (size_t)blockIdx.z * inZ;
    out += (size_t)blockIdx.z * outZ;
    const int c0 = blockIdx.x * 64, r0 = blockIdx.y * 64;
    __shared__ float sm[64][65];
    const int cl = threadIdx.x & 63;
    for (int rr = threadIdx.x >> 6; rr < 64; rr += 4) {
        const int r = r0 + rr;
        sm[cl][rr] = (r < R) ? in[(size_t)r * C + c0 + cl] : 0.f;
    }
    __syncthreads();
    const int cw = threadIdx.x >> 2, j0 = (threadIdx.x & 3) * 16;
    unsigned short tmp[16];
    #pragma unroll
    for (int j = 0; j < 16; ++j) tmp[j] = f2bf(sm[cw][j0 + j]);
    *(ushort8*)&out[(size_t)(c0 + cw) * Rp + r0 + j0]     = *(ushort8*)&tmp[0];
    *(ushort8*)&out[(size_t)(c0 + cw) * Rp + r0 + j0 + 8] = *(ushort8*)&tmp[8];
}

__global__ __launch_bounds__(256)
void k_h(const float* __restrict__ ef, const float* __restrict__ W1,
         const float* __restrict__ b1, unsigned short* __restrict__ h)
{
    const int idx = blockIdx.x * 256 + threadIdx.x;
    const int e = idx >> 7, hh = idx & 127;
    float v = b1[hh];
    const float* efp = &ef[(size_t)e * F_];
    #pragma unroll
    for (int f = 0; f < F_; ++f) v += efp[f] * W1[f * H_ + hh];
    h[idx] = f2bf(fmaxf(v, 0.f));
}

// ---- y[e][bg] = t[e] @ K[e]^T, written IN PLACE over t[e] ------------------
__global__ __launch_bounds__(256)
void k_y(unsigned short* t, const unsigned short* __restrict__ Kc)
{
    const int e = blockIdx.x;
    const int tid = threadIdx.x, lane = tid & 63, wid = tid >> 6;
    const int wm = wid >> 1, wn = wid & 1;
    const int row = lane & 15, koff = (lane >> 4) * 8;
    const unsigned short* A  = &t[(size_t)e * GL_ + (wm * 32 + row) * 64 + koff];
    const unsigned short* Bp = &Kc[(size_t)e * GL_ + (wn * 32 + row) * 64 + koff];
    const f32x4 fz = {0.f, 0.f, 0.f, 0.f};
    f32x4 acc[2][2] = {{fz, fz}, {fz, fz}};
    #pragma unroll
    for (int l0 = 0; l0 < 64; l0 += 32) {
        const bf16x8 a0 = *(const bf16x8*)(A + l0);
        const bf16x8 a1 = *(const bf16x8*)(A + 1024 + l0);
        const bf16x8 b0 = *(const bf16x8*)(Bp + l0);
        const bf16x8 bv = *(const bf16x8*)(Bp + 1024 + l0);
        acc[0][0] = MFMA16(a0, b0, acc[0][0]);
        acc[0][1] = MFMA16(a0, bv, acc[0][1]);
        acc[1][0] = MFMA16(a1, b0, acc[1][0]);
        acc[1][1] = MFMA16(a1, bv, acc[1][1]);
    }
    __shared__ unsigned short sm[64][72];
    #pragma unroll
    for (int mi = 0; mi < 2; ++mi)
        #pragma unroll
        for (int ni = 0; ni < 2; ++ni)
            #pragma unroll
            for (int r = 0; r < 4; ++r)
                sm[wm * 32 + mi * 16 + (lane >> 4) * 4 + r][wn * 32 + ni * 16 + row] =
                    f2bf(acc[mi][ni][r]);
    __syncthreads();   // all reads of t[e] complete before overwrite
    const int er = tid >> 2, c = (tid & 3) * 16;
    *(ushort8*)&t[(size_t)e * GL_ + er * 64 + c]     = *(ushort8*)&sm[er][c];
    *(ushort8*)&t[(size_t)e * GL_ + er * 64 + c + 8] = *(ushort8*)&sm[er][c + 8];
}

// ---- yT[bg][e_loc] <- y[e_loc][bg]  (bf16 transpose, chunk) ----------------
__global__ __launch_bounds__(256)
void k_tr(const unsigned short* __restrict__ y, unsigned short* __restrict__ yT, int ec)
{
    const int c0 = blockIdx.x * 64;
    const int r0 = blockIdx.y * 64;
    __shared__ unsigned int sm[64][65];
    const int cl = threadIdx.x & 63;
    for (int rr = threadIdx.x >> 6; rr < 64; rr += 4)
        sm[cl][rr] = y[(size_t)(r0 + rr) * GL_ + c0 + cl];
    __syncthreads();
    const int cw = threadIdx.x >> 2, j0 = (threadIdx.x & 3) * 16;
    unsigned short tmp[16];
    #pragma unroll
    for (int j = 0; j < 16; ++j) tmp[j] = (unsigned short)sm[cw][j0 + j];
    *(ushort8*)&yT[(size_t)(c0 + cw) * ec + r0 + j0]     = *(ushort8*)&tmp[0];
    *(ushort8*)&yT[(size_t)(c0 + cw) * ec + r0 + j0 + 8] = *(ushort8*)&tmp[8];
}

// ---- final: out = relu(sum_p bf16 planes[p] + bgc), single d_out write -----
__global__ __launch_bounds__(256)
void k_final(const unsigned short* __restrict__ planesB, int P,
             const float* __restrict__ bgc, float* __restrict__ out)
{
    const int i = (blockIdx.x * 256 + threadIdx.x) * 8;
    if (i >= ACC_ELEMS) return;
    float s[8];
    #pragma unroll
    for (int j = 0; j < 8; ++j) s[j] = bgc[(i + j) & 63];
    for (int p = 0; p < P; ++p) {
        const ushort8 v = *(const ushort8*)&planesB[(size_t)p * ACC_ELEMS + i];
        #pragma unroll
        for (int j = 0; j < 8; ++j) s[j] += bf2f((unsigned short)v[j]);
    }
    float4 o0, o1;
    o0.x = fmaxf(s[0], 0.f); o0.y = fmaxf(s[1], 0.f);
    o0.z = fmaxf(s[2], 0.f); o0.w = fmaxf(s[3], 0.f);
    o1.x = fmaxf(s[4], 0.f); o1.y = fmaxf(s[5], 0.f);
    o1.z = fmaxf(s[6], 0.f); o1.w = fmaxf(s[7], 0.f);
    *(float4*)&out[i]     = o0;
    *(float4*)&out[i + 4] = o1;
}

extern "C" void kernel_launch(void* const* d_in, const int* in_sizes, int n_in,
                              void* d_out, int out_size, void* d_ws, size_t ws_size,
                              hipStream_t stream) {
    const float* x   = (const float*)d_in[0];
    const float* inc = (const float*)d_in[1];
    const float* ef  = (const float*)d_in[2];
    const float* W1  = (const float*)d_in[3];
    const float* b1  = (const float*)d_in[4];
    const float* W2  = (const float*)d_in[5];
    const float* b2  = (const float*)d_in[6];
    const float* bgc = (const float*)d_in[7];
    float* out = (float*)d_out;

    const size_t persistU16 = (size_t)NP_ * E_      // incB
                            + (size_t)E_ * NP_      // incT
                            + (size_t)B_ * L_ * NP_ // xT
                            + (size_t)E_ * H_       // h
                            + (size_t)GL_ * H_;     // W2T
    const size_t persistBytes = persistU16 * 2;     // ~41.9 MB

    // smallest nc such that bf16 planes + 2 chunk buffers fit
    int nc = 1, Ec = E_;
    for (; nc <= 16; ++nc) {
        Ec = ((E_ + nc - 1) / nc + 127) / 128 * 128;
        const size_t need = persistBytes
                          + (size_t)nc * KS_ * ACC_ELEMS * 2     // bf16 planes
                          + 2 * (size_t)Ec * GL_ * 2;            // K + t chunk
        if (need <= ws_size) break;
    }
    if (nc > 16) { nc = 16; Ec = 1024; }

    unsigned short* planesB = (unsigned short*)d_ws;
    unsigned short* incB = planesB + (size_t)nc * KS_ * ACC_ELEMS;
    unsigned short* incT = incB + (size_t)NP_ * E_;
    unsigned short* xT   = incT + (size_t)E_ * NP_;
    unsigned short* h    = xT   + (size_t)B_ * L_ * NP_;
    unsigned short* W2T  = h    + (size_t)E_ * H_;
    unsigned short* Kc   = W2T  + (size_t)GL_ * H_;    // [Ec][4096]; later yT
    unsigned short* tc   = Kc   + (size_t)Ec * GL_;    // [Ec][4096]; later y

    k_cvt_incB<<<dim3(16, NP_), 256, 0, stream>>>(inc, incB);
    k_tr32<<<dim3(E_ / 64, NP_ / 64, 1), 256, 0, stream>>>(inc, incT, N_, E_, NP_, 0, 0);
    k_tr32<<<dim3(1, NP_ / 64, B_),      256, 0, stream>>>(x, xT, N_, L_, NP_,
                                                           (size_t)N_ * L_, (size_t)L_ * NP_);
    k_tr32<<<dim3(GL_ / 64, H_ / 64, 1), 256, 0, stream>>>(W2, W2T, H_, GL_, H_, 0, 0);
    k_h<<<dim3(E_ * H_ / 256), 256, 0, stream>>>(ef, W1, b1, h);

    int cidx = 0;
    for (int e_off = 0; e_off < E_; e_off += Ec, ++cidx) {
        const int ec = (E_ - e_off) < Ec ? (E_ - e_off) : Ec;   // multiple of 128
        gemm128<1><<<dim3((ec / 128) * 32), 256, 0, stream>>>(
            h + (size_t)e_off * H_, H_, W2T, H_, H_, 32, Kc, GL_, b2, nullptr, 0);
        gemm128<0><<<dim3((ec / 128) * 32), 256, 0, stream>>>(
            incT + (size_t)e_off * NP_, NP_, xT, NP_, NP_, 32, tc, GL_, nullptr, nullptr, 0);
        k_y<<<dim3(ec), 256, 0, stream>>>(tc, Kc);                  // y over t
        k_tr<<<dim3(GL_ / 64, ec / 64), 256, 0, stream>>>(tc, Kc, ec);  // yT over K
        gemm128<2><<<dim3(128, KS_), 256, 0, stream>>>(
            incB + e_off, E_, Kc, ec, ec, 32, nullptr, 0, nullptr, planesB, cidx * KS_);
    }

    k_final<<<dim3(ACC_ELEMS / 2048), 256, 0, stream>>>(planesB, nc * KS_, bgc, out);
}

// Round 9
// 737.042 us; speedup vs baseline: 4.8744x; 1.3405x over previous
//
#include <hip/hip_runtime.h>

constexpr int B_ = 64, N_ = 500, E_ = 16000, L_ = 64, G_ = 64, F_ = 8, H_ = 128;
constexpr int GL_ = 4096;     // G*L
constexpr int NP_ = 512;      // n padded
constexpr int KS_ = 4;        // K-split planes per chunk
constexpr int ACC_ELEMS = B_ * N_ * G_;               // 2,048,000

using bf16x8  = __attribute__((ext_vector_type(8))) short;
using f32x4   = __attribute__((ext_vector_type(4))) float;
using ushort8 = __attribute__((ext_vector_type(8))) unsigned short;

#define MFMA16(a, b, c) __builtin_amdgcn_mfma_f32_16x16x32_bf16((a), (b), (c), 0, 0, 0)

static __device__ __forceinline__ unsigned short f2bf(float f) {
    union { float f; unsigned u; } v; v.f = f;
    unsigned r = v.u + 0x7fffu + ((v.u >> 16) & 1u);
    return (unsigned short)(r >> 16);
}
static __device__ __forceinline__ float bf2f(unsigned short s) {
    union { float f; unsigned u; } v; v.u = ((unsigned)s) << 16;
    return v.f;
}

// ======================= 128x128 MFMA GEMM (modes 0/1) ======================
// C[M][N] = A[M][K] (row-major, lda) @ Bm[N][K]^T (row-major, ldb)
// MODE 0: store bf16 C. MODE 1: +bias[col], store bf16.
template<int MODE>
__global__ __launch_bounds__(256)
void gemm128(const unsigned short* __restrict__ A, int lda,
             const unsigned short* __restrict__ Bm, int ldb,
             int K, int nN,
             unsigned short* __restrict__ C, int ldc,
             const float* __restrict__ bias)
{
    const int nwg = gridDim.x;
    const int bid = blockIdx.x;
    const int swz = (nwg & 7) ? bid : ((bid & 7) * (nwg >> 3) + (bid >> 3));
    const int m0 = (swz / nN) * 128, n0 = (swz % nN) * 128;

    const int tid  = threadIdx.x;
    const int srow = tid >> 3;             // 0..31
    const int soff = (tid & 7) * 8;        // 8 ushorts = 16B
    const int lane = tid & 63, wid = tid >> 6;
    const int wm = wid >> 1, wn = wid & 1;
    const int fr = lane & 15, fq = lane >> 4;

    __shared__ __align__(16) unsigned short sm[2][128][72];
    auto As = sm[0];
    auto Bs = sm[1];

    uint4 ra[4], rb[4];
    const int nk = K / 64;
    #pragma unroll
    for (int i = 0; i < 4; ++i) {
        ra[i] = *(const uint4*)&A[(size_t)(m0 + i * 32 + srow) * lda + soff];
        rb[i] = *(const uint4*)&Bm[(size_t)(n0 + i * 32 + srow) * ldb + soff];
    }
    const f32x4 fz = {0.f, 0.f, 0.f, 0.f};
    f32x4 acc[4][4] = {{fz, fz, fz, fz}, {fz, fz, fz, fz},
                       {fz, fz, fz, fz}, {fz, fz, fz, fz}};

    for (int kt = 0; kt < nk; ++kt) {
        #pragma unroll
        for (int i = 0; i < 4; ++i) {
            *(uint4*)&As[i * 32 + srow][soff] = ra[i];
            *(uint4*)&Bs[i * 32 + srow][soff] = rb[i];
        }
        __syncthreads();
        if (kt + 1 < nk) {
            const int kk = (kt + 1) * 64;
            #pragma unroll
            for (int i = 0; i < 4; ++i) {
                ra[i] = *(const uint4*)&A[(size_t)(m0 + i * 32 + srow) * lda + kk + soff];
                rb[i] = *(const uint4*)&Bm[(size_t)(n0 + i * 32 + srow) * ldb + kk + soff];
            }
        }
        #pragma unroll
        for (int ks = 0; ks < 2; ++ks) {
            bf16x8 af[4], bf[4];
            #pragma unroll
            for (int i = 0; i < 4; ++i)
                af[i] = *(const bf16x8*)&As[wm * 64 + i * 16 + fr][ks * 32 + fq * 8];
            #pragma unroll
            for (int j = 0; j < 4; ++j)
                bf[j] = *(const bf16x8*)&Bs[wn * 64 + j * 16 + fr][ks * 32 + fq * 8];
            #pragma unroll
            for (int i = 0; i < 4; ++i)
                #pragma unroll
                for (int j = 0; j < 4; ++j)
                    acc[i][j] = MFMA16(af[i], bf[j], acc[i][j]);
        }
        __syncthreads();
    }

    auto Cs = (unsigned short(*)[128])&sm[0][0][0];
    #pragma unroll
    for (int i = 0; i < 4; ++i)
        #pragma unroll
        for (int j = 0; j < 4; ++j) {
            float bv = 0.f;
            if constexpr (MODE == 1) bv = bias[n0 + wn * 64 + j * 16 + fr];
            #pragma unroll
            for (int r = 0; r < 4; ++r)
                Cs[wm * 64 + i * 16 + fq * 4 + r][wn * 64 + j * 16 + fr] =
                    f2bf(acc[i][j][r] + bv);
        }
    __syncthreads();
    const int r2 = tid >> 4, o2 = (tid & 15) * 8;
    #pragma unroll
    for (int i = 0; i < 8; ++i) {
        const int row = i * 16 + r2;
        *(uint4*)&C[(size_t)(m0 + row) * ldc + n0 + o2] = *(const uint4*)&Cs[row][o2];
    }
}

// ---- k_y8: per block 8 edges; wave w computes y[e0+w] = t[e]@K[e]^T --------
// Output written IN PLACE over t as e-blocked tiles: [eb][bg 4096][8 e].
__global__ __launch_bounds__(512)
void k_y8(unsigned short* tc, const unsigned short* __restrict__ Kc)
{
    const int e0 = blockIdx.x * 8;
    const int tid = threadIdx.x, lane = tid & 63, w = tid >> 6;
    const int e = e0 + w;
    const int fr = lane & 15, fq = lane >> 4;
    const unsigned short* A  = &tc[(size_t)e * GL_];
    const unsigned short* Bp = &Kc[(size_t)e * GL_];
    const f32x4 fz = {0.f, 0.f, 0.f, 0.f};
    f32x4 acc[4][4] = {{fz, fz, fz, fz}, {fz, fz, fz, fz},
                       {fz, fz, fz, fz}, {fz, fz, fz, fz}};
    #pragma unroll
    for (int ks = 0; ks < 2; ++ks) {
        bf16x8 af[4], bf[4];
        #pragma unroll
        for (int i = 0; i < 4; ++i)
            af[i] = *(const bf16x8*)&A[(i * 16 + fr) * 64 + ks * 32 + fq * 8];
        #pragma unroll
        for (int j = 0; j < 4; ++j)
            bf[j] = *(const bf16x8*)&Bp[(j * 16 + fr) * 64 + ks * 32 + fq * 8];
        #pragma unroll
        for (int i = 0; i < 4; ++i)
            #pragma unroll
            for (int j = 0; j < 4; ++j)
                acc[i][j] = MFMA16(af[i], bf[j], acc[i][j]);
    }
    __shared__ unsigned short y8[GL_ * 8];   // 64KB, [bg][8]
    #pragma unroll
    for (int i = 0; i < 4; ++i)
        #pragma unroll
        for (int j = 0; j < 4; ++j)
            #pragma unroll
            for (int r = 0; r < 4; ++r) {
                const int bg = (i * 16 + fq * 4 + r) * 64 + j * 16 + fr;
                y8[bg * 8 + w] = f2bf(acc[i][j][r]);
            }
    __syncthreads();
    unsigned short* dst = tc + (size_t)e0 * GL_;   // same 64KB region
    #pragma unroll
    for (int p = 0; p < 8; ++p) {
        const int o = (p * 512 + tid) * 8;
        *(uint4*)&dst[o] = *(const uint4*)&y8[o];
    }
}

// ---- k_accd: planes[pbase+ky] = incB @ y8^T, direct loads, no LDS ----------
// A = incB rows n (k=e contiguous); B-frag = one uint4 of y8 tile.
__global__ __launch_bounds__(256)
void k_accd(const unsigned short* __restrict__ Ae,   // incB + e_off
            const unsigned short* __restrict__ y8,   // chunk tc base
            unsigned short* __restrict__ planesB, int pbase, int K)
{
    const int xcd = blockIdx.x & 7, grp = blockIdx.x >> 3;
    const int m0 = (grp & 3) * 128;
    const int n0 = (xcd + 8 * (grp >> 2)) * 128;
    const int KSY = gridDim.y;
    const int kl = ((K / KSY) / 64) * 64;
    const int kbeg = blockIdx.y * kl;
    const int kend = ((int)blockIdx.y == KSY - 1) ? K : kbeg + kl;

    const int lane = threadIdx.x & 63, wid = threadIdx.x >> 6;
    const int wm = wid >> 1, wn = wid & 1;
    const int fr = lane & 15, fq = lane >> 4;

    const f32x4 fz = {0.f, 0.f, 0.f, 0.f};
    f32x4 acc[4][4] = {{fz, fz, fz, fz}, {fz, fz, fz, fz},
                       {fz, fz, fz, fz}, {fz, fz, fz, fz}};

    for (int kk = kbeg; kk < kend; kk += 64) {
        #pragma unroll
        for (int ks = 0; ks < 2; ++ks) {
            const int e8 = kk + ks * 32 + fq * 8;
            const unsigned short* yb = &y8[(size_t)(e8 >> 3) * (GL_ * 8)];
            bf16x8 af[4], bf[4];
            #pragma unroll
            for (int i = 0; i < 4; ++i)
                af[i] = *(const bf16x8*)&Ae[(size_t)(m0 + wm * 64 + i * 16 + fr) * E_ + e8];
            #pragma unroll
            for (int j = 0; j < 4; ++j)
                bf[j] = *(const bf16x8*)&yb[(n0 + wn * 64 + j * 16 + fr) * 8];
            #pragma unroll
            for (int i = 0; i < 4; ++i)
                #pragma unroll
                for (int j = 0; j < 4; ++j)
                    acc[i][j] = MFMA16(af[i], bf[j], acc[i][j]);
        }
    }

    unsigned short* pl = planesB + (size_t)(pbase + blockIdx.y) * ACC_ELEMS;
    #pragma unroll
    for (int i = 0; i < 4; ++i)
        #pragma unroll
        for (int j = 0; j < 4; ++j) {
            const int col = n0 + wn * 64 + j * 16 + fr;
            const int b = col >> 6, g = col & 63;
            #pragma unroll
            for (int r = 0; r < 4; ++r) {
                const int n = m0 + wm * 64 + i * 16 + fq * 4 + r;
                if (n < N_)
                    pl[((size_t)b * N_ + n) * G_ + g] = f2bf(acc[i][j][r]);
            }
        }
}

// ======================= prologue / small kernels ===========================
__global__ __launch_bounds__(256)
void k_cvt_incB(const float* __restrict__ inc, unsigned short* __restrict__ incB)
{
    const int n = blockIdx.y;
    const int c = blockIdx.x * 1024 + threadIdx.x * 4;
    if (c >= E_) return;
    ushort4 u;
    if (n < N_) {
        const float4 v = *(const float4*)&inc[(size_t)n * E_ + c];
        u.x = f2bf(v.x); u.y = f2bf(v.y); u.z = f2bf(v.z); u.w = f2bf(v.w);
    } else { u.x = 0; u.y = 0; u.z = 0; u.w = 0; }
    *(ushort4*)&incB[(size_t)n * E_ + c] = u;
}

__global__ __launch_bounds__(256)
void k_tr32(const float* __restrict__ in, unsigned short* __restrict__ out,
            int R, int C, int Rp, size_t inZ, size_t outZ)
{
    in  += (size_t)blockIdx.z * inZ;
    out += (size_t)blockIdx.z * outZ;
    const int c0 = blockIdx.x * 64, r0 = blockIdx.y * 64;
    __shared__ float sm[64][65];
    const int cl = threadIdx.x & 63;
    for (int rr = threadIdx.x >> 6; rr < 64; rr += 4) {
        const int r = r0 + rr;
        sm[cl][rr] = (r < R) ? in[(size_t)r * C + c0 + cl] : 0.f;
    }
    __syncthreads();
    const int cw = threadIdx.x >> 2, j0 = (threadIdx.x & 3) * 16;
    unsigned short tmp[16];
    #pragma unroll
    for (int j = 0; j < 16; ++j) tmp[j] = f2bf(sm[cw][j0 + j]);
    *(ushort8*)&out[(size_t)(c0 + cw) * Rp + r0 + j0]     = *(ushort8*)&tmp[0];
    *(ushort8*)&out[(size_t)(c0 + cw) * Rp + r0 + j0 + 8] = *(ushort8*)&tmp[8];
}

__global__ __launch_bounds__(256)
void k_h(const float* __restrict__ ef, const float* __restrict__ W1,
         const float* __restrict__ b1, unsigned short* __restrict__ h)
{
    const int idx = blockIdx.x * 256 + threadIdx.x;
    const int e = idx >> 7, hh = idx & 127;
    float v = b1[hh];
    const float* efp = &ef[(size_t)e * F_];
    #pragma unroll
    for (int f = 0; f < F_; ++f) v += efp[f] * W1[f * H_ + hh];
    h[idx] = f2bf(fmaxf(v, 0.f));
}

// ---- final: out = relu(sum_p bf16 planes[p] + bgc), single d_out write -----
__global__ __launch_bounds__(256)
void k_final(const unsigned short* __restrict__ planesB, int P,
             const float* __restrict__ bgc, float* __restrict__ out)
{
    const int i = (blockIdx.x * 256 + threadIdx.x) * 8;
    if (i >= ACC_ELEMS) return;
    float s[8];
    #pragma unroll
    for (int j = 0; j < 8; ++j) s[j] = bgc[(i + j) & 63];
    for (int p = 0; p < P; ++p) {
        const ushort8 v = *(const ushort8*)&planesB[(size_t)p * ACC_ELEMS + i];
        #pragma unroll
        for (int j = 0; j < 8; ++j) s[j] += bf2f((unsigned short)v[j]);
    }
    float4 o0, o1;
    o0.x = fmaxf(s[0], 0.f); o0.y = fmaxf(s[1], 0.f);
    o0.z = fmaxf(s[2], 0.f); o0.w = fmaxf(s[3], 0.f);
    o1.x = fmaxf(s[4], 0.f); o1.y = fmaxf(s[5], 0.f);
    o1.z = fmaxf(s[6], 0.f); o1.w = fmaxf(s[7], 0.f);
    *(float4*)&out[i]     = o0;
    *(float4*)&out[i + 4] = o1;
}

extern "C" void kernel_launch(void* const* d_in, const int* in_sizes, int n_in,
                              void* d_out, int out_size, void* d_ws, size_t ws_size,
                              hipStream_t stream) {
    const float* x   = (const float*)d_in[0];
    const float* inc = (const float*)d_in[1];
    const float* ef  = (const float*)d_in[2];
    const float* W1  = (const float*)d_in[3];
    const float* b1  = (const float*)d_in[4];
    const float* W2  = (const float*)d_in[5];
    const float* b2  = (const float*)d_in[6];
    const float* bgc = (const float*)d_in[7];
    float* out = (float*)d_out;

    const size_t persistU16 = (size_t)NP_ * E_      // incB
                            + (size_t)E_ * NP_      // incT
                            + (size_t)B_ * L_ * NP_ // xT
                            + (size_t)E_ * H_       // h
                            + (size_t)GL_ * H_;     // W2T
    const size_t persistBytes = persistU16 * 2;     // ~41.9 MB

    int nc = 1, Ec = E_;
    for (; nc <= 16; ++nc) {
        Ec = ((E_ + nc - 1) / nc + 127) / 128 * 128;
        const size_t need = persistBytes
                          + (size_t)nc * KS_ * ACC_ELEMS * 2     // bf16 planes
                          + 2 * (size_t)Ec * GL_ * 2;            // K + t chunk
        if (need <= ws_size) break;
    }
    if (nc > 16) { nc = 16; Ec = 1024; }

    unsigned short* planesB = (unsigned short*)d_ws;
    unsigned short* incB = planesB + (size_t)nc * KS_ * ACC_ELEMS;
    unsigned short* incT = incB + (size_t)NP_ * E_;
    unsigned short* xT   = incT + (size_t)E_ * NP_;
    unsigned short* h    = xT   + (size_t)B_ * L_ * NP_;
    unsigned short* W2T  = h    + (size_t)E_ * H_;
    unsigned short* Kc   = W2T  + (size_t)GL_ * H_;    // [Ec][4096]
    unsigned short* tc   = Kc   + (size_t)Ec * GL_;    // [Ec][4096]; later y8

    k_cvt_incB<<<dim3(16, NP_), 256, 0, stream>>>(inc, incB);
    k_tr32<<<dim3(E_ / 64, NP_ / 64, 1), 256, 0, stream>>>(inc, incT, N_, E_, NP_, 0, 0);
    k_tr32<<<dim3(1, NP_ / 64, B_),      256, 0, stream>>>(x, xT, N_, L_, NP_,
                                                           (size_t)N_ * L_, (size_t)L_ * NP_);
    k_tr32<<<dim3(GL_ / 64, H_ / 64, 1), 256, 0, stream>>>(W2, W2T, H_, GL_, H_, 0, 0);
    k_h<<<dim3(E_ * H_ / 256), 256, 0, stream>>>(ef, W1, b1, h);

    int cidx = 0;
    for (int e_off = 0; e_off < E_; e_off += Ec, ++cidx) {
        const int ec = (E_ - e_off) < Ec ? (E_ - e_off) : Ec;   // multiple of 128
        gemm128<1><<<dim3((ec / 128) * 32), 256, 0, stream>>>(
            h + (size_t)e_off * H_, H_, W2T, H_, H_, 32, Kc, GL_, b2);
        gemm128<0><<<dim3((ec / 128) * 32), 256, 0, stream>>>(
            incT + (size_t)e_off * NP_, NP_, xT, NP_, NP_, 32, tc, GL_, nullptr);
        k_y8<<<dim3(ec / 8), 512, 0, stream>>>(tc, Kc);             // y8 over t
        k_accd<<<dim3(128, KS_), 256, 0, stream>>>(
            incB + e_off, tc, planesB, cidx * KS_, ec);
    }

    k_final<<<dim3(ACC_ELEMS / 2048), 256, 0, stream>>>(planesB, nc * KS_, bgc, out);
}

// Round 11
// 449.732 us; speedup vs baseline: 7.9883x; 1.6388x over previous
//
#include <hip/hip_runtime.h>

constexpr int B_ = 64, N_ = 500, E_ = 16000, L_ = 64, G_ = 64, F_ = 8, H_ = 128;
constexpr int GL_ = 4096;     // G*L
constexpr int NP_ = 512;      // n padded
constexpr int KS_ = 4;        // K-split planes per chunk
constexpr int ACC_ELEMS = B_ * N_ * G_;               // 2,048,000

using bf16x8  = __attribute__((ext_vector_type(8))) short;
using f32x4   = __attribute__((ext_vector_type(4))) float;
using ushort8 = __attribute__((ext_vector_type(8))) unsigned short;

#define MFMA16(a, b, c) __builtin_amdgcn_mfma_f32_16x16x32_bf16((a), (b), (c), 0, 0, 0)

typedef __attribute__((address_space(3))) unsigned int       lds_u32;
typedef const __attribute__((address_space(1))) unsigned int glb_u32;

static __device__ __forceinline__ unsigned short f2bf(float f) {
    union { float f; unsigned u; } v; v.f = f;
    unsigned r = v.u + 0x7fffu + ((v.u >> 16) & 1u);
    return (unsigned short)(r >> 16);
}
static __device__ __forceinline__ float bf2f(unsigned short s) {
    union { float f; unsigned u; } v; v.u = ((unsigned)s) << 16;
    return v.f;
}

// stage a 128x64 bf16 tile (16 KB = 1024 x 16B chunks) global -> LDS.
// 256 threads x 4 issues; per wave the LDS dest is base + lane*16 (linear).
static __device__ __forceinline__ void stage_tile(
    const unsigned short* __restrict__ g, int ld, int r0, int kk,
    unsigned short* lds, int tid)
{
    #pragma unroll
    for (int c = 0; c < 4; ++c) {
        const int ch  = tid + c * 256;          // 0..1023
        const int row = ch >> 3, off = (ch & 7) * 8;
        __builtin_amdgcn_global_load_lds(
            (glb_u32*)(g + (size_t)(r0 + row) * ld + kk + off),
            (lds_u32*)(lds + (size_t)ch * 8), 16, 0, 0);
    }
}

// ======================= 128x128 MFMA GEMM (modes 0/1) ======================
// C[M][N] = A[M][K] (row-major, lda) @ Bm[N][K]^T (row-major, ldb)
// MODE 0: store bf16 C. MODE 1: +bias[col], store bf16.
// m97-style: global_load_lds staging, single LDS buffer, 2 barriers / K-step.
template<int MODE>
__global__ __launch_bounds__(256)
void gemm128(const unsigned short* __restrict__ A, int lda,
             const unsigned short* __restrict__ Bm, int ldb,
             int K, int nN,
             unsigned short* __restrict__ C, int ldc,
             const float* __restrict__ bias)
{
    const int nwg = gridDim.x;
    const int bid = blockIdx.x;
    const int swz = (nwg & 7) ? bid : ((bid & 7) * (nwg >> 3) + (bid >> 3));
    const int m0 = (swz / nN) * 128, n0 = (swz % nN) * 128;

    const int tid  = threadIdx.x;
    const int lane = tid & 63, wid = tid >> 6;
    const int wm = wid >> 1, wn = wid & 1;
    const int fr = lane & 15, fq = lane >> 4;

    __shared__ __align__(16) unsigned short smem[2 * 128 * 64];   // 32 KB linear
    unsigned short* As = smem;            // [128][64]
    unsigned short* Bs = smem + 128 * 64; // [128][64]

    const f32x4 fz = {0.f, 0.f, 0.f, 0.f};
    f32x4 acc[4][4] = {{fz, fz, fz, fz}, {fz, fz, fz, fz},
                       {fz, fz, fz, fz}, {fz, fz, fz, fz}};

    const int nk = K / 64;
    for (int kt = 0; kt < nk; ++kt) {
        stage_tile(A, lda, m0, kt * 64, As, tid);
        stage_tile(Bm, ldb, n0, kt * 64, Bs, tid);
        __syncthreads();                       // vmcnt(0) drain + barrier
        #pragma unroll
        for (int ks = 0; ks < 2; ++ks) {
            bf16x8 af[4], bf[4];
            #pragma unroll
            for (int i = 0; i < 4; ++i)
                af[i] = *(const bf16x8*)&As[(wm * 64 + i * 16 + fr) * 64 + ks * 32 + fq * 8];
            #pragma unroll
            for (int j = 0; j < 4; ++j)
                bf[j] = *(const bf16x8*)&Bs[(wn * 64 + j * 16 + fr) * 64 + ks * 32 + fq * 8];
            #pragma unroll
            for (int i = 0; i < 4; ++i)
                #pragma unroll
                for (int j = 0; j < 4; ++j)
                    acc[i][j] = MFMA16(af[i], bf[j], acc[i][j]);
        }
        __syncthreads();                       // protect LDS before next stage
    }

    auto Cs = (unsigned short(*)[128])smem;    // 32 KB reuse
    #pragma unroll
    for (int i = 0; i < 4; ++i)
        #pragma unroll
        for (int j = 0; j < 4; ++j) {
            float bv = 0.f;
            if constexpr (MODE == 1) bv = bias[n0 + wn * 64 + j * 16 + fr];
            #pragma unroll
            for (int r = 0; r < 4; ++r)
                Cs[wm * 64 + i * 16 + fq * 4 + r][wn * 64 + j * 16 + fr] =
                    f2bf(acc[i][j][r] + bv);
        }
    __syncthreads();
    const int r2 = tid >> 4, o2 = (tid & 15) * 8;
    #pragma unroll
    for (int i = 0; i < 8; ++i) {
        const int row = i * 16 + r2;
        *(uint4*)&C[(size_t)(m0 + row) * ldc + n0 + o2] = *(const uint4*)&Cs[row][o2];
    }
}

// ---- k_y8: per block 8 edges; wave w computes y[e0+w] = t[e]@K[e]^T --------
// Output written IN PLACE over t as e-blocked tiles: [eb][bg 4096][8 e].
__global__ __launch_bounds__(512)
void k_y8(unsigned short* tc, const unsigned short* __restrict__ Kc)
{
    const int e0 = blockIdx.x * 8;
    const int tid = threadIdx.x, lane = tid & 63, w = tid >> 6;
    const int e = e0 + w;
    const int fr = lane & 15, fq = lane >> 4;
    const unsigned short* A  = &tc[(size_t)e * GL_];
    const unsigned short* Bp = &Kc[(size_t)e * GL_];
    const f32x4 fz = {0.f, 0.f, 0.f, 0.f};
    f32x4 acc[4][4] = {{fz, fz, fz, fz}, {fz, fz, fz, fz},
                       {fz, fz, fz, fz}, {fz, fz, fz, fz}};
    #pragma unroll
    for (int ks = 0; ks < 2; ++ks) {
        bf16x8 af[4], bf[4];
        #pragma unroll
        for (int i = 0; i < 4; ++i)
            af[i] = *(const bf16x8*)&A[(i * 16 + fr) * 64 + ks * 32 + fq * 8];
        #pragma unroll
        for (int j = 0; j < 4; ++j)
            bf[j] = *(const bf16x8*)&Bp[(j * 16 + fr) * 64 + ks * 32 + fq * 8];
        #pragma unroll
        for (int i = 0; i < 4; ++i)
            #pragma unroll
            for (int j = 0; j < 4; ++j)
                acc[i][j] = MFMA16(af[i], bf[j], acc[i][j]);
    }
    __shared__ unsigned short y8[GL_ * 8];   // 64KB, [bg][8]
    #pragma unroll
    for (int i = 0; i < 4; ++i)
        #pragma unroll
        for (int j = 0; j < 4; ++j)
            #pragma unroll
            for (int r = 0; r < 4; ++r) {
                const int bg = (i * 16 + fq * 4 + r) * 64 + j * 16 + fr;
                y8[bg * 8 + w] = f2bf(acc[i][j][r]);
            }
    __syncthreads();
    unsigned short* dst = tc + (size_t)e0 * GL_;   // same 64KB region
    #pragma unroll
    for (int p = 0; p < 8; ++p) {
        const int o = (p * 512 + tid) * 8;
        *(uint4*)&dst[o] = *(const uint4*)&y8[o];
    }
}

// ---- k_accd: planes[pbase+ky] = incB @ y8^T, direct loads, no LDS ----------
__global__ __launch_bounds__(256)
void k_accd(const unsigned short* __restrict__ Ae,   // incB + e_off
            const unsigned short* __restrict__ y8,   // chunk tc base
            unsigned short* __restrict__ planesB, int pbase, int K)
{
    const int xcd = blockIdx.x & 7, grp = blockIdx.x >> 3;
    const int m0 = (grp & 3) * 128;
    const int n0 = (xcd + 8 * (grp >> 2)) * 128;
    const int KSY = gridDim.y;
    const int kl = ((K / KSY) / 64) * 64;
    const int kbeg = blockIdx.y * kl;
    const int kend = ((int)blockIdx.y == KSY - 1) ? K : kbeg + kl;

    const int lane = threadIdx.x & 63, wid = threadIdx.x >> 6;
    const int wm = wid >> 1, wn = wid & 1;
    const int fr = lane & 15, fq = lane >> 4;

    const f32x4 fz = {0.f, 0.f, 0.f, 0.f};
    f32x4 acc[4][4] = {{fz, fz, fz, fz}, {fz, fz, fz, fz},
                       {fz, fz, fz, fz}, {fz, fz, fz, fz}};

    for (int kk = kbeg; kk < kend; kk += 64) {
        #pragma unroll
        for (int ks = 0; ks < 2; ++ks) {
            const int e8 = kk + ks * 32 + fq * 8;
            const unsigned short* yb = &y8[(size_t)(e8 >> 3) * (GL_ * 8)];
            bf16x8 af[4], bf[4];
            #pragma unroll
            for (int i = 0; i < 4; ++i)
                af[i] = *(const bf16x8*)&Ae[(size_t)(m0 + wm * 64 + i * 16 + fr) * E_ + e8];
            #pragma unroll
            for (int j = 0; j < 4; ++j)
                bf[j] = *(const bf16x8*)&yb[(n0 + wn * 64 + j * 16 + fr) * 8];
            #pragma unroll
            for (int i = 0; i < 4; ++i)
                #pragma unroll
                for (int j = 0; j < 4; ++j)
                    acc[i][j] = MFMA16(af[i], bf[j], acc[i][j]);
        }
    }

    unsigned short* pl = planesB + (size_t)(pbase + blockIdx.y) * ACC_ELEMS;
    #pragma unroll
    for (int i = 0; i < 4; ++i)
        #pragma unroll
        for (int j = 0; j < 4; ++j) {
            const int col = n0 + wn * 64 + j * 16 + fr;
            const int b = col >> 6, g = col & 63;
            #pragma unroll
            for (int r = 0; r < 4; ++r) {
                const int n = m0 + wm * 64 + i * 16 + fq * 4 + r;
                if (n < N_)
                    pl[((size_t)b * N_ + n) * G_ + g] = f2bf(acc[i][j][r]);
            }
        }
}

// ======================= prologue / small kernels ===========================
__global__ __launch_bounds__(256)
void k_cvt_incB(const float* __restrict__ inc, unsigned short* __restrict__ incB)
{
    const int n = blockIdx.y;
    const int c = blockIdx.x * 1024 + threadIdx.x * 4;
    if (c >= E_) return;
    ushort4 u;
    if (n < N_) {
        const float4 v = *(const float4*)&inc[(size_t)n * E_ + c];
        u.x = f2bf(v.x); u.y = f2bf(v.y); u.z = f2bf(v.z); u.w = f2bf(v.w);
    } else { u.x = 0; u.y = 0; u.z = 0; u.w = 0; }
    *(ushort4*)&incB[(size_t)n * E_ + c] = u;
}

__global__ __launch_bounds__(256)
void k_tr32(const float* __restrict__ in, unsigned short* __restrict__ out,
            int R, int C, int Rp, size_t inZ, size_t outZ)
{
    in  += (size_t)blockIdx.z * inZ;
    out += (size_t)blockIdx.z * outZ;
    const int c0 = blockIdx.x * 64, r0 = blockIdx.y * 64;
    __shared__ float sm[64][65];
    const int cl = threadIdx.x & 63;
    for (int rr = threadIdx.x >> 6; rr < 64; rr += 4) {
        const int r = r0 + rr;
        sm[cl][rr] = (r < R) ? in[(size_t)r * C + c0 + cl] : 0.f;
    }
    __syncthreads();
    const int cw = threadIdx.x >> 2, j0 = (threadIdx.x & 3) * 16;
    unsigned short tmp[16];
    #pragma unroll
    for (int j = 0; j < 16; ++j) tmp[j] = f2bf(sm[cw][j0 + j]);
    *(ushort8*)&out[(size_t)(c0 + cw) * Rp + r0 + j0]     = *(ushort8*)&tmp[0];
    *(ushort8*)&out[(size_t)(c0 + cw) * Rp + r0 + j0 + 8] = *(ushort8*)&tmp[8];
}

__global__ __launch_bounds__(256)
void k_h(const float* __restrict__ ef, const float* __restrict__ W1,
         const float* __restrict__ b1, unsigned short* __restrict__ h)
{
    const int idx = blockIdx.x * 256 + threadIdx.x;
    const int e = idx >> 7, hh = idx & 127;
    float v = b1[hh];
    const float* efp = &ef[(size_t)e * F_];
    #pragma unroll
    for (int f = 0; f < F_; ++f) v += efp[f] * W1[f * H_ + hh];
    h[idx] = f2bf(fmaxf(v, 0.f));
}

// ---- final: out = relu(sum_p bf16 planes[p] + bgc), single d_out write -----
__global__ __launch_bounds__(256)
void k_final(const unsigned short* __restrict__ planesB, int P,
             const float* __restrict__ bgc, float* __restrict__ out)
{
    const int i = (blockIdx.x * 256 + threadIdx.x) * 8;
    if (i >= ACC_ELEMS) return;
    float s[8];
    #pragma unroll
    for (int j = 0; j < 8; ++j) s[j] = bgc[(i + j) & 63];
    for (int p = 0; p < P; ++p) {
        const ushort8 v = *(const ushort8*)&planesB[(size_t)p * ACC_ELEMS + i];
        #pragma unroll
        for (int j = 0; j < 8; ++j) s[j] += bf2f((unsigned short)v[j]);
    }
    float4 o0, o1;
    o0.x = fmaxf(s[0], 0.f); o0.y = fmaxf(s[1], 0.f);
    o0.z = fmaxf(s[2], 0.f); o0.w = fmaxf(s[3], 0.f);
    o1.x = fmaxf(s[4], 0.f); o1.y = fmaxf(s[5], 0.f);
    o1.z = fmaxf(s[6], 0.f); o1.w = fmaxf(s[7], 0.f);
    *(float4*)&out[i]     = o0;
    *(float4*)&out[i + 4] = o1;
}

extern "C" void kernel_launch(void* const* d_in, const int* in_sizes, int n_in,
                              void* d_out, int out_size, void* d_ws, size_t ws_size,
                              hipStream_t stream) {
    const float* x   = (const float*)d_in[0];
    const float* inc = (const float*)d_in[1];
    const float* ef  = (const float*)d_in[2];
    const float* W1  = (const float*)d_in[3];
    const float* b1  = (const float*)d_in[4];
    const float* W2  = (const float*)d_in[5];
    const float* b2  = (const float*)d_in[6];
    const float* bgc = (const float*)d_in[7];
    float* out = (float*)d_out;

    const size_t persistU16 = (size_t)NP_ * E_      // incB
                            + (size_t)E_ * NP_      // incT
                            + (size_t)B_ * L_ * NP_ // xT
                            + (size_t)E_ * H_       // h
                            + (size_t)GL_ * H_;     // W2T
    const size_t persistBytes = persistU16 * 2;     // ~41.9 MB

    int nc = 1, Ec = E_;
    for (; nc <= 16; ++nc) {
        Ec = ((E_ + nc - 1) / nc + 127) / 128 * 128;
        const size_t need = persistBytes
                          + (size_t)nc * KS_ * ACC_ELEMS * 2     // bf16 planes
                          + 2 * (size_t)Ec * GL_ * 2;            // K + t chunk
        if (need <= ws_size) break;
    }
    if (nc > 16) { nc = 16; Ec = 1024; }

    unsigned short* planesB = (unsigned short*)d_ws;
    unsigned short* incB = planesB + (size_t)nc * KS_ * ACC_ELEMS;
    unsigned short* incT = incB + (size_t)NP_ * E_;
    unsigned short* xT   = incT + (size_t)E_ * NP_;
    unsigned short* h    = xT   + (size_t)B_ * L_ * NP_;
    unsigned short* W2T  = h    + (size_t)E_ * H_;
    unsigned short* Kc   = W2T  + (size_t)GL_ * H_;    // [Ec][4096]
    unsigned short* tc   = Kc   + (size_t)Ec * GL_;    // [Ec][4096]; later y8

    k_cvt_incB<<<dim3(16, NP_), 256, 0, stream>>>(inc, incB);
    k_tr32<<<dim3(E_ / 64, NP_ / 64, 1), 256, 0, stream>>>(inc, incT, N_, E_, NP_, 0, 0);
    k_tr32<<<dim3(1, NP_ / 64, B_),      256, 0, stream>>>(x, xT, N_, L_, NP_,
                                                           (size_t)N_ * L_, (size_t)L_ * NP_);
    k_tr32<<<dim3(GL_ / 64, H_ / 64, 1), 256, 0, stream>>>(W2, W2T, H_, GL_, H_, 0, 0);
    k_h<<<dim3(E_ * H_ / 256), 256, 0, stream>>>(ef, W1, b1, h);

    int cidx = 0;
    for (int e_off = 0; e_off < E_; e_off += Ec, ++cidx) {
        const int ec = (E_ - e_off) < Ec ? (E_ - e_off) : Ec;   // multiple of 128
        gemm128<1><<<dim3((ec / 128) * 32), 256, 0, stream>>>(
            h + (size_t)e_off * H_, H_, W2T, H_, H_, 32, Kc, GL_, b2);
        gemm128<0><<<dim3((ec / 128) * 32), 256, 0, stream>>>(
            incT + (size_t)e_off * NP_, NP_, xT, NP_, NP_, 32, tc, GL_, nullptr);
        k_y8<<<dim3(ec / 8), 512, 0, stream>>>(tc, Kc);             // y8 over t
        k_accd<<<dim3(128, KS_), 256, 0, stream>>>(
            incB + e_off, tc, planesB, cidx * KS_, ec);
    }

    k_final<<<dim3(ACC_ELEMS / 2048), 256, 0, stream>>>(planesB, nc * KS_, bgc, out);
}

// Round 12
// 409.314 us; speedup vs baseline: 8.7771x; 1.0987x over previous
//
#include <hip/hip_runtime.h>

constexpr int B_ = 64, N_ = 500, E_ = 16000, L_ = 64, G_ = 64, F_ = 8, H_ = 128;
constexpr int GL_ = 4096;     // G*L
constexpr int NP_ = 512;      // n padded
constexpr int KS_ = 4;        // K-split planes per chunk
constexpr int ACC_ELEMS = B_ * N_ * G_;               // 2,048,000

using bf16x8  = __attribute__((ext_vector_type(8))) short;
using f32x4   = __attribute__((ext_vector_type(4))) float;
using ushort8 = __attribute__((ext_vector_type(8))) unsigned short;

#define MFMA16(a, b, c) __builtin_amdgcn_mfma_f32_16x16x32_bf16((a), (b), (c), 0, 0, 0)

typedef __attribute__((address_space(3))) unsigned int       lds_u32;
typedef const __attribute__((address_space(1))) unsigned int glb_u32;

static __device__ __forceinline__ unsigned short f2bf(float f) {
    union { float f; unsigned u; } v; v.f = f;
    unsigned r = v.u + 0x7fffu + ((v.u >> 16) & 1u);
    return (unsigned short)(r >> 16);
}
static __device__ __forceinline__ float bf2f(unsigned short s) {
    union { float f; unsigned u; } v; v.u = ((unsigned)s) << 16;
    return v.f;
}

// stage a 128x64 bf16 tile (16 KB = 1024 x 16B chunks) global -> LDS.
static __device__ __forceinline__ void stage_tile(
    const unsigned short* __restrict__ g, int ld, int r0, int kk,
    unsigned short* lds, int tid)
{
    #pragma unroll
    for (int c = 0; c < 4; ++c) {
        const int ch  = tid + c * 256;          // 0..1023
        const int row = ch >> 3, off = (ch & 7) * 8;
        __builtin_amdgcn_global_load_lds(
            (glb_u32*)(g + (size_t)(r0 + row) * ld + kk + off),
            (lds_u32*)(lds + (size_t)ch * 8), 16, 0, 0);
    }
}

// ======================= 128x128 MFMA GEMM (modes 0/1) ======================
template<int MODE>
__global__ __launch_bounds__(256)
void gemm128(const unsigned short* __restrict__ A, int lda,
             const unsigned short* __restrict__ Bm, int ldb,
             int K, int nN,
             unsigned short* __restrict__ C, int ldc,
             const float* __restrict__ bias)
{
    const int nwg = gridDim.x;
    const int bid = blockIdx.x;
    const int swz = (nwg & 7) ? bid : ((bid & 7) * (nwg >> 3) + (bid >> 3));
    const int m0 = (swz / nN) * 128, n0 = (swz % nN) * 128;

    const int tid  = threadIdx.x;
    const int lane = tid & 63, wid = tid >> 6;
    const int wm = wid >> 1, wn = wid & 1;
    const int fr = lane & 15, fq = lane >> 4;

    __shared__ __align__(16) unsigned short smem[2 * 128 * 64];   // 32 KB linear
    unsigned short* As = smem;
    unsigned short* Bs = smem + 128 * 64;

    const f32x4 fz = {0.f, 0.f, 0.f, 0.f};
    f32x4 acc[4][4] = {{fz, fz, fz, fz}, {fz, fz, fz, fz},
                       {fz, fz, fz, fz}, {fz, fz, fz, fz}};

    const int nk = K / 64;
    for (int kt = 0; kt < nk; ++kt) {
        stage_tile(A, lda, m0, kt * 64, As, tid);
        stage_tile(Bm, ldb, n0, kt * 64, Bs, tid);
        __syncthreads();
        #pragma unroll
        for (int ks = 0; ks < 2; ++ks) {
            bf16x8 af[4], bf[4];
            #pragma unroll
            for (int i = 0; i < 4; ++i)
                af[i] = *(const bf16x8*)&As[(wm * 64 + i * 16 + fr) * 64 + ks * 32 + fq * 8];
            #pragma unroll
            for (int j = 0; j < 4; ++j)
                bf[j] = *(const bf16x8*)&Bs[(wn * 64 + j * 16 + fr) * 64 + ks * 32 + fq * 8];
            #pragma unroll
            for (int i = 0; i < 4; ++i)
                #pragma unroll
                for (int j = 0; j < 4; ++j)
                    acc[i][j] = MFMA16(af[i], bf[j], acc[i][j]);
        }
        __syncthreads();
    }

    auto Cs = (unsigned short(*)[128])smem;
    #pragma unroll
    for (int i = 0; i < 4; ++i)
        #pragma unroll
        for (int j = 0; j < 4; ++j) {
            float bv = 0.f;
            if constexpr (MODE == 1) bv = bias[n0 + wn * 64 + j * 16 + fr];
            #pragma unroll
            for (int r = 0; r < 4; ++r)
                Cs[wm * 64 + i * 16 + fq * 4 + r][wn * 64 + j * 16 + fr] =
                    f2bf(acc[i][j][r] + bv);
        }
    __syncthreads();
    const int r2 = tid >> 4, o2 = (tid & 15) * 8;
    #pragma unroll
    for (int i = 0; i < 8; ++i) {
        const int row = i * 16 + r2;
        *(uint4*)&C[(size_t)(m0 + row) * ldc + n0 + o2] = *(const uint4*)&Cs[row][o2];
    }
}

// ---- k_y8: per block 8 edges; wave w computes y[e0+w] = t[e]@K[e]^T --------
__global__ __launch_bounds__(512)
void k_y8(unsigned short* tc, const unsigned short* __restrict__ Kc)
{
    const int e0 = blockIdx.x * 8;
    const int tid = threadIdx.x, lane = tid & 63, w = tid >> 6;
    const int e = e0 + w;
    const int fr = lane & 15, fq = lane >> 4;
    const unsigned short* A  = &tc[(size_t)e * GL_];
    const unsigned short* Bp = &Kc[(size_t)e * GL_];
    const f32x4 fz = {0.f, 0.f, 0.f, 0.f};
    f32x4 acc[4][4] = {{fz, fz, fz, fz}, {fz, fz, fz, fz},
                       {fz, fz, fz, fz}, {fz, fz, fz, fz}};
    #pragma unroll
    for (int ks = 0; ks < 2; ++ks) {
        bf16x8 af[4], bf[4];
        #pragma unroll
        for (int i = 0; i < 4; ++i)
            af[i] = *(const bf16x8*)&A[(i * 16 + fr) * 64 + ks * 32 + fq * 8];
        #pragma unroll
        for (int j = 0; j < 4; ++j)
            bf[j] = *(const bf16x8*)&Bp[(j * 16 + fr) * 64 + ks * 32 + fq * 8];
        #pragma unroll
        for (int i = 0; i < 4; ++i)
            #pragma unroll
            for (int j = 0; j < 4; ++j)
                acc[i][j] = MFMA16(af[i], bf[j], acc[i][j]);
    }
    __shared__ unsigned short y8[GL_ * 8];   // 64KB, [bg][8]
    #pragma unroll
    for (int i = 0; i < 4; ++i)
        #pragma unroll
        for (int j = 0; j < 4; ++j)
            #pragma unroll
            for (int r = 0; r < 4; ++r) {
                const int bg = (i * 16 + fq * 4 + r) * 64 + j * 16 + fr;
                y8[bg * 8 + w] = f2bf(acc[i][j][r]);
            }
    __syncthreads();
    unsigned short* dst = tc + (size_t)e0 * GL_;
    #pragma unroll
    for (int p = 0; p < 8; ++p) {
        const int o = (p * 512 + tid) * 8;
        *(uint4*)&dst[o] = *(const uint4*)&y8[o];
    }
}

// ---- k_accd: planes[pbase+ky] = incB8 @ y8^T, 64x128 tiles, direct loads ---
// A (incB8) and B (y8) both e-tiled: fragment = contiguous 16B.
__global__ __launch_bounds__(256)
void k_accd(const unsigned short* __restrict__ Ae,   // incB8 + e_off*NP_
            const unsigned short* __restrict__ y8,   // chunk tc base
            unsigned short* __restrict__ planesB, int pbase, int K)
{
    // 256 blocks: 8 m-tiles (64 rows) x 32 n-tiles (128 cols); same-n m-tiles
    // run consecutively on one XCD -> B-panel K-slice L2-resident.
    const int xcd = blockIdx.x & 7, grp = blockIdx.x >> 3;   // grp 0..31
    const int m0 = (grp & 7) * 64;
    const int n0 = (xcd + 8 * (grp >> 3)) * 128;
    const int KSY = gridDim.y;
    const int kl = ((K / KSY) / 64) * 64;
    const int kbeg = blockIdx.y * kl;
    const int kend = ((int)blockIdx.y == KSY - 1) ? K : kbeg + kl;

    const int lane = threadIdx.x & 63, wid = threadIdx.x >> 6;
    const int wm = wid >> 1, wn = wid & 1;          // m 32 each, n 64 each
    const int fr = lane & 15, fq = lane >> 4;

    const f32x4 fz = {0.f, 0.f, 0.f, 0.f};
    f32x4 acc[2][4] = {{fz, fz, fz, fz}, {fz, fz, fz, fz}};

    for (int kk = kbeg; kk < kend; kk += 64) {
        #pragma unroll
        for (int ks = 0; ks < 2; ++ks) {
            const int e8 = kk + ks * 32 + fq * 8;
            const size_t eb = (size_t)(e8 >> 3);
            bf16x8 af[2], bf[4];
            #pragma unroll
            for (int i = 0; i < 2; ++i)
                af[i] = *(const bf16x8*)&Ae[(eb * NP_ + m0 + wm * 32 + i * 16 + fr) * 8];
            #pragma unroll
            for (int j = 0; j < 4; ++j)
                bf[j] = *(const bf16x8*)&y8[eb * GL_ * 8 + (n0 + wn * 64 + j * 16 + fr) * 8];
            #pragma unroll
            for (int i = 0; i < 2; ++i)
                #pragma unroll
                for (int j = 0; j < 4; ++j)
                    acc[i][j] = MFMA16(af[i], bf[j], acc[i][j]);
        }
    }

    unsigned short* pl = planesB + (size_t)(pbase + blockIdx.y) * ACC_ELEMS;
    #pragma unroll
    for (int i = 0; i < 2; ++i)
        #pragma unroll
        for (int j = 0; j < 4; ++j) {
            const int col = n0 + wn * 64 + j * 16 + fr;
            const int b = col >> 6, g = col & 63;
            #pragma unroll
            for (int r = 0; r < 4; ++r) {
                const int n = m0 + wm * 32 + i * 16 + fq * 4 + r;
                if (n < N_)
                    pl[((size_t)b * N_ + n) * G_ + g] = f2bf(acc[i][j][r]);
            }
        }
}

// ======================= prologue / small kernels ===========================
// incB8[e/8][n 512][8]: e-tiled bf16 incidence (A-operand of k_accd).
__global__ __launch_bounds__(256)
void k_cvt_incB8(const float* __restrict__ inc, unsigned short* __restrict__ incB8)
{
    const int e0 = blockIdx.x * 64;     // 250 blocks
    const int n0 = blockIdx.y * 64;     // 8 blocks
    const int tid = threadIdx.x;
    __shared__ unsigned short sm[64][72];   // [n][e], 16B-aligned rows
    const int cl = tid & 63;
    for (int rr = tid >> 6; rr < 64; rr += 4) {
        const int n = n0 + rr;
        sm[rr][cl] = (n < N_) ? f2bf(inc[(size_t)n * E_ + e0 + cl]) : (unsigned short)0;
    }
    __syncthreads();
    const int eb = tid >> 5, idx = tid & 31;    // 8 e-blocks x 32 threads
    #pragma unroll
    for (int k = 0; k < 2; ++k) {
        const int row = idx * 2 + k;
        *(ushort8*)&incB8[((size_t)((e0 >> 3) + eb) * NP_ + n0 + row) * 8] =
            *(const ushort8*)&sm[row][eb * 8];
    }
}

__global__ __launch_bounds__(256)
void k_tr32(const float* __restrict__ in, unsigned short* __restrict__ out,
            int R, int C, int Rp, size_t inZ, size_t outZ)
{
    in  += (size_t)blockIdx.z * inZ;
    out += (size_t)blockIdx.z * outZ;
    const int c0 = blockIdx.x * 64, r0 = blockIdx.y * 64;
    __shared__ float sm[64][65];
    const int cl = threadIdx.x & 63;
    for (int rr = threadIdx.x >> 6; rr < 64; rr += 4) {
        const int r = r0 + rr;
        sm[cl][rr] = (r < R) ? in[(size_t)r * C + c0 + cl] : 0.f;
    }
    __syncthreads();
    const int cw = threadIdx.x >> 2, j0 = (threadIdx.x & 3) * 16;
    unsigned short tmp[16];
    #pragma unroll
    for (int j = 0; j < 16; ++j) tmp[j] = f2bf(sm[cw][j0 + j]);
    *(ushort8*)&out[(size_t)(c0 + cw) * Rp + r0 + j0]     = *(ushort8*)&tmp[0];
    *(ushort8*)&out[(size_t)(c0 + cw) * Rp + r0 + j0 + 8] = *(ushort8*)&tmp[8];
}

__global__ __launch_bounds__(256)
void k_h(const float* __restrict__ ef, const float* __restrict__ W1,
         const float* __restrict__ b1, unsigned short* __restrict__ h)
{
    const int idx = blockIdx.x * 256 + threadIdx.x;
    const int e = idx >> 7, hh = idx & 127;
    float v = b1[hh];
    const float* efp = &ef[(size_t)e * F_];
    #pragma unroll
    for (int f = 0; f < F_; ++f) v += efp[f] * W1[f * H_ + hh];
    h[idx] = f2bf(fmaxf(v, 0.f));
}

// ---- final: out = relu(sum_p bf16 planes[p] + bgc), single d_out write -----
__global__ __launch_bounds__(256)
void k_final(const unsigned short* __restrict__ planesB, int P,
             const float* __restrict__ bgc, float* __restrict__ out)
{
    const int i = (blockIdx.x * 256 + threadIdx.x) * 8;
    if (i >= ACC_ELEMS) return;
    float s[8];
    #pragma unroll
    for (int j = 0; j < 8; ++j) s[j] = bgc[(i + j) & 63];
    for (int p = 0; p < P; ++p) {
        const ushort8 v = *(const ushort8*)&planesB[(size_t)p * ACC_ELEMS + i];
        #pragma unroll
        for (int j = 0; j < 8; ++j) s[j] += bf2f((unsigned short)v[j]);
    }
    float4 o0, o1;
    o0.x = fmaxf(s[0], 0.f); o0.y = fmaxf(s[1], 0.f);
    o0.z = fmaxf(s[2], 0.f); o0.w = fmaxf(s[3], 0.f);
    o1.x = fmaxf(s[4], 0.f); o1.y = fmaxf(s[5], 0.f);
    o1.z = fmaxf(s[6], 0.f); o1.w = fmaxf(s[7], 0.f);
    *(float4*)&out[i]     = o0;
    *(float4*)&out[i + 4] = o1;
}

extern "C" void kernel_launch(void* const* d_in, const int* in_sizes, int n_in,
                              void* d_out, int out_size, void* d_ws, size_t ws_size,
                              hipStream_t stream) {
    const float* x   = (const float*)d_in[0];
    const float* inc = (const float*)d_in[1];
    const float* ef  = (const float*)d_in[2];
    const float* W1  = (const float*)d_in[3];
    const float* b1  = (const float*)d_in[4];
    const float* W2  = (const float*)d_in[5];
    const float* b2  = (const float*)d_in[6];
    const float* bgc = (const float*)d_in[7];
    float* out = (float*)d_out;

    const size_t persistU16 = (size_t)NP_ * E_      // incB8
                            + (size_t)E_ * NP_      // incT
                            + (size_t)B_ * L_ * NP_ // xT
                            + (size_t)E_ * H_       // h
                            + (size_t)GL_ * H_;     // W2T
    const size_t persistBytes = persistU16 * 2;     // ~41.9 MB

    int nc = 1, Ec = E_;
    for (; nc <= 16; ++nc) {
        Ec = ((E_ + nc - 1) / nc + 127) / 128 * 128;
        const size_t need = persistBytes
                          + (size_t)nc * KS_ * ACC_ELEMS * 2     // bf16 planes
                          + 2 * (size_t)Ec * GL_ * 2;            // K + t chunk
        if (need <= ws_size) break;
    }
    if (nc > 16) { nc = 16; Ec = 1024; }

    unsigned short* planesB = (unsigned short*)d_ws;
    unsigned short* incB8 = planesB + (size_t)nc * KS_ * ACC_ELEMS;
    unsigned short* incT = incB8 + (size_t)NP_ * E_;
    unsigned short* xT   = incT + (size_t)E_ * NP_;
    unsigned short* h    = xT   + (size_t)B_ * L_ * NP_;
    unsigned short* W2T  = h    + (size_t)E_ * H_;
    unsigned short* Kc   = W2T  + (size_t)GL_ * H_;    // [Ec][4096]
    unsigned short* tc   = Kc   + (size_t)Ec * GL_;    // [Ec][4096]; later y8

    k_cvt_incB8<<<dim3(E_ / 64, NP_ / 64), 256, 0, stream>>>(inc, incB8);
    k_tr32<<<dim3(E_ / 64, NP_ / 64, 1), 256, 0, stream>>>(inc, incT, N_, E_, NP_, 0, 0);
    k_tr32<<<dim3(1, NP_ / 64, B_),      256, 0, stream>>>(x, xT, N_, L_, NP_,
                                                           (size_t)N_ * L_, (size_t)L_ * NP_);
    k_tr32<<<dim3(GL_ / 64, H_ / 64, 1), 256, 0, stream>>>(W2, W2T, H_, GL_, H_, 0, 0);
    k_h<<<dim3(E_ * H_ / 256), 256, 0, stream>>>(ef, W1, b1, h);

    int cidx = 0;
    for (int e_off = 0; e_off < E_; e_off += Ec, ++cidx) {
        const int ec = (E_ - e_off) < Ec ? (E_ - e_off) : Ec;   // multiple of 128
        gemm128<1><<<dim3((ec / 128) * 32), 256, 0, stream>>>(
            h + (size_t)e_off * H_, H_, W2T, H_, H_, 32, Kc, GL_, b2);
        gemm128<0><<<dim3((ec / 128) * 32), 256, 0, stream>>>(
            incT + (size_t)e_off * NP_, NP_, xT, NP_, NP_, 32, tc, GL_, nullptr);
        k_y8<<<dim3(ec / 8), 512, 0, stream>>>(tc, Kc);             // y8 over t
        k_accd<<<dim3(256, KS_), 256, 0, stream>>>(
            incB8 + (size_t)e_off * NP_, tc, planesB, cidx * KS_, ec);
    }

    k_final<<<dim3(ACC_ELEMS / 2048), 256, 0, stream>>>(planesB, nc * KS_, bgc, out);
}

// Round 13
// 397.495 us; speedup vs baseline: 9.0381x; 1.0297x over previous
//
#include <hip/hip_runtime.h>

constexpr int B_ = 64, N_ = 500, E_ = 16000, L_ = 64, G_ = 64, F_ = 8, H_ = 128;
constexpr int GL_ = 4096;     // G*L
constexpr int NP_ = 512;      // n padded
constexpr int KS_ = 4;        // K-split planes per chunk
constexpr int ACC_ELEMS = B_ * N_ * G_;               // 2,048,000

using bf16x8  = __attribute__((ext_vector_type(8))) short;
using f32x4   = __attribute__((ext_vector_type(4))) float;
using ushort8 = __attribute__((ext_vector_type(8))) unsigned short;

#define MFMA16(a, b, c) __builtin_amdgcn_mfma_f32_16x16x32_bf16((a), (b), (c), 0, 0, 0)

typedef __attribute__((address_space(3))) unsigned int       lds_u32;
typedef const __attribute__((address_space(1))) unsigned int glb_u32;

static __device__ __forceinline__ unsigned short f2bf(float f) {
    union { float f; unsigned u; } v; v.f = f;
    unsigned r = v.u + 0x7fffu + ((v.u >> 16) & 1u);
    return (unsigned short)(r >> 16);
}
static __device__ __forceinline__ float bf2f(unsigned short s) {
    union { float f; unsigned u; } v; v.u = ((unsigned)s) << 16;
    return v.f;
}

// stage 128x64 bf16 tile global->LDS, PRE-SWIZZLED SOURCE (rule #21):
// LDS chunk (row,c) holds global chunk (row, c ^ (row&7)); LDS dest linear.
static __device__ __forceinline__ void stage_tile(
    const unsigned short* __restrict__ g, int ld, int r0, int kk,
    unsigned short* lds, int tid)
{
    #pragma unroll
    for (int c = 0; c < 4; ++c) {
        const int ch  = tid + c * 256;              // 0..1023 (16B chunks)
        const int row = ch >> 3;
        const int csw = (ch & 7) ^ (row & 7);       // swizzled source column
        __builtin_amdgcn_global_load_lds(
            (glb_u32*)(g + (size_t)(r0 + row) * ld + kk + csw * 8),
            (lds_u32*)(lds + (size_t)ch * 8), 16, 0, 0);
    }
}

// ---- shared 128x128 GEMM body (2-phase, gload_lds staging, swizzled LDS) ---
static __device__ __forceinline__ void gemm_body(
    const unsigned short* __restrict__ A, int lda,
    const unsigned short* __restrict__ Bm, int ldb,
    int K, int nN,
    unsigned short* __restrict__ C, int ldc,
    const float* __restrict__ bias)
{
    const int nwg = gridDim.x;
    const int bid = blockIdx.x;
    const int swz = (nwg & 7) ? bid : ((bid & 7) * (nwg >> 3) + (bid >> 3));
    const int m0 = (swz / nN) * 128, n0 = (swz % nN) * 128;

    const int tid  = threadIdx.x;
    const int lane = tid & 63, wid = tid >> 6;
    const int wm = wid >> 1, wn = wid & 1;
    const int fr = lane & 15, fq = lane >> 4;

    __shared__ __align__(16) unsigned short smem[2 * 128 * 64];   // 32 KB linear
    unsigned short* As = smem;
    unsigned short* Bs = smem + 128 * 64;

    const f32x4 fz = {0.f, 0.f, 0.f, 0.f};
    f32x4 acc[4][4] = {{fz, fz, fz, fz}, {fz, fz, fz, fz},
                       {fz, fz, fz, fz}, {fz, fz, fz, fz}};

    const int rowA[4] = {wm * 64 + 0 * 16 + fr, wm * 64 + 1 * 16 + fr,
                         wm * 64 + 2 * 16 + fr, wm * 64 + 3 * 16 + fr};
    const int rowB[4] = {wn * 64 + 0 * 16 + fr, wn * 64 + 1 * 16 + fr,
                         wn * 64 + 2 * 16 + fr, wn * 64 + 3 * 16 + fr};

    const int nk = K / 64;
    for (int kt = 0; kt < nk; ++kt) {
        stage_tile(A, lda, m0, kt * 64, As, tid);
        stage_tile(Bm, ldb, n0, kt * 64, Bs, tid);
        __syncthreads();
        #pragma unroll
        for (int ks = 0; ks < 2; ++ks) {
            bf16x8 af[4], bf[4];
            #pragma unroll
            for (int i = 0; i < 4; ++i)
                af[i] = *(const bf16x8*)&As[rowA[i] * 64 +
                         (((ks * 4 + fq) ^ (rowA[i] & 7)) * 8)];
            #pragma unroll
            for (int j = 0; j < 4; ++j)
                bf[j] = *(const bf16x8*)&Bs[rowB[j] * 64 +
                         (((ks * 4 + fq) ^ (rowB[j] & 7)) * 8)];
            #pragma unroll
            for (int i = 0; i < 4; ++i)
                #pragma unroll
                for (int j = 0; j < 4; ++j)
                    acc[i][j] = MFMA16(af[i], bf[j], acc[i][j]);
        }
        __syncthreads();
    }

    auto Cs = (unsigned short(*)[128])smem;
    #pragma unroll
    for (int i = 0; i < 4; ++i)
        #pragma unroll
        for (int j = 0; j < 4; ++j) {
            const float bv = bias ? bias[n0 + wn * 64 + j * 16 + fr] : 0.f;
            #pragma unroll
            for (int r = 0; r < 4; ++r)
                Cs[wm * 64 + i * 16 + fq * 4 + r][wn * 64 + j * 16 + fr] =
                    f2bf(acc[i][j][r] + bv);
        }
    __syncthreads();
    const int r2 = tid >> 4, o2 = (tid & 15) * 8;
    #pragma unroll
    for (int i = 0; i < 8; ++i) {
        const int row = i * 16 + r2;
        *(uint4*)&C[(size_t)(m0 + row) * ldc + n0 + o2] = *(const uint4*)&Cs[row][o2];
    }
}

// ---- merged dispatch: y==0 -> K-gen (bias), y==1 -> t-gemm -----------------
__global__ __launch_bounds__(256)
void gemm_pair(const unsigned short* __restrict__ A0, int lda0,
               const unsigned short* __restrict__ B0, int ldb0, int K0,
               unsigned short* __restrict__ C0, const float* __restrict__ bias0,
               const unsigned short* __restrict__ A1, int lda1,
               const unsigned short* __restrict__ B1, int ldb1, int K1,
               unsigned short* __restrict__ C1, int nN)
{
    if (blockIdx.y == 0)
        gemm_body(A0, lda0, B0, ldb0, K0, nN, C0, GL_, bias0);
    else
        gemm_body(A1, lda1, B1, ldb1, K1, nN, C1, GL_, nullptr);
}

// ---- k_y8: per block 8 edges; wave w computes y[e0+w] = t[e]@K[e]^T --------
__global__ __launch_bounds__(512)
void k_y8(unsigned short* tc, const unsigned short* __restrict__ Kc)
{
    const int e0 = blockIdx.x * 8;
    const int tid = threadIdx.x, lane = tid & 63, w = tid >> 6;
    const int e = e0 + w;
    const int fr = lane & 15, fq = lane >> 4;
    const unsigned short* A  = &tc[(size_t)e * GL_];
    const unsigned short* Bp = &Kc[(size_t)e * GL_];
    const f32x4 fz = {0.f, 0.f, 0.f, 0.f};
    f32x4 acc[4][4] = {{fz, fz, fz, fz}, {fz, fz, fz, fz},
                       {fz, fz, fz, fz}, {fz, fz, fz, fz}};
    #pragma unroll
    for (int ks = 0; ks < 2; ++ks) {
        bf16x8 af[4], bf[4];
        #pragma unroll
        for (int i = 0; i < 4; ++i)
            af[i] = *(const bf16x8*)&A[(i * 16 + fr) * 64 + ks * 32 + fq * 8];
        #pragma unroll
        for (int j = 0; j < 4; ++j)
            bf[j] = *(const bf16x8*)&Bp[(j * 16 + fr) * 64 + ks * 32 + fq * 8];
        #pragma unroll
        for (int i = 0; i < 4; ++i)
            #pragma unroll
            for (int j = 0; j < 4; ++j)
                acc[i][j] = MFMA16(af[i], bf[j], acc[i][j]);
    }
    __shared__ unsigned short y8[GL_ * 8];   // 64KB, [bg][8]
    #pragma unroll
    for (int i = 0; i < 4; ++i)
        #pragma unroll
        for (int j = 0; j < 4; ++j)
            #pragma unroll
            for (int r = 0; r < 4; ++r) {
                const int bg = (i * 16 + fq * 4 + r) * 64 + j * 16 + fr;
                y8[bg * 8 + w] = f2bf(acc[i][j][r]);
            }
    __syncthreads();
    unsigned short* dst = tc + (size_t)e0 * GL_;
    #pragma unroll
    for (int p = 0; p < 8; ++p) {
        const int o = (p * 512 + tid) * 8;
        *(uint4*)&dst[o] = *(const uint4*)&y8[o];
    }
}

// ---- k_accd: planes[pbase+ky] = incB8 @ y8^T, 64x128 tiles, direct loads ---
__global__ __launch_bounds__(256)
void k_accd(const unsigned short* __restrict__ Ae,   // incB8 + e_off*NP_
            const unsigned short* __restrict__ y8,   // chunk tc base
            unsigned short* __restrict__ planesB, int pbase, int K)
{
    const int xcd = blockIdx.x & 7, grp = blockIdx.x >> 3;   // grp 0..31
    const int m0 = (grp & 7) * 64;
    const int n0 = (xcd + 8 * (grp >> 3)) * 128;
    const int KSY = gridDim.y;
    const int kl = ((K / KSY) / 64) * 64;
    const int kbeg = blockIdx.y * kl;
    const int kend = ((int)blockIdx.y == KSY - 1) ? K : kbeg + kl;

    const int lane = threadIdx.x & 63, wid = threadIdx.x >> 6;
    const int wm = wid >> 1, wn = wid & 1;
    const int fr = lane & 15, fq = lane >> 4;

    const f32x4 fz = {0.f, 0.f, 0.f, 0.f};
    f32x4 acc[2][4] = {{fz, fz, fz, fz}, {fz, fz, fz, fz}};

    for (int kk = kbeg; kk < kend; kk += 64) {
        #pragma unroll
        for (int ks = 0; ks < 2; ++ks) {
            const int e8 = kk + ks * 32 + fq * 8;
            const size_t eb = (size_t)(e8 >> 3);
            bf16x8 af[2], bf[4];
            #pragma unroll
            for (int i = 0; i < 2; ++i)
                af[i] = *(const bf16x8*)&Ae[(eb * NP_ + m0 + wm * 32 + i * 16 + fr) * 8];
            #pragma unroll
            for (int j = 0; j < 4; ++j)
                bf[j] = *(const bf16x8*)&y8[eb * GL_ * 8 + (n0 + wn * 64 + j * 16 + fr) * 8];
            #pragma unroll
            for (int i = 0; i < 2; ++i)
                #pragma unroll
                for (int j = 0; j < 4; ++j)
                    acc[i][j] = MFMA16(af[i], bf[j], acc[i][j]);
        }
    }

    unsigned short* pl = planesB + (size_t)(pbase + blockIdx.y) * ACC_ELEMS;
    #pragma unroll
    for (int i = 0; i < 2; ++i)
        #pragma unroll
        for (int j = 0; j < 4; ++j) {
            const int col = n0 + wn * 64 + j * 16 + fr;
            const int b = col >> 6, g = col & 63;
            #pragma unroll
            for (int r = 0; r < 4; ++r) {
                const int n = m0 + wm * 32 + i * 16 + fq * 4 + r;
                if (n < N_)
                    pl[((size_t)b * N_ + n) * G_ + g] = f2bf(acc[i][j][r]);
            }
        }
}

// ======================= prologue / small kernels ===========================
__global__ __launch_bounds__(256)
void k_cvt_incB8(const float* __restrict__ inc, unsigned short* __restrict__ incB8)
{
    const int e0 = blockIdx.x * 64;
    const int n0 = blockIdx.y * 64;
    const int tid = threadIdx.x;
    __shared__ unsigned short sm[64][72];
    const int cl = tid & 63;
    for (int rr = tid >> 6; rr < 64; rr += 4) {
        const int n = n0 + rr;
        sm[rr][cl] = (n < N_) ? f2bf(inc[(size_t)n * E_ + e0 + cl]) : (unsigned short)0;
    }
    __syncthreads();
    const int eb = tid >> 5, idx = tid & 31;
    #pragma unroll
    for (int k = 0; k < 2; ++k) {
        const int row = idx * 2 + k;
        *(ushort8*)&incB8[((size_t)((e0 >> 3) + eb) * NP_ + n0 + row) * 8] =
            *(const ushort8*)&sm[row][eb * 8];
    }
}

__global__ __launch_bounds__(256)
void k_tr32(const float* __restrict__ in, unsigned short* __restrict__ out,
            int R, int C, int Rp, size_t inZ, size_t outZ)
{
    in  += (size_t)blockIdx.z * inZ;
    out += (size_t)blockIdx.z * outZ;
    const int c0 = blockIdx.x * 64, r0 = blockIdx.y * 64;
    __shared__ float sm[64][65];
    const int cl = threadIdx.x & 63;
    for (int rr = threadIdx.x >> 6; rr < 64; rr += 4) {
        const int r = r0 + rr;
        sm[cl][rr] = (r < R) ? in[(size_t)r * C + c0 + cl] : 0.f;
    }
    __syncthreads();
    const int cw = threadIdx.x >> 2, j0 = (threadIdx.x & 3) * 16;
    unsigned short tmp[16];
    #pragma unroll
    for (int j = 0; j < 16; ++j) tmp[j] = f2bf(sm[cw][j0 + j]);
    *(ushort8*)&out[(size_t)(c0 + cw) * Rp + r0 + j0]     = *(ushort8*)&tmp[0];
    *(ushort8*)&out[(size_t)(c0 + cw) * Rp + r0 + j0 + 8] = *(ushort8*)&tmp[8];
}

__global__ __launch_bounds__(256)
void k_h(const float* __restrict__ ef, const float* __restrict__ W1,
         const float* __restrict__ b1, unsigned short* __restrict__ h)
{
    const int idx = blockIdx.x * 256 + threadIdx.x;
    const int e = idx >> 7, hh = idx & 127;
    float v = b1[hh];
    const float* efp = &ef[(size_t)e * F_];
    #pragma unroll
    for (int f = 0; f < F_; ++f) v += efp[f] * W1[f * H_ + hh];
    h[idx] = f2bf(fmaxf(v, 0.f));
}

__global__ __launch_bounds__(256)
void k_final(const unsigned short* __restrict__ planesB, int P,
             const float* __restrict__ bgc, float* __restrict__ out)
{
    const int i = (blockIdx.x * 256 + threadIdx.x) * 8;
    if (i >= ACC_ELEMS) return;
    float s[8];
    #pragma unroll
    for (int j = 0; j < 8; ++j) s[j] = bgc[(i + j) & 63];
    for (int p = 0; p < P; ++p) {
        const ushort8 v = *(const ushort8*)&planesB[(size_t)p * ACC_ELEMS + i];
        #pragma unroll
        for (int j = 0; j < 8; ++j) s[j] += bf2f((unsigned short)v[j]);
    }
    float4 o0, o1;
    o0.x = fmaxf(s[0], 0.f); o0.y = fmaxf(s[1], 0.f);
    o0.z = fmaxf(s[2], 0.f); o0.w = fmaxf(s[3], 0.f);
    o1.x = fmaxf(s[4], 0.f); o1.y = fmaxf(s[5], 0.f);
    o1.z = fmaxf(s[6], 0.f); o1.w = fmaxf(s[7], 0.f);
    *(float4*)&out[i]     = o0;
    *(float4*)&out[i + 4] = o1;
}

extern "C" void kernel_launch(void* const* d_in, const int* in_sizes, int n_in,
                              void* d_out, int out_size, void* d_ws, size_t ws_size,
                              hipStream_t stream) {
    const float* x   = (const float*)d_in[0];
    const float* inc = (const float*)d_in[1];
    const float* ef  = (const float*)d_in[2];
    const float* W1  = (const float*)d_in[3];
    const float* b1  = (const float*)d_in[4];
    const float* W2  = (const float*)d_in[5];
    const float* b2  = (const float*)d_in[6];
    const float* bgc = (const float*)d_in[7];
    float* out = (float*)d_out;

    const size_t persistU16 = (size_t)NP_ * E_      // incB8
                            + (size_t)E_ * NP_      // incT
                            + (size_t)B_ * L_ * NP_ // xT
                            + (size_t)E_ * H_       // h
                            + (size_t)GL_ * H_;     // W2T
    const size_t persistBytes = persistU16 * 2;     // ~41.9 MB

    int nc = 1, Ec = E_;
    for (; nc <= 16; ++nc) {
        Ec = ((E_ + nc - 1) / nc + 127) / 128 * 128;
        const size_t need = persistBytes
                          + (size_t)nc * KS_ * ACC_ELEMS * 2     // bf16 planes
                          + 2 * (size_t)Ec * GL_ * 2;            // K + t chunk
        if (need <= ws_size) break;
    }
    if (nc > 16) { nc = 16; Ec = 1024; }

    unsigned short* planesB = (unsigned short*)d_ws;
    unsigned short* incB8 = planesB + (size_t)nc * KS_ * ACC_ELEMS;
    unsigned short* incT = incB8 + (size_t)NP_ * E_;
    unsigned short* xT   = incT + (size_t)E_ * NP_;
    unsigned short* h    = xT   + (size_t)B_ * L_ * NP_;
    unsigned short* W2T  = h    + (size_t)E_ * H_;
    unsigned short* Kc   = W2T  + (size_t)GL_ * H_;    // [Ec][4096]
    unsigned short* tc   = Kc   + (size_t)Ec * GL_;    // [Ec][4096]; later y8

    k_cvt_incB8<<<dim3(E_ / 64, NP_ / 64), 256, 0, stream>>>(inc, incB8);
    k_tr32<<<dim3(E_ / 64, NP_ / 64, 1), 256, 0, stream>>>(inc, incT, N_, E_, NP_, 0, 0);
    k_tr32<<<dim3(1, NP_ / 64, B_),      256, 0, stream>>>(x, xT, N_, L_, NP_,
                                                           (size_t)N_ * L_, (size_t)L_ * NP_);
    k_tr32<<<dim3(GL_ / 64, H_ / 64, 1), 256, 0, stream>>>(W2, W2T, H_, GL_, H_, 0, 0);
    k_h<<<dim3(E_ * H_ / 256), 256, 0, stream>>>(ef, W1, b1, h);

    int cidx = 0;
    for (int e_off = 0; e_off < E_; e_off += Ec, ++cidx) {
        const int ec = (E_ - e_off) < Ec ? (E_ - e_off) : Ec;   // multiple of 128
        gemm_pair<<<dim3((ec / 128) * 32, 2), 256, 0, stream>>>(
            h + (size_t)e_off * H_, H_, W2T, H_, H_, Kc, b2,
            incT + (size_t)e_off * NP_, NP_, xT, NP_, NP_, tc, 32);
        k_y8<<<dim3(ec / 8), 512, 0, stream>>>(tc, Kc);             // y8 over t
        k_accd<<<dim3(256, KS_), 256, 0, stream>>>(
            incB8 + (size_t)e_off * NP_, tc, planesB, cidx * KS_, ec);
    }

    k_final<<<dim3(ACC_ELEMS / 2048), 256, 0, stream>>>(planesB, nc * KS_, bgc, out);
}

// Round 14
// 373.241 us; speedup vs baseline: 9.6255x; 1.0650x over previous
//
#include <hip/hip_runtime.h>

constexpr int B_ = 64, N_ = 500, E_ = 16000, L_ = 64, G_ = 64, F_ = 8, H_ = 128;
constexpr int GL_ = 4096;     // G*L
constexpr int NP_ = 512;      // n padded
constexpr int KS_ = 4;        // K-split planes per chunk
constexpr int ACC_ELEMS = B_ * N_ * G_;               // 2,048,000

using bf16x8  = __attribute__((ext_vector_type(8))) short;
using f32x4   = __attribute__((ext_vector_type(4))) float;
using ushort8 = __attribute__((ext_vector_type(8))) unsigned short;

#define MFMA16(a, b, c) __builtin_amdgcn_mfma_f32_16x16x32_bf16((a), (b), (c), 0, 0, 0)

typedef __attribute__((address_space(3))) unsigned int       lds_u32;
typedef const __attribute__((address_space(1))) unsigned int glb_u32;

static __device__ __forceinline__ unsigned short f2bf(float f) {
    union { float f; unsigned u; } v; v.f = f;
    unsigned r = v.u + 0x7fffu + ((v.u >> 16) & 1u);
    return (unsigned short)(r >> 16);
}
static __device__ __forceinline__ float bf2f(unsigned short s) {
    union { float f; unsigned u; } v; v.u = ((unsigned)s) << 16;
    return v.f;
}

// stage 128x64 bf16 tile global->LDS, pre-swizzled source (rule #21):
// LDS chunk (row,c) holds global chunk (row, c ^ (row&7)); LDS dest linear.
// 4 global_load_lds instructions per thread (8 per A+B pair -> vmcnt +8/wave).
static __device__ __forceinline__ void stage_tile(
    const unsigned short* __restrict__ g, int ld, int r0, int kk,
    unsigned short* lds, int tid)
{
    #pragma unroll
    for (int c = 0; c < 4; ++c) {
        const int ch  = tid + c * 256;              // 0..1023 (16B chunks)
        const int row = ch >> 3;
        const int csw = (ch & 7) ^ (row & 7);       // swizzled source column
        __builtin_amdgcn_global_load_lds(
            (glb_u32*)(g + (size_t)(r0 + row) * ld + kk + csw * 8),
            (lds_u32*)(lds + (size_t)ch * 8), 16, 0, 0);
    }
}

// ---- 128x128 GEMM body: counted-vmcnt double-buffered pipeline -------------
static __device__ __forceinline__ void gemm_body(
    const unsigned short* __restrict__ A, int lda,
    const unsigned short* __restrict__ Bm, int ldb,
    int K, int nN,
    unsigned short* __restrict__ C, int ldc,
    const float* __restrict__ bias)
{
    const int nwg = gridDim.x;
    const int bid = blockIdx.x;
    const int swz = (nwg & 7) ? bid : ((bid & 7) * (nwg >> 3) + (bid >> 3));
    const int m0 = (swz / nN) * 128, n0 = (swz % nN) * 128;

    const int tid  = threadIdx.x;
    const int lane = tid & 63, wid = tid >> 6;
    const int wm = wid >> 1, wn = wid & 1;
    const int fr = lane & 15, fq = lane >> 4;

    __shared__ __align__(16) unsigned short smem[4 * 128 * 64];   // 64 KB dbuf
    unsigned short* const As0 = smem;
    unsigned short* const Bs0 = smem + 128 * 64;
    unsigned short* const As1 = smem + 2 * 128 * 64;
    unsigned short* const Bs1 = smem + 3 * 128 * 64;

    const f32x4 fz = {0.f, 0.f, 0.f, 0.f};
    f32x4 acc[4][4] = {{fz, fz, fz, fz}, {fz, fz, fz, fz},
                       {fz, fz, fz, fz}, {fz, fz, fz, fz}};

    const int rowA[4] = {wm * 64 + 0 * 16 + fr, wm * 64 + 1 * 16 + fr,
                         wm * 64 + 2 * 16 + fr, wm * 64 + 3 * 16 + fr};
    const int rowB[4] = {wn * 64 + 0 * 16 + fr, wn * 64 + 1 * 16 + fr,
                         wn * 64 + 2 * 16 + fr, wn * 64 + 3 * 16 + fr};

    const int nk = K / 64;
    stage_tile(A, lda, m0, 0, As0, tid);
    stage_tile(Bm, ldb, n0, 0, Bs0, tid);

    for (int kt = 0; kt < nk; ++kt) {
        unsigned short* const Ac = (kt & 1) ? As1 : As0;
        unsigned short* const Bc = (kt & 1) ? Bs1 : Bs0;
        if (kt + 1 < nk) {
            unsigned short* const An = (kt & 1) ? As0 : As1;
            unsigned short* const Bn = (kt & 1) ? Bs0 : Bs1;
            stage_tile(A, lda, m0, (kt + 1) * 64, An, tid);   // prefetch ahead
            stage_tile(Bm, ldb, n0, (kt + 1) * 64, Bn, tid);
            asm volatile("s_waitcnt vmcnt(8)" ::: "memory");  // old tile landed
        } else {
            asm volatile("s_waitcnt vmcnt(0)" ::: "memory");  // drain last tile
        }
        __builtin_amdgcn_s_barrier();
        __builtin_amdgcn_sched_barrier(0);
        #pragma unroll
        for (int ks = 0; ks < 2; ++ks) {
            bf16x8 af[4], bf[4];
            #pragma unroll
            for (int i = 0; i < 4; ++i)
                af[i] = *(const bf16x8*)&Ac[rowA[i] * 64 +
                         (((ks * 4 + fq) ^ (rowA[i] & 7)) * 8)];
            #pragma unroll
            for (int j = 0; j < 4; ++j)
                bf[j] = *(const bf16x8*)&Bc[rowB[j] * 64 +
                         (((ks * 4 + fq) ^ (rowB[j] & 7)) * 8)];
            #pragma unroll
            for (int i = 0; i < 4; ++i)
                #pragma unroll
                for (int j = 0; j < 4; ++j)
                    acc[i][j] = MFMA16(af[i], bf[j], acc[i][j]);
        }
        __builtin_amdgcn_sched_barrier(0);
        __builtin_amdgcn_s_barrier();          // protect buf before restage
    }

    auto Cs = (unsigned short(*)[128])smem;
    #pragma unroll
    for (int i = 0; i < 4; ++i)
        #pragma unroll
        for (int j = 0; j < 4; ++j) {
            const float bv = bias ? bias[n0 + wn * 64 + j * 16 + fr] : 0.f;
            #pragma unroll
            for (int r = 0; r < 4; ++r)
                Cs[wm * 64 + i * 16 + fq * 4 + r][wn * 64 + j * 16 + fr] =
                    f2bf(acc[i][j][r] + bv);
        }
    __syncthreads();
    const int r2 = tid >> 4, o2 = (tid & 15) * 8;
    #pragma unroll
    for (int i = 0; i < 8; ++i) {
        const int row = i * 16 + r2;
        *(uint4*)&C[(size_t)(m0 + row) * ldc + n0 + o2] = *(const uint4*)&Cs[row][o2];
    }
}

// ---- merged dispatch: y==0 -> K-gen (bias), y==1 -> t-gemm -----------------
__global__ __launch_bounds__(256)
void gemm_pair(const unsigned short* __restrict__ A0, int lda0,
               const unsigned short* __restrict__ B0, int ldb0, int K0,
               unsigned short* __restrict__ C0, const float* __restrict__ bias0,
               const unsigned short* __restrict__ A1, int lda1,
               const unsigned short* __restrict__ B1, int ldb1, int K1,
               unsigned short* __restrict__ C1, int nN)
{
    if (blockIdx.y == 0)
        gemm_body(A0, lda0, B0, ldb0, K0, nN, C0, GL_, bias0);
    else
        gemm_body(A1, lda1, B1, ldb1, K1, nN, C1, GL_, nullptr);
}

// ---- k_y8: per block 8 edges; wave w computes y[e0+w] = t[e]@K[e]^T --------
__global__ __launch_bounds__(512)
void k_y8(unsigned short* tc, const unsigned short* __restrict__ Kc)
{
    const int e0 = blockIdx.x * 8;
    const int tid = threadIdx.x, lane = tid & 63, w = tid >> 6;
    const int e = e0 + w;
    const int fr = lane & 15, fq = lane >> 4;
    const unsigned short* A  = &tc[(size_t)e * GL_];
    const unsigned short* Bp = &Kc[(size_t)e * GL_];
    const f32x4 fz = {0.f, 0.f, 0.f, 0.f};
    f32x4 acc[4][4] = {{fz, fz, fz, fz}, {fz, fz, fz, fz},
                       {fz, fz, fz, fz}, {fz, fz, fz, fz}};
    #pragma unroll
    for (int ks = 0; ks < 2; ++ks) {
        bf16x8 af[4], bf[4];
        #pragma unroll
        for (int i = 0; i < 4; ++i)
            af[i] = *(const bf16x8*)&A[(i * 16 + fr) * 64 + ks * 32 + fq * 8];
        #pragma unroll
        for (int j = 0; j < 4; ++j)
            bf[j] = *(const bf16x8*)&Bp[(j * 16 + fr) * 64 + ks * 32 + fq * 8];
        #pragma unroll
        for (int i = 0; i < 4; ++i)
            #pragma unroll
            for (int j = 0; j < 4; ++j)
                acc[i][j] = MFMA16(af[i], bf[j], acc[i][j]);
    }
    __shared__ unsigned short y8[GL_ * 8];   // 64KB, [bg][8]
    #pragma unroll
    for (int i = 0; i < 4; ++i)
        #pragma unroll
        for (int j = 0; j < 4; ++j)
            #pragma unroll
            for (int r = 0; r < 4; ++r) {
                const int bg = (i * 16 + fq * 4 + r) * 64 + j * 16 + fr;
                y8[bg * 8 + w] = f2bf(acc[i][j][r]);
            }
    __syncthreads();
    unsigned short* dst = tc + (size_t)e0 * GL_;
    #pragma unroll
    for (int p = 0; p < 8; ++p) {
        const int o = (p * 512 + tid) * 8;
        *(uint4*)&dst[o] = *(const uint4*)&y8[o];
    }
}

// ---- k_accd: planes[pbase+ky] = incB8 @ y8^T, 64x128 tiles, direct loads ---
__global__ __launch_bounds__(256)
void k_accd(const unsigned short* __restrict__ Ae,   // incB8 + e_off*NP_
            const unsigned short* __restrict__ y8,   // chunk tc base
            unsigned short* __restrict__ planesB, int pbase, int K)
{
    const int xcd = blockIdx.x & 7, grp = blockIdx.x >> 3;   // grp 0..31
    const int m0 = (grp & 7) * 64;
    const int n0 = (xcd + 8 * (grp >> 3)) * 128;
    const int KSY = gridDim.y;
    const int kl = ((K / KSY) / 64) * 64;
    const int kbeg = blockIdx.y * kl;
    const int kend = ((int)blockIdx.y == KSY - 1) ? K : kbeg + kl;

    const int lane = threadIdx.x & 63, wid = threadIdx.x >> 6;
    const int wm = wid >> 1, wn = wid & 1;
    const int fr = lane & 15, fq = lane >> 4;

    const f32x4 fz = {0.f, 0.f, 0.f, 0.f};
    f32x4 acc[2][4] = {{fz, fz, fz, fz}, {fz, fz, fz, fz}};

    for (int kk = kbeg; kk < kend; kk += 64) {
        #pragma unroll
        for (int ks = 0; ks < 2; ++ks) {
            const int e8 = kk + ks * 32 + fq * 8;
            const size_t eb = (size_t)(e8 >> 3);
            bf16x8 af[2], bf[4];
            #pragma unroll
            for (int i = 0; i < 2; ++i)
                af[i] = *(const bf16x8*)&Ae[(eb * NP_ + m0 + wm * 32 + i * 16 + fr) * 8];
            #pragma unroll
            for (int j = 0; j < 4; ++j)
                bf[j] = *(const bf16x8*)&y8[eb * GL_ * 8 + (n0 + wn * 64 + j * 16 + fr) * 8];
            #pragma unroll
            for (int i = 0; i < 2; ++i)
                #pragma unroll
                for (int j = 0; j < 4; ++j)
                    acc[i][j] = MFMA16(af[i], bf[j], acc[i][j]);
        }
    }

    unsigned short* pl = planesB + (size_t)(pbase + blockIdx.y) * ACC_ELEMS;
    #pragma unroll
    for (int i = 0; i < 2; ++i)
        #pragma unroll
        for (int j = 0; j < 4; ++j) {
            const int col = n0 + wn * 64 + j * 16 + fr;
            const int b = col >> 6, g = col & 63;
            #pragma unroll
            for (int r = 0; r < 4; ++r) {
                const int n = m0 + wm * 32 + i * 16 + fq * 4 + r;
                if (n < N_)
                    pl[((size_t)b * N_ + n) * G_ + g] = f2bf(acc[i][j][r]);
            }
        }
}

// ======================= prologue / small kernels ===========================
// merged: read inc tile once -> incT[e][n] (bf16, zero-pad) + incB8[e/8][n][8]
__global__ __launch_bounds__(256)
void k_cvt_inc(const float* __restrict__ inc, unsigned short* __restrict__ incT,
               unsigned short* __restrict__ incB8)
{
    const int e0 = blockIdx.x * 64, n0 = blockIdx.y * 64;
    const int tid = threadIdx.x, cl = tid & 63;
    __shared__ unsigned short sm[64][80];   // [e][n], 160B rows (16B-aligned)
    for (int rr = tid >> 6; rr < 64; rr += 4) {
        const int n = n0 + rr;
        sm[cl][rr] = (n < N_) ? f2bf(inc[(size_t)n * E_ + e0 + cl]) : (unsigned short)0;
    }
    __syncthreads();
    {   // incT rows (e-major, n contiguous)
        const int cw = tid >> 2, j0 = (tid & 3) * 16;
        *(ushort8*)&incT[(size_t)(e0 + cw) * NP_ + n0 + j0]     = *(const ushort8*)&sm[cw][j0];
        *(ushort8*)&incT[(size_t)(e0 + cw) * NP_ + n0 + j0 + 8] = *(const ushort8*)&sm[cw][j0 + 8];
    }
    {   // incB8 e-tiled
        const int eb = tid >> 5, idx = tid & 31;
        #pragma unroll
        for (int k = 0; k < 2; ++k) {
            const int row = idx * 2 + k;
            unsigned short tmp[8];
            #pragma unroll
            for (int q = 0; q < 8; ++q) tmp[q] = sm[eb * 8 + q][row];
            *(ushort8*)&incB8[((size_t)((e0 >> 3) + eb) * NP_ + n0 + row) * 8] =
                *(const ushort8*)&tmp[0];
        }
    }
}

__global__ __launch_bounds__(256)
void k_tr32(const float* __restrict__ in, unsigned short* __restrict__ out,
            int R, int C, int Rp, size_t inZ, size_t outZ)
{
    in  += (size_t)blockIdx.z * inZ;
    out += (size_t)blockIdx.z * outZ;
    const int c0 = blockIdx.x * 64, r0 = blockIdx.y * 64;
    __shared__ float sm[64][65];
    const int cl = threadIdx.x & 63;
    for (int rr = threadIdx.x >> 6; rr < 64; rr += 4) {
        const int r = r0 + rr;
        sm[cl][rr] = (r < R) ? in[(size_t)r * C + c0 + cl] : 0.f;
    }
    __syncthreads();
    const int cw = threadIdx.x >> 2, j0 = (threadIdx.x & 3) * 16;
    unsigned short tmp[16];
    #pragma unroll
    for (int j = 0; j < 16; ++j) tmp[j] = f2bf(sm[cw][j0 + j]);
    *(ushort8*)&out[(size_t)(c0 + cw) * Rp + r0 + j0]     = *(ushort8*)&tmp[0];
    *(ushort8*)&out[(size_t)(c0 + cw) * Rp + r0 + j0 + 8] = *(ushort8*)&tmp[8];
}

__global__ __launch_bounds__(256)
void k_h(const float* __restrict__ ef, const float* __restrict__ W1,
         const float* __restrict__ b1, unsigned short* __restrict__ h)
{
    const int idx = blockIdx.x * 256 + threadIdx.x;
    const int e = idx >> 7, hh = idx & 127;
    float v = b1[hh];
    const float* efp = &ef[(size_t)e * F_];
    #pragma unroll
    for (int f = 0; f < F_; ++f) v += efp[f] * W1[f * H_ + hh];
    h[idx] = f2bf(fmaxf(v, 0.f));
}

__global__ __launch_bounds__(256)
void k_final(const unsigned short* __restrict__ planesB, int P,
             const float* __restrict__ bgc, float* __restrict__ out)
{
    const int i = (blockIdx.x * 256 + threadIdx.x) * 8;
    if (i >= ACC_ELEMS) return;
    float s[8];
    #pragma unroll
    for (int j = 0; j < 8; ++j) s[j] = bgc[(i + j) & 63];
    for (int p = 0; p < P; ++p) {
        const ushort8 v = *(const ushort8*)&planesB[(size_t)p * ACC_ELEMS + i];
        #pragma unroll
        for (int j = 0; j < 8; ++j) s[j] += bf2f((unsigned short)v[j]);
    }
    float4 o0, o1;
    o0.x = fmaxf(s[0], 0.f); o0.y = fmaxf(s[1], 0.f);
    o0.z = fmaxf(s[2], 0.f); o0.w = fmaxf(s[3], 0.f);
    o1.x = fmaxf(s[4], 0.f); o1.y = fmaxf(s[5], 0.f);
    o1.z = fmaxf(s[6], 0.f); o1.w = fmaxf(s[7], 0.f);
    *(float4*)&out[i]     = o0;
    *(float4*)&out[i + 4] = o1;
}

extern "C" void kernel_launch(void* const* d_in, const int* in_sizes, int n_in,
                              void* d_out, int out_size, void* d_ws, size_t ws_size,
                              hipStream_t stream) {
    const float* x   = (const float*)d_in[0];
    const float* inc = (const float*)d_in[1];
    const float* ef  = (const float*)d_in[2];
    const float* W1  = (const float*)d_in[3];
    const float* b1  = (const float*)d_in[4];
    const float* W2  = (const float*)d_in[5];
    const float* b2  = (const float*)d_in[6];
    const float* bgc = (const float*)d_in[7];
    float* out = (float*)d_out;

    const size_t persistU16 = (size_t)NP_ * E_      // incB8
                            + (size_t)E_ * NP_      // incT
                            + (size_t)B_ * L_ * NP_ // xT
                            + (size_t)E_ * H_       // h
                            + (size_t)GL_ * H_;     // W2T
    const size_t persistBytes = persistU16 * 2;     // ~41.9 MB

    int nc = 1, Ec = E_;
    for (; nc <= 16; ++nc) {
        Ec = ((E_ + nc - 1) / nc + 127) / 128 * 128;
        const size_t need = persistBytes
                          + (size_t)nc * KS_ * ACC_ELEMS * 2     // bf16 planes
                          + 2 * (size_t)Ec * GL_ * 2;            // K + t chunk
        if (need <= ws_size) break;
    }
    if (nc > 16) { nc = 16; Ec = 1024; }

    unsigned short* planesB = (unsigned short*)d_ws;
    unsigned short* incB8 = planesB + (size_t)nc * KS_ * ACC_ELEMS;
    unsigned short* incT = incB8 + (size_t)NP_ * E_;
    unsigned short* xT   = incT + (size_t)E_ * NP_;
    unsigned short* h    = xT   + (size_t)B_ * L_ * NP_;
    unsigned short* W2T  = h    + (size_t)E_ * H_;
    unsigned short* Kc   = W2T  + (size_t)GL_ * H_;    // [Ec][4096]
    unsigned short* tc   = Kc   + (size_t)Ec * GL_;    // [Ec][4096]; later y8

    k_cvt_inc<<<dim3(E_ / 64, NP_ / 64), 256, 0, stream>>>(inc, incT, incB8);
    k_tr32<<<dim3(1, NP_ / 64, B_),      256, 0, stream>>>(x, xT, N_, L_, NP_,
                                                           (size_t)N_ * L_, (size_t)L_ * NP_);
    k_tr32<<<dim3(GL_ / 64, H_ / 64, 1), 256, 0, stream>>>(W2, W2T, H_, GL_, H_, 0, 0);
    k_h<<<dim3(E_ * H_ / 256), 256, 0, stream>>>(ef, W1, b1, h);

    int cidx = 0;
    for (int e_off = 0; e_off < E_; e_off += Ec, ++cidx) {
        const int ec = (E_ - e_off) < Ec ? (E_ - e_off) : Ec;   // multiple of 128
        gemm_pair<<<dim3((ec / 128) * 32, 2), 256, 0, stream>>>(
            h + (size_t)e_off * H_, H_, W2T, H_, H_, Kc, b2,
            incT + (size_t)e_off * NP_, NP_, xT, NP_, NP_, tc, 32);
        k_y8<<<dim3(ec / 8), 512, 0, stream>>>(tc, Kc);             // y8 over t
        k_accd<<<dim3(256, KS_), 256, 0, stream>>>(
            incB8 + (size_t)e_off * NP_, tc, planesB, cidx * KS_, ec);
    }

    k_final<<<dim3(ACC_ELEMS / 2048), 256, 0, stream>>>(planesB, nc * KS_, bgc, out);
}

// Round 15
// 366.594 us; speedup vs baseline: 9.8000x; 1.0181x over previous
//
#include <hip/hip_runtime.h>

constexpr int B_ = 64, N_ = 500, E_ = 16000, L_ = 64, G_ = 64, F_ = 8, H_ = 128;
constexpr int GL_ = 4096;     // G*L
constexpr int NP_ = 512;      // n padded
constexpr int KS_ = 4;        // K-split planes per chunk
constexpr int ACC_ELEMS = B_ * N_ * G_;               // 2,048,000

using bf16x8  = __attribute__((ext_vector_type(8))) short;
using f32x4   = __attribute__((ext_vector_type(4))) float;
using ushort8 = __attribute__((ext_vector_type(8))) unsigned short;

#define MFMA16(a, b, c) __builtin_amdgcn_mfma_f32_16x16x32_bf16((a), (b), (c), 0, 0, 0)

typedef __attribute__((address_space(3))) unsigned int       lds_u32;
typedef const __attribute__((address_space(1))) unsigned int glb_u32;

static __device__ __forceinline__ unsigned short f2bf(float f) {
    union { float f; unsigned u; } v; v.f = f;
    unsigned r = v.u + 0x7fffu + ((v.u >> 16) & 1u);
    return (unsigned short)(r >> 16);
}
static __device__ __forceinline__ float bf2f(unsigned short s) {
    union { float f; unsigned u; } v; v.u = ((unsigned)s) << 16;
    return v.f;
}

// stage 128x32 bf16 tile (8 KB = 512 x 16B chunks) global->LDS, pre-swizzled
// source (rule #21): LDS chunk (row,c) holds global chunk (row, c^((row>>1)&3)).
// 2 load-insts per thread per tile -> 4 per A+B pair (vmcnt units).
static __device__ __forceinline__ void stage32(
    const unsigned short* __restrict__ g, int ld, int r0, int kk,
    unsigned short* lds, int tid)
{
    #pragma unroll
    for (int c = 0; c < 2; ++c) {
        const int ch  = tid + c * 256;              // 0..511
        const int row = ch >> 2;
        const int csw = (ch & 3) ^ ((row >> 1) & 3);
        __builtin_amdgcn_global_load_lds(
            (glb_u32*)(g + (size_t)(r0 + row) * ld + kk + csw * 8),
            (lds_u32*)(lds + (size_t)ch * 8), 16, 0, 0);
    }
}

// ---- 128x128 GEMM body: BK=32, 3-buffer, depth-2 counted-vmcnt pipeline ----
static __device__ __forceinline__ void gemm_body(
    const unsigned short* __restrict__ A, int lda,
    const unsigned short* __restrict__ Bm, int ldb,
    int K, int nN,
    unsigned short* __restrict__ C, int ldc,
    const float* __restrict__ bias)
{
    const int nwg = gridDim.x;
    const int bid = blockIdx.x;
    const int swz = (nwg & 7) ? bid : ((bid & 7) * (nwg >> 3) + (bid >> 3));
    const int m0 = (swz / nN) * 128, n0 = (swz % nN) * 128;

    const int tid  = threadIdx.x;
    const int lane = tid & 63, wid = tid >> 6;
    const int wm = wid >> 1, wn = wid & 1;
    const int fr = lane & 15, fq = lane >> 4;

    __shared__ __align__(16) unsigned short smem[3 * 8192];   // 48 KB: 3x(A+B)

    const f32x4 fz = {0.f, 0.f, 0.f, 0.f};
    f32x4 acc[4][4] = {{fz, fz, fz, fz}, {fz, fz, fz, fz},
                       {fz, fz, fz, fz}, {fz, fz, fz, fz}};

    const int rowA[4] = {wm * 64 + 0 * 16 + fr, wm * 64 + 1 * 16 + fr,
                         wm * 64 + 2 * 16 + fr, wm * 64 + 3 * 16 + fr};
    const int rowB[4] = {wn * 64 + 0 * 16 + fr, wn * 64 + 1 * 16 + fr,
                         wn * 64 + 2 * 16 + fr, wn * 64 + 3 * 16 + fr};
    int cA[4], cB[4];
    #pragma unroll
    for (int i = 0; i < 4; ++i) {
        cA[i] = (fq ^ ((rowA[i] >> 1) & 3)) * 8;
        cB[i] = (fq ^ ((rowB[i] >> 1) & 3)) * 8;
    }

    const int nk = K / 32;
    stage32(A, lda, m0, 0, smem, tid);                 // pair 0 -> buf 0
    stage32(Bm, ldb, n0, 0, smem + 4096, tid);
    stage32(A, lda, m0, 32, smem + 8192, tid);         // pair 1 -> buf 1
    stage32(Bm, ldb, n0, 32, smem + 8192 + 4096, tid);

    int cur = 0;
    for (int kt = 0; kt < nk; ++kt) {
        unsigned short* const As = smem + cur * 8192;
        unsigned short* const Bs = As + 4096;
        if (kt + 2 < nk) {
            int nxt = cur + 2; if (nxt >= 3) nxt -= 3;
            unsigned short* const An = smem + nxt * 8192;
            stage32(A, lda, m0, (kt + 2) * 32, An, tid);
            stage32(Bm, ldb, n0, (kt + 2) * 32, An + 4096, tid);
            asm volatile("s_waitcnt vmcnt(8)" ::: "memory");   // pair kt landed
        } else if (kt + 1 < nk) {
            asm volatile("s_waitcnt vmcnt(4)" ::: "memory");
        } else {
            asm volatile("s_waitcnt vmcnt(0)" ::: "memory");
        }
        __builtin_amdgcn_s_barrier();
        __builtin_amdgcn_sched_barrier(0);
        {
            bf16x8 af[4], bf[4];
            #pragma unroll
            for (int i = 0; i < 4; ++i)
                af[i] = *(const bf16x8*)&As[rowA[i] * 32 + cA[i]];
            #pragma unroll
            for (int j = 0; j < 4; ++j)
                bf[j] = *(const bf16x8*)&Bs[rowB[j] * 32 + cB[j]];
            #pragma unroll
            for (int i = 0; i < 4; ++i)
                #pragma unroll
                for (int j = 0; j < 4; ++j)
                    acc[i][j] = MFMA16(af[i], bf[j], acc[i][j]);
        }
        __builtin_amdgcn_sched_barrier(0);
        __builtin_amdgcn_s_barrier();          // protect buf before restage
        cur = (cur + 1 == 3) ? 0 : cur + 1;
    }

    auto Cs = (unsigned short(*)[128])smem;    // 32 KB of the 48 KB
    #pragma unroll
    for (int i = 0; i < 4; ++i)
        #pragma unroll
        for (int j = 0; j < 4; ++j) {
            const float bv = bias ? bias[n0 + wn * 64 + j * 16 + fr] : 0.f;
            #pragma unroll
            for (int r = 0; r < 4; ++r)
                Cs[wm * 64 + i * 16 + fq * 4 + r][wn * 64 + j * 16 + fr] =
                    f2bf(acc[i][j][r] + bv);
        }
    __syncthreads();
    const int r2 = tid >> 4, o2 = (tid & 15) * 8;
    #pragma unroll
    for (int i = 0; i < 8; ++i) {
        const int row = i * 16 + r2;
        *(uint4*)&C[(size_t)(m0 + row) * ldc + n0 + o2] = *(const uint4*)&Cs[row][o2];
    }
}

// ---- merged dispatch: y==0 -> K-gen (bias), y==1 -> t-gemm -----------------
__global__ __launch_bounds__(256)
void gemm_pair(const unsigned short* __restrict__ A0, int lda0,
               const unsigned short* __restrict__ B0, int ldb0, int K0,
               unsigned short* __restrict__ C0, const float* __restrict__ bias0,
               const unsigned short* __restrict__ A1, int lda1,
               const unsigned short* __restrict__ B1, int ldb1, int K1,
               unsigned short* __restrict__ C1, int nN)
{
    if (blockIdx.y == 0)
        gemm_body(A0, lda0, B0, ldb0, K0, nN, C0, GL_, bias0);
    else
        gemm_body(A1, lda1, B1, ldb1, K1, nN, C1, GL_, nullptr);
}

// ---- k_y8: per block 8 edges; wave w computes y[e0+w] = t[e]@K[e]^T --------
__global__ __launch_bounds__(512)
void k_y8(unsigned short* tc, const unsigned short* __restrict__ Kc)
{
    const int e0 = blockIdx.x * 8;
    const int tid = threadIdx.x, lane = tid & 63, w = tid >> 6;
    const int e = e0 + w;
    const int fr = lane & 15, fq = lane >> 4;
    const unsigned short* A  = &tc[(size_t)e * GL_];
    const unsigned short* Bp = &Kc[(size_t)e * GL_];
    const f32x4 fz = {0.f, 0.f, 0.f, 0.f};
    f32x4 acc[4][4] = {{fz, fz, fz, fz}, {fz, fz, fz, fz},
                       {fz, fz, fz, fz}, {fz, fz, fz, fz}};
    #pragma unroll
    for (int ks = 0; ks < 2; ++ks) {
        bf16x8 af[4], bf[4];
        #pragma unroll
        for (int i = 0; i < 4; ++i)
            af[i] = *(const bf16x8*)&A[(i * 16 + fr) * 64 + ks * 32 + fq * 8];
        #pragma unroll
        for (int j = 0; j < 4; ++j)
            bf[j] = *(const bf16x8*)&Bp[(j * 16 + fr) * 64 + ks * 32 + fq * 8];
        #pragma unroll
        for (int i = 0; i < 4; ++i)
            #pragma unroll
            for (int j = 0; j < 4; ++j)
                acc[i][j] = MFMA16(af[i], bf[j], acc[i][j]);
    }
    __shared__ unsigned short y8[GL_ * 8];   // 64KB, [bg][8]
    #pragma unroll
    for (int i = 0; i < 4; ++i)
        #pragma unroll
        for (int j = 0; j < 4; ++j)
            #pragma unroll
            for (int r = 0; r < 4; ++r) {
                const int bg = (i * 16 + fq * 4 + r) * 64 + j * 16 + fr;
                y8[bg * 8 + w] = f2bf(acc[i][j][r]);
            }
    __syncthreads();
    unsigned short* dst = tc + (size_t)e0 * GL_;
    #pragma unroll
    for (int p = 0; p < 8; ++p) {
        const int o = (p * 512 + tid) * 8;
        *(uint4*)&dst[o] = *(const uint4*)&y8[o];
    }
}

// ---- k_accd: planes[pbase+ky] = incB8 @ y8^T, 64x128 tiles, direct loads ---
__global__ __launch_bounds__(256)
void k_accd(const unsigned short* __restrict__ Ae,   // incB8 + e_off*NP_
            const unsigned short* __restrict__ y8,   // chunk tc base
            unsigned short* __restrict__ planesB, int pbase, int K)
{
    const int xcd = blockIdx.x & 7, grp = blockIdx.x >> 3;   // grp 0..31
    const int m0 = (grp & 7) * 64;
    const int n0 = (xcd + 8 * (grp >> 3)) * 128;
    const int KSY = gridDim.y;
    const int kl = ((K / KSY) / 64) * 64;
    const int kbeg = blockIdx.y * kl;
    const int kend = ((int)blockIdx.y == KSY - 1) ? K : kbeg + kl;

    const int lane = threadIdx.x & 63, wid = threadIdx.x >> 6;
    const int wm = wid >> 1, wn = wid & 1;
    const int fr = lane & 15, fq = lane >> 4;

    const f32x4 fz = {0.f, 0.f, 0.f, 0.f};
    f32x4 acc[2][4] = {{fz, fz, fz, fz}, {fz, fz, fz, fz}};

    for (int kk = kbeg; kk < kend; kk += 64) {
        #pragma unroll
        for (int ks = 0; ks < 2; ++ks) {
            const int e8 = kk + ks * 32 + fq * 8;
            const size_t eb = (size_t)(e8 >> 3);
            bf16x8 af[2], bf[4];
            #pragma unroll
            for (int i = 0; i < 2; ++i)
                af[i] = *(const bf16x8*)&Ae[(eb * NP_ + m0 + wm * 32 + i * 16 + fr) * 8];
            #pragma unroll
            for (int j = 0; j < 4; ++j)
                bf[j] = *(const bf16x8*)&y8[eb * GL_ * 8 + (n0 + wn * 64 + j * 16 + fr) * 8];
            #pragma unroll
            for (int i = 0; i < 2; ++i)
                #pragma unroll
                for (int j = 0; j < 4; ++j)
                    acc[i][j] = MFMA16(af[i], bf[j], acc[i][j]);
        }
    }

    unsigned short* pl = planesB + (size_t)(pbase + blockIdx.y) * ACC_ELEMS;
    #pragma unroll
    for (int i = 0; i < 2; ++i)
        #pragma unroll
        for (int j = 0; j < 4; ++j) {
            const int col = n0 + wn * 64 + j * 16 + fr;
            const int b = col >> 6, g = col & 63;
            #pragma unroll
            for (int r = 0; r < 4; ++r) {
                const int n = m0 + wm * 32 + i * 16 + fq * 4 + r;
                if (n < N_)
                    pl[((size_t)b * N_ + n) * G_ + g] = f2bf(acc[i][j][r]);
            }
        }
}

// ======================= prologue / small kernels ===========================
// merged: read inc tile once -> incT[e][n] (bf16, zero-pad) + incB8[e/8][n][8]
__global__ __launch_bounds__(256)
void k_cvt_inc(const float* __restrict__ inc, unsigned short* __restrict__ incT,
               unsigned short* __restrict__ incB8)
{
    const int e0 = blockIdx.x * 64, n0 = blockIdx.y * 64;
    const int tid = threadIdx.x, cl = tid & 63;
    __shared__ unsigned short sm[64][80];   // [e][n]
    for (int rr = tid >> 6; rr < 64; rr += 4) {
        const int n = n0 + rr;
        sm[cl][rr] = (n < N_) ? f2bf(inc[(size_t)n * E_ + e0 + cl]) : (unsigned short)0;
    }
    __syncthreads();
    {   // incT rows (e-major, n contiguous)
        const int cw = tid >> 2, j0 = (tid & 3) * 16;
        *(ushort8*)&incT[(size_t)(e0 + cw) * NP_ + n0 + j0]     = *(const ushort8*)&sm[cw][j0];
        *(ushort8*)&incT[(size_t)(e0 + cw) * NP_ + n0 + j0 + 8] = *(const ushort8*)&sm[cw][j0 + 8];
    }
    {   // incB8 e-tiled
        const int eb = tid >> 5, idx = tid & 31;
        #pragma unroll
        for (int k = 0; k < 2; ++k) {
            const int row = idx * 2 + k;
            unsigned short tmp[8];
            #pragma unroll
            for (int q = 0; q < 8; ++q) tmp[q] = sm[eb * 8 + q][row];
            *(ushort8*)&incB8[((size_t)((e0 >> 3) + eb) * NP_ + n0 + row) * 8] =
                *(const ushort8*)&tmp[0];
        }
    }
}

__global__ __launch_bounds__(256)
void k_tr32(const float* __restrict__ in, unsigned short* __restrict__ out,
            int R, int C, int Rp, size_t inZ, size_t outZ)
{
    in  += (size_t)blockIdx.z * inZ;
    out += (size_t)blockIdx.z * outZ;
    const int c0 = blockIdx.x * 64, r0 = blockIdx.y * 64;
    __shared__ float sm[64][65];
    const int cl = threadIdx.x & 63;
    for (int rr = threadIdx.x >> 6; rr < 64; rr += 4) {
        const int r = r0 + rr;
        sm[cl][rr] = (r < R) ? in[(size_t)r * C + c0 + cl] : 0.f;
    }
    __syncthreads();
    const int cw = threadIdx.x >> 2, j0 = (threadIdx.x & 3) * 16;
    unsigned short tmp[16];
    #pragma unroll
    for (int j = 0; j < 16; ++j) tmp[j] = f2bf(sm[cw][j0 + j]);
    *(ushort8*)&out[(size_t)(c0 + cw) * Rp + r0 + j0]     = *(ushort8*)&tmp[0];
    *(ushort8*)&out[(size_t)(c0 + cw) * Rp + r0 + j0 + 8] = *(ushort8*)&tmp[8];
}

__global__ __launch_bounds__(256)
void k_h(const float* __restrict__ ef, const float* __restrict__ W1,
         const float* __restrict__ b1, unsigned short* __restrict__ h)
{
    const int idx = blockIdx.x * 256 + threadIdx.x;
    const int e = idx >> 7, hh = idx & 127;
    float v = b1[hh];
    const float* efp = &ef[(size_t)e * F_];
    #pragma unroll
    for (int f = 0; f < F_; ++f) v += efp[f] * W1[f * H_ + hh];
    h[idx] = f2bf(fmaxf(v, 0.f));
}

__global__ __launch_bounds__(256)
void k_final(const unsigned short* __restrict__ planesB, int P,
             const float* __restrict__ bgc, float* __restrict__ out)
{
    const int i = (blockIdx.x * 256 + threadIdx.x) * 8;
    if (i >= ACC_ELEMS) return;
    float s[8];
    #pragma unroll
    for (int j = 0; j < 8; ++j) s[j] = bgc[(i + j) & 63];
    for (int p = 0; p < P; ++p) {
        const ushort8 v = *(const ushort8*)&planesB[(size_t)p * ACC_ELEMS + i];
        #pragma unroll
        for (int j = 0; j < 8; ++j) s[j] += bf2f((unsigned short)v[j]);
    }
    float4 o0, o1;
    o0.x = fmaxf(s[0], 0.f); o0.y = fmaxf(s[1], 0.f);
    o0.z = fmaxf(s[2], 0.f); o0.w = fmaxf(s[3], 0.f);
    o1.x = fmaxf(s[4], 0.f); o1.y = fmaxf(s[5], 0.f);
    o1.z = fmaxf(s[6], 0.f); o1.w = fmaxf(s[7], 0.f);
    *(float4*)&out[i]     = o0;
    *(float4*)&out[i + 4] = o1;
}

extern "C" void kernel_launch(void* const* d_in, const int* in_sizes, int n_in,
                              void* d_out, int out_size, void* d_ws, size_t ws_size,
                              hipStream_t stream) {
    const float* x   = (const float*)d_in[0];
    const float* inc = (const float*)d_in[1];
    const float* ef  = (const float*)d_in[2];
    const float* W1  = (const float*)d_in[3];
    const float* b1  = (const float*)d_in[4];
    const float* W2  = (const float*)d_in[5];
    const float* b2  = (const float*)d_in[6];
    const float* bgc = (const float*)d_in[7];
    float* out = (float*)d_out;

    const size_t persistU16 = (size_t)NP_ * E_      // incB8
                            + (size_t)E_ * NP_      // incT
                            + (size_t)B_ * L_ * NP_ // xT
                            + (size_t)E_ * H_       // h
                            + (size_t)GL_ * H_;     // W2T
    const size_t persistBytes = persistU16 * 2;     // ~41.9 MB

    int nc = 1, Ec = E_;
    for (; nc <= 16; ++nc) {
        Ec = ((E_ + nc - 1) / nc + 127) / 128 * 128;
        const size_t need = persistBytes
                          + (size_t)nc * KS_ * ACC_ELEMS * 2     // bf16 planes
                          + 2 * (size_t)Ec * GL_ * 2;            // K + t chunk
        if (need <= ws_size) break;
    }
    if (nc > 16) { nc = 16; Ec = 1024; }

    unsigned short* planesB = (unsigned short*)d_ws;
    unsigned short* incB8 = planesB + (size_t)nc * KS_ * ACC_ELEMS;
    unsigned short* incT = incB8 + (size_t)NP_ * E_;
    unsigned short* xT   = incT + (size_t)E_ * NP_;
    unsigned short* h    = xT   + (size_t)B_ * L_ * NP_;
    unsigned short* W2T  = h    + (size_t)E_ * H_;
    unsigned short* Kc   = W2T  + (size_t)GL_ * H_;    // [Ec][4096]
    unsigned short* tc   = Kc   + (size_t)Ec * GL_;    // [Ec][4096]; later y8

    k_cvt_inc<<<dim3(E_ / 64, NP_ / 64), 256, 0, stream>>>(inc, incT, incB8);
    k_tr32<<<dim3(1, NP_ / 64, B_),      256, 0, stream>>>(x, xT, N_, L_, NP_,
                                                           (size_t)N_ * L_, (size_t)L_ * NP_);
    k_tr32<<<dim3(GL_ / 64, H_ / 64, 1), 256, 0, stream>>>(W2, W2T, H_, GL_, H_, 0, 0);
    k_h<<<dim3(E_ * H_ / 256), 256, 0, stream>>>(ef, W1, b1, h);

    int cidx = 0;
    for (int e_off = 0; e_off < E_; e_off += Ec, ++cidx) {
        const int ec = (E_ - e_off) < Ec ? (E_ - e_off) : Ec;   // multiple of 128
        gemm_pair<<<dim3((ec / 128) * 32, 2), 256, 0, stream>>>(
            h + (size_t)e_off * H_, H_, W2T, H_, H_, Kc, b2,
            incT + (size_t)e_off * NP_, NP_, xT, NP_, NP_, tc, 32);
        k_y8<<<dim3(ec / 8), 512, 0, stream>>>(tc, Kc);             // y8 over t
        k_accd<<<dim3(256, KS_), 256, 0, stream>>>(
            incB8 + (size_t)e_off * NP_, tc, planesB, cidx * KS_, ec);
    }

    k_final<<<dim3(ACC_ELEMS / 2048), 256, 0, stream>>>(planesB, nc * KS_, bgc, out);
}

// Round 16
// 351.318 us; speedup vs baseline: 10.2261x; 1.0435x over previous
//
#include <hip/hip_runtime.h>

constexpr int B_ = 64, N_ = 500, E_ = 16000, L_ = 64, G_ = 64, F_ = 8, H_ = 128;
constexpr int GL_ = 4096;     // G*L
constexpr int NP_ = 512;      // n padded
constexpr int KS_ = 4;        // K-split planes per chunk
constexpr int ACC_ELEMS = B_ * N_ * G_;               // 2,048,000

using bf16x8  = __attribute__((ext_vector_type(8))) short;
using f32x4   = __attribute__((ext_vector_type(4))) float;
using ushort8 = __attribute__((ext_vector_type(8))) unsigned short;

#define MFMA16(a, b, c) __builtin_amdgcn_mfma_f32_16x16x32_bf16((a), (b), (c), 0, 0, 0)

typedef __attribute__((address_space(3))) unsigned int       lds_u32;
typedef const __attribute__((address_space(1))) unsigned int glb_u32;

static __device__ __forceinline__ unsigned short f2bf(float f) {
    union { float f; unsigned u; } v; v.f = f;
    unsigned r = v.u + 0x7fffu + ((v.u >> 16) & 1u);
    return (unsigned short)(r >> 16);
}
static __device__ __forceinline__ float bf2f(unsigned short s) {
    union { float f; unsigned u; } v; v.u = ((unsigned)s) << 16;
    return v.f;
}

// stage 128x32 bf16 tile (8 KB = 512 x 16B chunks) global->LDS, pre-swizzled
// source (rule #21): LDS chunk (row,c) holds global chunk (row, c^((row>>1)&3)).
static __device__ __forceinline__ void stage32(
    const unsigned short* __restrict__ g, int ld, int r0, int kk,
    unsigned short* lds, int tid)
{
    #pragma unroll
    for (int c = 0; c < 2; ++c) {
        const int ch  = tid + c * 256;              // 0..511
        const int row = ch >> 2;
        const int csw = (ch & 3) ^ ((row >> 1) & 3);
        __builtin_amdgcn_global_load_lds(
            (glb_u32*)(g + (size_t)(r0 + row) * ld + kk + csw * 8),
            (lds_u32*)(lds + (size_t)ch * 8), 16, 0, 0);
    }
}

// ---- 128x128 GEMM body: BK=32, 3-buffer, depth-2 counted-vmcnt pipeline ----
static __device__ __forceinline__ void gemm_body(
    const unsigned short* __restrict__ A, int lda,
    const unsigned short* __restrict__ Bm, int ldb,
    int K, int nN,
    unsigned short* __restrict__ C, int ldc,
    const float* __restrict__ bias)
{
    const int nwg = gridDim.x;
    const int bid = blockIdx.x;
    const int swz = (nwg & 7) ? bid : ((bid & 7) * (nwg >> 3) + (bid >> 3));
    const int m0 = (swz / nN) * 128, n0 = (swz % nN) * 128;

    const int tid  = threadIdx.x;
    const int lane = tid & 63, wid = tid >> 6;
    const int wm = wid >> 1, wn = wid & 1;
    const int fr = lane & 15, fq = lane >> 4;

    __shared__ __align__(16) unsigned short smem[3 * 8192];   // 48 KB: 3x(A+B)

    const f32x4 fz = {0.f, 0.f, 0.f, 0.f};
    f32x4 acc[4][4] = {{fz, fz, fz, fz}, {fz, fz, fz, fz},
                       {fz, fz, fz, fz}, {fz, fz, fz, fz}};

    const int rowA[4] = {wm * 64 + 0 * 16 + fr, wm * 64 + 1 * 16 + fr,
                         wm * 64 + 2 * 16 + fr, wm * 64 + 3 * 16 + fr};
    const int rowB[4] = {wn * 64 + 0 * 16 + fr, wn * 64 + 1 * 16 + fr,
                         wn * 64 + 2 * 16 + fr, wn * 64 + 3 * 16 + fr};
    int cA[4], cB[4];
    #pragma unroll
    for (int i = 0; i < 4; ++i) {
        cA[i] = (fq ^ ((rowA[i] >> 1) & 3)) * 8;
        cB[i] = (fq ^ ((rowB[i] >> 1) & 3)) * 8;
    }

    const int nk = K / 32;
    stage32(A, lda, m0, 0, smem, tid);                 // pair 0 -> buf 0
    stage32(Bm, ldb, n0, 0, smem + 4096, tid);
    stage32(A, lda, m0, 32, smem + 8192, tid);         // pair 1 -> buf 1
    stage32(Bm, ldb, n0, 32, smem + 8192 + 4096, tid);

    int cur = 0;
    for (int kt = 0; kt < nk; ++kt) {
        unsigned short* const As = smem + cur * 8192;
        unsigned short* const Bs = As + 4096;
        if (kt + 2 < nk) {
            int nxt = cur + 2; if (nxt >= 3) nxt -= 3;
            unsigned short* const An = smem + nxt * 8192;
            stage32(A, lda, m0, (kt + 2) * 32, An, tid);
            stage32(Bm, ldb, n0, (kt + 2) * 32, An + 4096, tid);
            asm volatile("s_waitcnt vmcnt(8)" ::: "memory");   // pair kt landed
        } else if (kt + 1 < nk) {
            asm volatile("s_waitcnt vmcnt(4)" ::: "memory");
        } else {
            asm volatile("s_waitcnt vmcnt(0)" ::: "memory");
        }
        __builtin_amdgcn_s_barrier();
        __builtin_amdgcn_sched_barrier(0);
        {
            bf16x8 af[4], bf[4];
            #pragma unroll
            for (int i = 0; i < 4; ++i)
                af[i] = *(const bf16x8*)&As[rowA[i] * 32 + cA[i]];
            #pragma unroll
            for (int j = 0; j < 4; ++j)
                bf[j] = *(const bf16x8*)&Bs[rowB[j] * 32 + cB[j]];
            #pragma unroll
            for (int i = 0; i < 4; ++i)
                #pragma unroll
                for (int j = 0; j < 4; ++j)
                    acc[i][j] = MFMA16(af[i], bf[j], acc[i][j]);
        }
        __builtin_amdgcn_sched_barrier(0);
        __builtin_amdgcn_s_barrier();          // protect buf before restage
        cur = (cur + 1 == 3) ? 0 : cur + 1;
    }

    auto Cs = (unsigned short(*)[128])smem;    // 32 KB of the 48 KB
    #pragma unroll
    for (int i = 0; i < 4; ++i)
        #pragma unroll
        for (int j = 0; j < 4; ++j) {
            const float bv = bias ? bias[n0 + wn * 64 + j * 16 + fr] : 0.f;
            #pragma unroll
            for (int r = 0; r < 4; ++r)
                Cs[wm * 64 + i * 16 + fq * 4 + r][wn * 64 + j * 16 + fr] =
                    f2bf(acc[i][j][r] + bv);
        }
    __syncthreads();
    const int r2 = tid >> 4, o2 = (tid & 15) * 8;
    #pragma unroll
    for (int i = 0; i < 8; ++i) {
        const int row = i * 16 + r2;
        *(uint4*)&C[(size_t)(m0 + row) * ldc + n0 + o2] = *(const uint4*)&Cs[row][o2];
    }
}

// ---- merged dispatch: y==0 -> K-gen (bias), y==1 -> t-gemm -----------------
__global__ __launch_bounds__(256)
void gemm_pair(const unsigned short* __restrict__ A0, int lda0,
               const unsigned short* __restrict__ B0, int ldb0, int K0,
               unsigned short* __restrict__ C0, const float* __restrict__ bias0,
               const unsigned short* __restrict__ A1, int lda1,
               const unsigned short* __restrict__ B1, int ldb1, int K1,
               unsigned short* __restrict__ C1, int nN)
{
    if (blockIdx.y == 0)
        gemm_body(A0, lda0, B0, ldb0, K0, nN, C0, GL_, bias0);
    else
        gemm_body(A1, lda1, B1, ldb1, K1, nN, C1, GL_, nullptr);
}

// ---- k_y8: per block 8 edges; wave w computes y[e0+w] = t[e]@K[e]^T --------
__global__ __launch_bounds__(512)
void k_y8(unsigned short* tc, const unsigned short* __restrict__ Kc)
{
    const int e0 = blockIdx.x * 8;
    const int tid = threadIdx.x, lane = tid & 63, w = tid >> 6;
    const int e = e0 + w;
    const int fr = lane & 15, fq = lane >> 4;
    const unsigned short* A  = &tc[(size_t)e * GL_];
    const unsigned short* Bp = &Kc[(size_t)e * GL_];
    const f32x4 fz = {0.f, 0.f, 0.f, 0.f};
    f32x4 acc[4][4] = {{fz, fz, fz, fz}, {fz, fz, fz, fz},
                       {fz, fz, fz, fz}, {fz, fz, fz, fz}};
    #pragma unroll
    for (int ks = 0; ks < 2; ++ks) {
        bf16x8 af[4], bf[4];
        #pragma unroll
        for (int i = 0; i < 4; ++i)
            af[i] = *(const bf16x8*)&A[(i * 16 + fr) * 64 + ks * 32 + fq * 8];
        #pragma unroll
        for (int j = 0; j < 4; ++j)
            bf[j] = *(const bf16x8*)&Bp[(j * 16 + fr) * 64 + ks * 32 + fq * 8];
        #pragma unroll
        for (int i = 0; i < 4; ++i)
            #pragma unroll
            for (int j = 0; j < 4; ++j)
                acc[i][j] = MFMA16(af[i], bf[j], acc[i][j]);
    }
    __shared__ unsigned short y8[GL_ * 8];   // 64KB, [bg][8]
    #pragma unroll
    for (int i = 0; i < 4; ++i)
        #pragma unroll
        for (int j = 0; j < 4; ++j)
            #pragma unroll
            for (int r = 0; r < 4; ++r) {
                const int bg = (i * 16 + fq * 4 + r) * 64 + j * 16 + fr;
                y8[bg * 8 + w] = f2bf(acc[i][j][r]);
            }
    __syncthreads();
    unsigned short* dst = tc + (size_t)e0 * GL_;
    #pragma unroll
    for (int p = 0; p < 8; ++p) {
        const int o = (p * 512 + tid) * 8;
        *(uint4*)&dst[o] = *(const uint4*)&y8[o];
    }
}

// ---- k_accd: planes[pbase+ky] = incB8 @ y8^T, 64x128 tiles, direct loads ---
__global__ __launch_bounds__(256)
void k_accd(const unsigned short* __restrict__ Ae,   // incB8 + e_off*NP_
            const unsigned short* __restrict__ y8,   // chunk tc base
            unsigned short* __restrict__ planesB, int pbase, int K)
{
    const int xcd = blockIdx.x & 7, grp = blockIdx.x >> 3;   // grp 0..31
    const int m0 = (grp & 7) * 64;
    const int n0 = (xcd + 8 * (grp >> 3)) * 128;
    const int KSY = gridDim.y;
    const int kl = ((K / KSY) / 64) * 64;
    const int kbeg = blockIdx.y * kl;
    const int kend = ((int)blockIdx.y == KSY - 1) ? K : kbeg + kl;

    const int lane = threadIdx.x & 63, wid = threadIdx.x >> 6;
    const int wm = wid >> 1, wn = wid & 1;
    const int fr = lane & 15, fq = lane >> 4;

    const f32x4 fz = {0.f, 0.f, 0.f, 0.f};
    f32x4 acc[2][4] = {{fz, fz, fz, fz}, {fz, fz, fz, fz}};

    for (int kk = kbeg; kk < kend; kk += 64) {
        #pragma unroll
        for (int ks = 0; ks < 2; ++ks) {
            const int e8 = kk + ks * 32 + fq * 8;
            const size_t eb = (size_t)(e8 >> 3);
            bf16x8 af[2], bf[4];
            #pragma unroll
            for (int i = 0; i < 2; ++i)
                af[i] = *(const bf16x8*)&Ae[(eb * NP_ + m0 + wm * 32 + i * 16 + fr) * 8];
            #pragma unroll
            for (int j = 0; j < 4; ++j)
                bf[j] = *(const bf16x8*)&y8[eb * GL_ * 8 + (n0 + wn * 64 + j * 16 + fr) * 8];
            #pragma unroll
            for (int i = 0; i < 2; ++i)
                #pragma unroll
                for (int j = 0; j < 4; ++j)
                    acc[i][j] = MFMA16(af[i], bf[j], acc[i][j]);
        }
    }

    unsigned short* pl = planesB + (size_t)(pbase + blockIdx.y) * ACC_ELEMS;
    #pragma unroll
    for (int i = 0; i < 2; ++i)
        #pragma unroll
        for (int j = 0; j < 4; ++j) {
            const int col = n0 + wn * 64 + j * 16 + fr;
            const int b = col >> 6, g = col & 63;
            #pragma unroll
            for (int r = 0; r < 4; ++r) {
                const int n = m0 + wm * 32 + i * 16 + fq * 4 + r;
                if (n < N_)
                    pl[((size_t)b * N_ + n) * G_ + g] = f2bf(acc[i][j][r]);
            }
        }
}

// ======================= merged prologue (1 dispatch) =======================
// ranges: [0,2000) inc-cvt | [2000,2512) x-transpose | [2512,2640) W2T |
//         [2640,10640) h-MLP. All sub-tasks independent (read inputs only).
constexpr int PREP_CVT = 2000, PREP_XT = 2512, PREP_W2 = 2640, PREP_NB = 10640;

__global__ __launch_bounds__(256)
void k_prep(const float* __restrict__ x, const float* __restrict__ inc,
            const float* __restrict__ ef, const float* __restrict__ W1,
            const float* __restrict__ b1, const float* __restrict__ W2,
            unsigned short* __restrict__ incT, unsigned short* __restrict__ incB8,
            unsigned short* __restrict__ xT, unsigned short* __restrict__ W2T,
            unsigned short* __restrict__ h)
{
    __shared__ __align__(16) char smraw[64 * 65 * 4];   // union: u16[64][80] / f32[64][65]
    const int q = blockIdx.x;
    const int tid = threadIdx.x;

    if (q < PREP_CVT) {
        // inc tile -> incT[e][n] + incB8[e/8][n][8]
        auto sm = (unsigned short(*)[80])smraw;
        const int e0 = (q % 250) * 64, n0 = (q / 250) * 64;
        const int cl = tid & 63;
        for (int rr = tid >> 6; rr < 64; rr += 4) {
            const int n = n0 + rr;
            sm[cl][rr] = (n < N_) ? f2bf(inc[(size_t)n * E_ + e0 + cl]) : (unsigned short)0;
        }
        __syncthreads();
        {
            const int cw = tid >> 2, j0 = (tid & 3) * 16;
            *(ushort8*)&incT[(size_t)(e0 + cw) * NP_ + n0 + j0]     = *(const ushort8*)&sm[cw][j0];
            *(ushort8*)&incT[(size_t)(e0 + cw) * NP_ + n0 + j0 + 8] = *(const ushort8*)&sm[cw][j0 + 8];
        }
        {
            const int eb = tid >> 5, idx = tid & 31;
            #pragma unroll
            for (int k = 0; k < 2; ++k) {
                const int row = idx * 2 + k;
                unsigned short tmp[8];
                #pragma unroll
                for (int p = 0; p < 8; ++p) tmp[p] = sm[eb * 8 + p][row];
                *(ushort8*)&incB8[((size_t)((e0 >> 3) + eb) * NP_ + n0 + row) * 8] =
                    *(const ushort8*)&tmp[0];
            }
        }
    } else if (q < PREP_W2) {
        // f32 [R][C] -> bf16 [C][Rp] transpose (x or W2)
        auto sm = (float(*)[65])smraw;
        const float* in; unsigned short* out;
        int R, C, Rp, c0, r0;
        if (q < PREP_XT) {            // x: per-batch [500][64] -> [64][512]
            const int t = q - PREP_CVT, z = t >> 3, by = t & 7;
            in = x + (size_t)z * N_ * L_; out = xT + (size_t)z * L_ * NP_;
            R = N_; C = L_; Rp = NP_; c0 = 0; r0 = by * 64;
        } else {                      // W2: [128][4096] -> [4096][128]
            const int t = q - PREP_XT;
            in = W2; out = W2T;
            R = H_; C = GL_; Rp = H_; c0 = (t & 63) * 64; r0 = (t >> 6) * 64;
        }
        const int cl = tid & 63;
        for (int rr = tid >> 6; rr < 64; rr += 4) {
            const int r = r0 + rr;
            sm[cl][rr] = (r < R) ? in[(size_t)r * C + c0 + cl] : 0.f;
        }
        __syncthreads();
        const int cw = tid >> 2, j0 = (tid & 3) * 16;
        unsigned short tmp[16];
        #pragma unroll
        for (int j = 0; j < 16; ++j) tmp[j] = f2bf(sm[cw][j0 + j]);
        *(ushort8*)&out[(size_t)(c0 + cw) * Rp + r0 + j0]     = *(ushort8*)&tmp[0];
        *(ushort8*)&out[(size_t)(c0 + cw) * Rp + r0 + j0 + 8] = *(ushort8*)&tmp[8];
    } else {
        // h = relu(ef @ W1 + b1)
        const int idx = (q - PREP_W2) * 256 + tid;
        const int e = idx >> 7, hh = idx & 127;
        float v = b1[hh];
        const float* efp = &ef[(size_t)e * F_];
        #pragma unroll
        for (int f = 0; f < F_; ++f) v += efp[f] * W1[f * H_ + hh];
        h[idx] = f2bf(fmaxf(v, 0.f));
    }
}

// ---- final: out = relu(sum_p bf16 planes[p] + bgc), single d_out write -----
__global__ __launch_bounds__(256)
void k_final(const unsigned short* __restrict__ planesB, int P,
             const float* __restrict__ bgc, float* __restrict__ out)
{
    const int i = (blockIdx.x * 256 + threadIdx.x) * 8;
    if (i >= ACC_ELEMS) return;
    float s[8];
    #pragma unroll
    for (int j = 0; j < 8; ++j) s[j] = bgc[(i + j) & 63];
    for (int p = 0; p < P; ++p) {
        const ushort8 v = *(const ushort8*)&planesB[(size_t)p * ACC_ELEMS + i];
        #pragma unroll
        for (int j = 0; j < 8; ++j) s[j] += bf2f((unsigned short)v[j]);
    }
    float4 o0, o1;
    o0.x = fmaxf(s[0], 0.f); o0.y = fmaxf(s[1], 0.f);
    o0.z = fmaxf(s[2], 0.f); o0.w = fmaxf(s[3], 0.f);
    o1.x = fmaxf(s[4], 0.f); o1.y = fmaxf(s[5], 0.f);
    o1.z = fmaxf(s[6], 0.f); o1.w = fmaxf(s[7], 0.f);
    *(float4*)&out[i]     = o0;
    *(float4*)&out[i + 4] = o1;
}

extern "C" void kernel_launch(void* const* d_in, const int* in_sizes, int n_in,
                              void* d_out, int out_size, void* d_ws, size_t ws_size,
                              hipStream_t stream) {
    const float* x   = (const float*)d_in[0];
    const float* inc = (const float*)d_in[1];
    const float* ef  = (const float*)d_in[2];
    const float* W1  = (const float*)d_in[3];
    const float* b1  = (const float*)d_in[4];
    const float* W2  = (const float*)d_in[5];
    const float* b2  = (const float*)d_in[6];
    const float* bgc = (const float*)d_in[7];
    float* out = (float*)d_out;

    const size_t persistU16 = (size_t)NP_ * E_      // incB8
                            + (size_t)E_ * NP_      // incT
                            + (size_t)B_ * L_ * NP_ // xT
                            + (size_t)E_ * H_       // h
                            + (size_t)GL_ * H_;     // W2T
    const size_t persistBytes = persistU16 * 2;     // ~41.9 MB

    int nc = 1, Ec = E_;
    for (; nc <= 16; ++nc) {
        Ec = ((E_ + nc - 1) / nc + 127) / 128 * 128;
        const size_t need = persistBytes
                          + (size_t)nc * KS_ * ACC_ELEMS * 2     // bf16 planes
                          + 2 * (size_t)Ec * GL_ * 2;            // K + t chunk
        if (need <= ws_size) break;
    }
    if (nc > 16) { nc = 16; Ec = 1024; }

    unsigned short* planesB = (unsigned short*)d_ws;
    unsigned short* incB8 = planesB + (size_t)nc * KS_ * ACC_ELEMS;
    unsigned short* incT = incB8 + (size_t)NP_ * E_;
    unsigned short* xT   = incT + (size_t)E_ * NP_;
    unsigned short* h    = xT   + (size_t)B_ * L_ * NP_;
    unsigned short* W2T  = h    + (size_t)E_ * H_;
    unsigned short* Kc   = W2T  + (size_t)GL_ * H_;    // [Ec][4096]
    unsigned short* tc   = Kc   + (size_t)Ec * GL_;    // [Ec][4096]; later y8

    k_prep<<<dim3(PREP_NB), 256, 0, stream>>>(x, inc, ef, W1, b1, W2,
                                              incT, incB8, xT, W2T, h);

    int cidx = 0;
    for (int e_off = 0; e_off < E_; e_off += Ec, ++cidx) {
        const int ec = (E_ - e_off) < Ec ? (E_ - e_off) : Ec;   // multiple of 128
        gemm_pair<<<dim3((ec / 128) * 32, 2), 256, 0, stream>>>(
            h + (size_t)e_off * H_, H_, W2T, H_, H_, Kc, b2,
            incT + (size_t)e_off * NP_, NP_, xT, NP_, NP_, tc, 32);
        k_y8<<<dim3(ec / 8), 512, 0, stream>>>(tc, Kc);             // y8 over t
        k_accd<<<dim3(256, KS_), 256, 0, stream>>>(
            incB8 + (size_t)e_off * NP_, tc, planesB, cidx * KS_, ec);
    }

    k_final<<<dim3(ACC_ELEMS / 2048), 256, 0, stream>>>(planesB, nc * KS_, bgc, out);
}

// Round 17
// 345.668 us; speedup vs baseline: 10.3932x; 1.0163x over previous
//
#include <hip/hip_runtime.h>

constexpr int B_ = 64, N_ = 500, E_ = 16000, L_ = 64, G_ = 64, F_ = 8, H_ = 128;
constexpr int GL_ = 4096;     // G*L
constexpr int NP_ = 512;      // n padded
constexpr int KS_ = 4;        // K-split planes per chunk
constexpr int ACC_ELEMS = B_ * N_ * G_;               // 2,048,000

using bf16x8  = __attribute__((ext_vector_type(8))) short;
using f32x4   = __attribute__((ext_vector_type(4))) float;
using ushort8 = __attribute__((ext_vector_type(8))) unsigned short;

#define MFMA16(a, b, c) __builtin_amdgcn_mfma_f32_16x16x32_bf16((a), (b), (c), 0, 0, 0)

typedef __attribute__((address_space(3))) unsigned int       lds_u32;
typedef const __attribute__((address_space(1))) unsigned int glb_u32;

static __device__ __forceinline__ unsigned short f2bf(float f) {
    union { float f; unsigned u; } v; v.f = f;
    unsigned r = v.u + 0x7fffu + ((v.u >> 16) & 1u);
    return (unsigned short)(r >> 16);
}
static __device__ __forceinline__ float bf2f(unsigned short s) {
    union { float f; unsigned u; } v; v.u = ((unsigned)s) << 16;
    return v.f;
}

// stage 128x32 bf16 tile (8 KB = 512 x 16B chunks) global->LDS, pre-swizzled
// source (rule #21): LDS chunk (row,c) holds global chunk (row, c^((row>>1)&3)).
static __device__ __forceinline__ void stage32(
    const unsigned short* __restrict__ g, int ld, int r0, int kk,
    unsigned short* lds, int tid)
{
    #pragma unroll
    for (int c = 0; c < 2; ++c) {
        const int ch  = tid + c * 256;              // 0..511
        const int row = ch >> 2;
        const int csw = (ch & 3) ^ ((row >> 1) & 3);
        __builtin_amdgcn_global_load_lds(
            (glb_u32*)(g + (size_t)(r0 + row) * ld + kk + csw * 8),
            (lds_u32*)(lds + (size_t)ch * 8), 16, 0, 0);
    }
}

// ---- 128x128 GEMM body: BK=32, 3-buffer, depth-2, ONE barrier per K-step ---
static __device__ __forceinline__ void gemm_body(
    const unsigned short* __restrict__ A, int lda,
    const unsigned short* __restrict__ Bm, int ldb,
    int K, int nN,
    unsigned short* __restrict__ C, int ldc,
    const float* __restrict__ bias)
{
    const int nwg = gridDim.x;
    const int bid = blockIdx.x;
    const int swz = (nwg & 7) ? bid : ((bid & 7) * (nwg >> 3) + (bid >> 3));
    const int m0 = (swz / nN) * 128, n0 = (swz % nN) * 128;

    const int tid  = threadIdx.x;
    const int lane = tid & 63, wid = tid >> 6;
    const int wm = wid >> 1, wn = wid & 1;
    const int fr = lane & 15, fq = lane >> 4;

    __shared__ __align__(16) unsigned short smem[3 * 8192];   // 48 KB: 3x(A+B)

    const f32x4 fz = {0.f, 0.f, 0.f, 0.f};
    f32x4 acc[4][4] = {{fz, fz, fz, fz}, {fz, fz, fz, fz},
                       {fz, fz, fz, fz}, {fz, fz, fz, fz}};

    const int rowA[4] = {wm * 64 + 0 * 16 + fr, wm * 64 + 1 * 16 + fr,
                         wm * 64 + 2 * 16 + fr, wm * 64 + 3 * 16 + fr};
    const int rowB[4] = {wn * 64 + 0 * 16 + fr, wn * 64 + 1 * 16 + fr,
                         wn * 64 + 2 * 16 + fr, wn * 64 + 3 * 16 + fr};
    int cA[4], cB[4];
    #pragma unroll
    for (int i = 0; i < 4; ++i) {
        cA[i] = (fq ^ ((rowA[i] >> 1) & 3)) * 8;
        cB[i] = (fq ^ ((rowB[i] >> 1) & 3)) * 8;
    }

    const int nk = K / 32;
    stage32(A, lda, m0, 0, smem, tid);                 // tile 0 -> buf 0
    stage32(Bm, ldb, n0, 0, smem + 4096, tid);
    stage32(A, lda, m0, 32, smem + 8192, tid);         // tile 1 -> buf 1
    stage32(Bm, ldb, n0, 32, smem + 8192 + 4096, tid);

    int cur = 0;
    for (int kt = 0; kt < nk; ++kt) {
        // ensure THIS tile's loads landed (self), then sync all waves.
        if (kt + 1 < nk) {
            asm volatile("s_waitcnt vmcnt(4)" ::: "memory");
        } else {
            asm volatile("s_waitcnt vmcnt(0)" ::: "memory");
        }
        __builtin_amdgcn_s_barrier();
        __builtin_amdgcn_sched_barrier(0);
        // barrier ordered all reads of buf[(kt-1)%3] == target buf -> safe.
        if (kt + 2 < nk) {
            int nxt = cur + 2; if (nxt >= 3) nxt -= 3;
            unsigned short* const An = smem + nxt * 8192;
            stage32(A, lda, m0, (kt + 2) * 32, An, tid);
            stage32(Bm, ldb, n0, (kt + 2) * 32, An + 4096, tid);
        }
        unsigned short* const As = smem + cur * 8192;
        unsigned short* const Bs = As + 4096;
        {
            bf16x8 af[4], bf[4];
            #pragma unroll
            for (int i = 0; i < 4; ++i)
                af[i] = *(const bf16x8*)&As[rowA[i] * 32 + cA[i]];
            #pragma unroll
            for (int j = 0; j < 4; ++j)
                bf[j] = *(const bf16x8*)&Bs[rowB[j] * 32 + cB[j]];
            #pragma unroll
            for (int i = 0; i < 4; ++i)
                #pragma unroll
                for (int j = 0; j < 4; ++j)
                    acc[i][j] = MFMA16(af[i], bf[j], acc[i][j]);
        }
        __builtin_amdgcn_sched_barrier(0);
        cur = (cur + 1 == 3) ? 0 : cur + 1;
    }

    __syncthreads();                           // loop reads done before Cs reuse
    auto Cs = (unsigned short(*)[128])smem;    // 32 KB of the 48 KB
    #pragma unroll
    for (int i = 0; i < 4; ++i)
        #pragma unroll
        for (int j = 0; j < 4; ++j) {
            const float bv = bias ? bias[n0 + wn * 64 + j * 16 + fr] : 0.f;
            #pragma unroll
            for (int r = 0; r < 4; ++r)
                Cs[wm * 64 + i * 16 + fq * 4 + r]
                  [(wn * 64 + j * 16 + fr) ^ (fq << 3)] =      // bank swizzle
                    f2bf(acc[i][j][r] + bv);
        }
    __syncthreads();
    const int r2 = tid >> 4, o2 = (tid & 15) * 8;
    #pragma unroll
    for (int i = 0; i < 8; ++i) {
        const int row = i * 16 + r2;
        const int o2s = o2 ^ (((row >> 2) & 3) << 3);          // undo swizzle
        *(uint4*)&C[(size_t)(m0 + row) * ldc + n0 + o2] = *(const uint4*)&Cs[row][o2s];
    }
}

// ---- merged dispatch: y==0 -> K-gen (bias), y==1 -> t-gemm -----------------
__global__ __launch_bounds__(256)
void gemm_pair(const unsigned short* __restrict__ A0, int lda0,
               const unsigned short* __restrict__ B0, int ldb0, int K0,
               unsigned short* __restrict__ C0, const float* __restrict__ bias0,
               const unsigned short* __restrict__ A1, int lda1,
               const unsigned short* __restrict__ B1, int ldb1, int K1,
               unsigned short* __restrict__ C1, int nN)
{
    if (blockIdx.y == 0)
        gemm_body(A0, lda0, B0, ldb0, K0, nN, C0, GL_, bias0);
    else
        gemm_body(A1, lda1, B1, ldb1, K1, nN, C1, GL_, nullptr);
}

// ---- k_y8: per block 8 edges; wave w computes y[e0+w] = t[e]@K[e]^T --------
__global__ __launch_bounds__(512)
void k_y8(unsigned short* tc, const unsigned short* __restrict__ Kc)
{
    const int e0 = blockIdx.x * 8;
    const int tid = threadIdx.x, lane = tid & 63, w = tid >> 6;
    const int e = e0 + w;
    const int fr = lane & 15, fq = lane >> 4;
    const unsigned short* A  = &tc[(size_t)e * GL_];
    const unsigned short* Bp = &Kc[(size_t)e * GL_];
    const f32x4 fz = {0.f, 0.f, 0.f, 0.f};
    f32x4 acc[4][4] = {{fz, fz, fz, fz}, {fz, fz, fz, fz},
                       {fz, fz, fz, fz}, {fz, fz, fz, fz}};
    #pragma unroll
    for (int ks = 0; ks < 2; ++ks) {
        bf16x8 af[4], bf[4];
        #pragma unroll
        for (int i = 0; i < 4; ++i)
            af[i] = *(const bf16x8*)&A[(i * 16 + fr) * 64 + ks * 32 + fq * 8];
        #pragma unroll
        for (int j = 0; j < 4; ++j)
            bf[j] = *(const bf16x8*)&Bp[(j * 16 + fr) * 64 + ks * 32 + fq * 8];
        #pragma unroll
        for (int i = 0; i < 4; ++i)
            #pragma unroll
            for (int j = 0; j < 4; ++j)
                acc[i][j] = MFMA16(af[i], bf[j], acc[i][j]);
    }
    __shared__ unsigned short y8[GL_ * 8];   // 64KB, [bg][8]
    #pragma unroll
    for (int i = 0; i < 4; ++i)
        #pragma unroll
        for (int j = 0; j < 4; ++j)
            #pragma unroll
            for (int r = 0; r < 4; ++r) {
                const int bg = (i * 16 + fq * 4 + r) * 64 + j * 16 + fr;
                y8[bg * 8 + w] = f2bf(acc[i][j][r]);
            }
    __syncthreads();
    unsigned short* dst = tc + (size_t)e0 * GL_;
    #pragma unroll
    for (int p = 0; p < 8; ++p) {
        const int o = (p * 512 + tid) * 8;
        *(uint4*)&dst[o] = *(const uint4*)&y8[o];
    }
}

// ---- k_accd: planes[pbase+ky] = incB8 @ y8^T, 64x128 tiles, direct loads ---
__global__ __launch_bounds__(256)
void k_accd(const unsigned short* __restrict__ Ae,   // incB8 + e_off*NP_
            const unsigned short* __restrict__ y8,   // chunk tc base
            unsigned short* __restrict__ planesB, int pbase, int K)
{
    const int xcd = blockIdx.x & 7, grp = blockIdx.x >> 3;   // grp 0..31
    const int m0 = (grp & 7) * 64;
    const int n0 = (xcd + 8 * (grp >> 3)) * 128;
    const int KSY = gridDim.y;
    const int kl = ((K / KSY) / 64) * 64;
    const int kbeg = blockIdx.y * kl;
    const int kend = ((int)blockIdx.y == KSY - 1) ? K : kbeg + kl;

    const int lane = threadIdx.x & 63, wid = threadIdx.x >> 6;
    const int wm = wid >> 1, wn = wid & 1;
    const int fr = lane & 15, fq = lane >> 4;

    const f32x4 fz = {0.f, 0.f, 0.f, 0.f};
    f32x4 acc[2][4] = {{fz, fz, fz, fz}, {fz, fz, fz, fz}};

    for (int kk = kbeg; kk < kend; kk += 64) {
        #pragma unroll
        for (int ks = 0; ks < 2; ++ks) {
            const int e8 = kk + ks * 32 + fq * 8;
            const size_t eb = (size_t)(e8 >> 3);
            bf16x8 af[2], bf[4];
            #pragma unroll
            for (int i = 0; i < 2; ++i)
                af[i] = *(const bf16x8*)&Ae[(eb * NP_ + m0 + wm * 32 + i * 16 + fr) * 8];
            #pragma unroll
            for (int j = 0; j < 4; ++j)
                bf[j] = *(const bf16x8*)&y8[eb * GL_ * 8 + (n0 + wn * 64 + j * 16 + fr) * 8];
            #pragma unroll
            for (int i = 0; i < 2; ++i)
                #pragma unroll
                for (int j = 0; j < 4; ++j)
                    acc[i][j] = MFMA16(af[i], bf[j], acc[i][j]);
        }
    }

    unsigned short* pl = planesB + (size_t)(pbase + blockIdx.y) * ACC_ELEMS;
    #pragma unroll
    for (int i = 0; i < 2; ++i)
        #pragma unroll
        for (int j = 0; j < 4; ++j) {
            const int col = n0 + wn * 64 + j * 16 + fr;
            const int b = col >> 6, g = col & 63;
            #pragma unroll
            for (int r = 0; r < 4; ++r) {
                const int n = m0 + wm * 32 + i * 16 + fq * 4 + r;
                if (n < N_)
                    pl[((size_t)b * N_ + n) * G_ + g] = f2bf(acc[i][j][r]);
            }
        }
}

// ======================= merged prologue (1 dispatch) =======================
constexpr int PREP_CVT = 2000, PREP_XT = 2512, PREP_W2 = 2640, PREP_NB = 10640;

__global__ __launch_bounds__(256)
void k_prep(const float* __restrict__ x, const float* __restrict__ inc,
            const float* __restrict__ ef, const float* __restrict__ W1,
            const float* __restrict__ b1, const float* __restrict__ W2,
            unsigned short* __restrict__ incT, unsigned short* __restrict__ incB8,
            unsigned short* __restrict__ xT, unsigned short* __restrict__ W2T,
            unsigned short* __restrict__ h)
{
    __shared__ __align__(16) char smraw[64 * 65 * 4];
    const int q = blockIdx.x;
    const int tid = threadIdx.x;

    if (q < PREP_CVT) {
        auto sm = (unsigned short(*)[80])smraw;
        const int e0 = (q % 250) * 64, n0 = (q / 250) * 64;
        const int cl = tid & 63;
        for (int rr = tid >> 6; rr < 64; rr += 4) {
            const int n = n0 + rr;
            sm[cl][rr] = (n < N_) ? f2bf(inc[(size_t)n * E_ + e0 + cl]) : (unsigned short)0;
        }
        __syncthreads();
        {
            const int cw = tid >> 2, j0 = (tid & 3) * 16;
            *(ushort8*)&incT[(size_t)(e0 + cw) * NP_ + n0 + j0]     = *(const ushort8*)&sm[cw][j0];
            *(ushort8*)&incT[(size_t)(e0 + cw) * NP_ + n0 + j0 + 8] = *(const ushort8*)&sm[cw][j0 + 8];
        }
        {
            const int eb = tid >> 5, idx = tid & 31;
            #pragma unroll
            for (int k = 0; k < 2; ++k) {
                const int row = idx * 2 + k;
                unsigned short tmp[8];
                #pragma unroll
                for (int p = 0; p < 8; ++p) tmp[p] = sm[eb * 8 + p][row];
                *(ushort8*)&incB8[((size_t)((e0 >> 3) + eb) * NP_ + n0 + row) * 8] =
                    *(const ushort8*)&tmp[0];
            }
        }
    } else if (q < PREP_W2) {
        auto sm = (float(*)[65])smraw;
        const float* in; unsigned short* out;
        int R, C, Rp, c0, r0;
        if (q < PREP_XT) {
            const int t = q - PREP_CVT, z = t >> 3, by = t & 7;
            in = x + (size_t)z * N_ * L_; out = xT + (size_t)z * L_ * NP_;
            R = N_; C = L_; Rp = NP_; c0 = 0; r0 = by * 64;
        } else {
            const int t = q - PREP_XT;
            in = W2; out = W2T;
            R = H_; C = GL_; Rp = H_; c0 = (t & 63) * 64; r0 = (t >> 6) * 64;
        }
        const int cl = tid & 63;
        for (int rr = tid >> 6; rr < 64; rr += 4) {
            const int r = r0 + rr;
            sm[cl][rr] = (r < R) ? in[(size_t)r * C + c0 + cl] : 0.f;
        }
        __syncthreads();
        const int cw = tid >> 2, j0 = (tid & 3) * 16;
        unsigned short tmp[16];
        #pragma unroll
        for (int j = 0; j < 16; ++j) tmp[j] = f2bf(sm[cw][j0 + j]);
        *(ushort8*)&out[(size_t)(c0 + cw) * Rp + r0 + j0]     = *(ushort8*)&tmp[0];
        *(ushort8*)&out[(size_t)(c0 + cw) * Rp + r0 + j0 + 8] = *(ushort8*)&tmp[8];
    } else {
        const int idx = (q - PREP_W2) * 256 + tid;
        const int e = idx >> 7, hh = idx & 127;
        float v = b1[hh];
        const float* efp = &ef[(size_t)e * F_];
        #pragma unroll
        for (int f = 0; f < F_; ++f) v += efp[f] * W1[f * H_ + hh];
        h[idx] = f2bf(fmaxf(v, 0.f));
    }
}

// ---- final: out = relu(sum_p bf16 planes[p] + bgc), single d_out write -----
__global__ __launch_bounds__(256)
void k_final(const unsigned short* __restrict__ planesB, int P,
             const float* __restrict__ bgc, float* __restrict__ out)
{
    const int i = (blockIdx.x * 256 + threadIdx.x) * 8;
    if (i >= ACC_ELEMS) return;
    float s[8];
    #pragma unroll
    for (int j = 0; j < 8; ++j) s[j] = bgc[(i + j) & 63];
    for (int p = 0; p < P; ++p) {
        const ushort8 v = *(const ushort8*)&planesB[(size_t)p * ACC_ELEMS + i];
        #pragma unroll
        for (int j = 0; j < 8; ++j) s[j] += bf2f((unsigned short)v[j]);
    }
    float4 o0, o1;
    o0.x = fmaxf(s[0], 0.f); o0.y = fmaxf(s[1], 0.f);
    o0.z = fmaxf(s[2], 0.f); o0.w = fmaxf(s[3], 0.f);
    o1.x = fmaxf(s[4], 0.f); o1.y = fmaxf(s[5], 0.f);
    o1.z = fmaxf(s[6], 0.f); o1.w = fmaxf(s[7], 0.f);
    *(float4*)&out[i]     = o0;
    *(float4*)&out[i + 4] = o1;
}

extern "C" void kernel_launch(void* const* d_in, const int* in_sizes, int n_in,
                              void* d_out, int out_size, void* d_ws, size_t ws_size,
                              hipStream_t stream) {
    const float* x   = (const float*)d_in[0];
    const float* inc = (const float*)d_in[1];
    const float* ef  = (const float*)d_in[2];
    const float* W1  = (const float*)d_in[3];
    const float* b1  = (const float*)d_in[4];
    const float* W2  = (const float*)d_in[5];
    const float* b2  = (const float*)d_in[6];
    const float* bgc = (const float*)d_in[7];
    float* out = (float*)d_out;

    const size_t persistU16 = (size_t)NP_ * E_      // incB8
                            + (size_t)E_ * NP_      // incT
                            + (size_t)B_ * L_ * NP_ // xT
                            + (size_t)E_ * H_       // h
                            + (size_t)GL_ * H_;     // W2T
    const size_t persistBytes = persistU16 * 2;     // ~41.9 MB

    int nc = 1, Ec = E_;
    for (; nc <= 16; ++nc) {
        Ec = ((E_ + nc - 1) / nc + 127) / 128 * 128;
        const size_t need = persistBytes
                          + (size_t)nc * KS_ * ACC_ELEMS * 2     // bf16 planes
                          + 2 * (size_t)Ec * GL_ * 2;            // K + t chunk
        if (need <= ws_size) break;
    }
    if (nc > 16) { nc = 16; Ec = 1024; }

    unsigned short* planesB = (unsigned short*)d_ws;
    unsigned short* incB8 = planesB + (size_t)nc * KS_ * ACC_ELEMS;
    unsigned short* incT = incB8 + (size_t)NP_ * E_;
    unsigned short* xT   = incT + (size_t)E_ * NP_;
    unsigned short* h    = xT   + (size_t)B_ * L_ * NP_;
    unsigned short* W2T  = h    + (size_t)E_ * H_;
    unsigned short* Kc   = W2T  + (size_t)GL_ * H_;    // [Ec][4096]
    unsigned short* tc   = Kc   + (size_t)Ec * GL_;    // [Ec][4096]; later y8

    k_prep<<<dim3(PREP_NB), 256, 0, stream>>>(x, inc, ef, W1, b1, W2,
                                              incT, incB8, xT, W2T, h);

    int cidx = 0;
    for (int e_off = 0; e_off < E_; e_off += Ec, ++cidx) {
        const int ec = (E_ - e_off) < Ec ? (E_ - e_off) : Ec;   // multiple of 128
        gemm_pair<<<dim3((ec / 128) * 32, 2), 256, 0, stream>>>(
            h + (size_t)e_off * H_, H_, W2T, H_, H_, Kc, b2,
            incT + (size_t)e_off * NP_, NP_, xT, NP_, NP_, tc, 32);
        k_y8<<<dim3(ec / 8), 512, 0, stream>>>(tc, Kc);             // y8 over t
        k_accd<<<dim3(256, KS_), 256, 0, stream>>>(
            incB8 + (size_t)e_off * NP_, tc, planesB, cidx * KS_, ec);
    }

    k_final<<<dim3(ACC_ELEMS / 2048), 256, 0, stream>>>(planesB, nc * KS_, bgc, out);
}